// Round 2
// baseline (2236.102 us; speedup 1.0000x reference)
//
#include <hip/hip_runtime.h>
#include <math.h>

// ---------------- constants ----------------
static constexpr int NIMG = 16;
static constexpr int HDIM = 56;
static constexpr int TOK  = NIMG * HDIM * HDIM;      // 50176
static constexpr size_t TC = (size_t)TOK * 256;      // 12,845,056

__device__ inline float bf2f(unsigned short u) {
  unsigned int i = ((unsigned int)u) << 16; float f; __builtin_memcpy(&f, &i, 4); return f;
}
__device__ inline unsigned short f2bf(float f) {
  unsigned int i; __builtin_memcpy(&i, &f, 4);
  unsigned int r = i + 0x7fffu + ((i >> 16) & 1u);
  return (unsigned short)(r >> 16);
}

// ---------------- transpose NCHW -> NHWC ----------------
__global__ __launch_bounds__(256) void nchw2nhwc(const float* __restrict__ x,
                                                 float* __restrict__ y) {
  __shared__ float tile[32][33];
  int nh = blockIdx.z;
  int n = nh / 56, h = nh % 56;
  int c0 = blockIdx.y * 32, w0 = blockIdx.x * 32;
  int tx = threadIdx.x, ty = threadIdx.y;
#pragma unroll
  for (int i = 0; i < 4; i++) {
    int c = c0 + ty + i * 8, w = w0 + tx;
    if (w < 56) tile[ty + i * 8][tx] = x[(((size_t)n * 256 + c) * 56 + h) * 56 + w];
  }
  __syncthreads();
#pragma unroll
  for (int i = 0; i < 4; i++) {
    int w = w0 + ty + i * 8, c = c0 + tx;
    if (w < 56) y[(((size_t)n * 56 + h) * 56 + w) * 256 + c] = tile[tx][ty + i * 8];
  }
}

// ---------------- transpose NHWC -> NCHW ----------------
__global__ __launch_bounds__(256) void nhwc2nchw(const float* __restrict__ y,
                                                 float* __restrict__ o) {
  __shared__ float tile[32][33];
  int nh = blockIdx.z;
  int n = nh / 56, h = nh % 56;
  int w0 = blockIdx.x * 32, c0 = blockIdx.y * 32;
  int tx = threadIdx.x, ty = threadIdx.y;
#pragma unroll
  for (int i = 0; i < 4; i++) {
    int w = w0 + ty + i * 8, c = c0 + tx;
    if (w < 56) tile[ty + i * 8][tx] = y[(((size_t)n * 56 + h) * 56 + w) * 256 + c];
  }
  __syncthreads();
#pragma unroll
  for (int i = 0; i < 4; i++) {
    int c = c0 + ty + i * 8, w = w0 + tx;
    if (w < 56) o[(((size_t)n * 256 + c) * 56 + h) * 56 + w] = tile[tx][ty + i * 8];
  }
}

// ---------------- 3x3 depthwise conv residual (pos) ----------------
__global__ __launch_bounds__(256) void posconv_kernel(const float* __restrict__ xt,
                                                      const float* __restrict__ w,
                                                      const float* __restrict__ b,
                                                      float* __restrict__ xh) {
  int t = blockIdx.x, c = threadIdx.x;
  int n = t / 3136, rem = t % 3136, h = rem / 56, ww = rem % 56;
  float acc = b[c];
  for (int dh = -1; dh <= 1; dh++) {
    int hh = h + dh;
    if ((unsigned)hh >= 56u) continue;
    for (int dw = -1; dw <= 1; dw++) {
      int wc = ww + dw;
      if ((unsigned)wc >= 56u) continue;
      acc += xt[(((size_t)n * 56 + hh) * 56 + wc) * 256 + c] *
             w[((dh + 1) * 3 + (dw + 1)) * 256 + c];
    }
  }
  xh[(size_t)t * 256 + c] = xt[(size_t)t * 256 + c] + acc;
}

// ---------------- LayerNorm over C=256 ----------------
__global__ __launch_bounds__(256) void ln_kernel(const float* __restrict__ x,
                                                 const float* __restrict__ g,
                                                 const float* __restrict__ b,
                                                 float* __restrict__ y) {
  int t = blockIdx.x, c = threadIdx.x;
  float v = x[(size_t)t * 256 + c];
  __shared__ float red[256];
  red[c] = v;
  __syncthreads();
  for (int s = 128; s > 0; s >>= 1) {
    if (c < s) red[c] += red[c + s];
    __syncthreads();
  }
  float mu = red[0] * (1.f / 256.f);
  __syncthreads();
  float d = v - mu;
  red[c] = d * d;
  __syncthreads();
  for (int s = 128; s > 0; s >>= 1) {
    if (c < s) red[c] += red[c + s];
    __syncthreads();
  }
  float var = red[0] * (1.f / 256.f);
  y[(size_t)t * 256 + c] = d * rsqrtf(var + 1e-6f) * g[c] + b[c];
}

// ---------------- generic tiled GEMM: C = A[Mxlda] * W[N x ldw]^T + bias ----------------
// flags: 1 = exact GELU after bias, 2 = add residual R (fp32, ld=ldc), 8 = skip bias
template <bool ABF, bool OBF>
__global__ __launch_bounds__(256) void gemm_t(const void* __restrict__ A_, int lda,
                                              const float* __restrict__ W, int ldw,
                                              const float* __restrict__ bias,
                                              const float* __restrict__ R,
                                              void* __restrict__ C_, int ldc,
                                              int K, int flags) {
  __shared__ float As[16][65];
  __shared__ float Ws[16][65];
  int tid = threadIdx.x;
  int m0 = blockIdx.y * 64, n0 = blockIdx.x * 64;
  int lr = tid >> 2;             // 0..63
  int lk = (tid & 3) * 4;        // 0,4,8,12
  int tm4 = (tid >> 4) * 4, tn4 = (tid & 15) * 4;
  float acc[4][4] = {};
  for (int k0 = 0; k0 < K; k0 += 16) {
    if (ABF) {
      const unsigned short* A = (const unsigned short*)A_;
      short4 av = *reinterpret_cast<const short4*>(&A[(size_t)(m0 + lr) * lda + k0 + lk]);
      As[lk + 0][lr] = bf2f((unsigned short)av.x);
      As[lk + 1][lr] = bf2f((unsigned short)av.y);
      As[lk + 2][lr] = bf2f((unsigned short)av.z);
      As[lk + 3][lr] = bf2f((unsigned short)av.w);
    } else {
      const float* A = (const float*)A_;
      float4 av = *reinterpret_cast<const float4*>(&A[(size_t)(m0 + lr) * lda + k0 + lk]);
      As[lk + 0][lr] = av.x; As[lk + 1][lr] = av.y;
      As[lk + 2][lr] = av.z; As[lk + 3][lr] = av.w;
    }
    float4 wv = *reinterpret_cast<const float4*>(&W[(size_t)(n0 + lr) * ldw + k0 + lk]);
    Ws[lk + 0][lr] = wv.x; Ws[lk + 1][lr] = wv.y;
    Ws[lk + 2][lr] = wv.z; Ws[lk + 3][lr] = wv.w;
    __syncthreads();
#pragma unroll
    for (int kk = 0; kk < 16; kk++) {
      float a[4], bv[4];
#pragma unroll
      for (int i = 0; i < 4; i++) { a[i] = As[kk][tm4 + i]; bv[i] = Ws[kk][tn4 + i]; }
#pragma unroll
      for (int i = 0; i < 4; i++)
#pragma unroll
        for (int j = 0; j < 4; j++) acc[i][j] += a[i] * bv[j];
    }
    __syncthreads();
  }
#pragma unroll
  for (int i = 0; i < 4; i++) {
    int m = m0 + tm4 + i;
#pragma unroll
    for (int j = 0; j < 4; j++) {
      int n = n0 + tn4 + j;
      float v = acc[i][j];
      if (!(flags & 8)) v += bias[n];
      if (flags & 1) v = 0.5f * v * (1.0f + erff(v * 0.70710678118654752f));
      if (flags & 2) v += R[(size_t)m * ldc + n];
      if (OBF) ((unsigned short*)C_)[(size_t)m * ldc + n] = f2bf(v);
      else     ((float*)C_)[(size_t)m * ldc + n] = v;
    }
  }
}

// ---------------- pool LN1 output: 2x2 cell means + window means ----------------
__global__ __launch_bounds__(256) void pool_kernel(const float* __restrict__ x,
                                                   float* __restrict__ plx,
                                                   float* __restrict__ wmx) {
  int np = blockIdx.x, c = threadIdx.x;
  int n = np / 49, p = np % 49, wr = p / 7, wc = p % 7;
  float tot = 0.f;
  for (int s = 0; s < 16; s++) {
    int i = s >> 2, j = s & 3;
    float a = 0.f;
    for (int di = 0; di < 2; di++)
      for (int dj = 0; dj < 2; dj++) {
        size_t t = ((size_t)n * 56 + wr * 8 + i * 2 + di) * 56 + wc * 8 + j * 2 + dj;
        a += x[t * 256 + c];
      }
    a *= 0.25f;
    plx[((size_t)np * 16 + s) * 256 + c] = a;
    tot += a;
  }
  wmx[(size_t)np * 256 + c] = tot * (1.f / 16.f);
}

// ---------------- window-mean projection: qkwin = wmx @ qkv_w[0:512]^T + b ---------
__global__ __launch_bounds__(256) void winproj_kernel(const float* __restrict__ wmx,
                                                      const float* __restrict__ qkv_w,
                                                      const float* __restrict__ qkv_b,
                                                      float* __restrict__ qkwin) {
  int np = blockIdx.x, t = threadIdx.x;
  __shared__ float xs[256];
  xs[t] = wmx[(size_t)np * 256 + t];
  __syncthreads();
  for (int rep = 0; rep < 2; rep++) {
    int n = t + rep * 256;
    const float* wrow = qkv_w + (size_t)n * 256;
    float s = qkv_b[n];
    for (int c = 0; c < 256; c++) s += xs[c] * wrow[c];
    qkwin[(size_t)np * 512 + n] = s;
  }
}

// ---------------- routing logits + top-4 (set semantics) ----------------
__global__ __launch_bounds__(64) void topk_kernel(const float* __restrict__ qkwin,
                                                  int* __restrict__ idx) {
  int np = blockIdx.x;
  int n = np / 49;
  int j = threadIdx.x;
  __shared__ float lg[49];
  if (j < 49) {
    const float* qp = qkwin + (size_t)np * 512;
    const float* kp = qkwin + ((size_t)n * 49 + j) * 512 + 256;
    float s = 0.f;
    for (int c = 0; c < 256; c++) s += qp[c] * kp[c];
    lg[j] = s;
  }
  __syncthreads();
  if (j == 0) {
    unsigned long long used = 0ull;
    for (int t = 0; t < 4; t++) {
      float best = -INFINITY;
      int bi = 0;
      for (int q = 0; q < 49; q++)
        if (!((used >> q) & 1ull) && lg[q] > best) { best = lg[q]; bi = q; }
      idx[np * 4 + t] = bi;
      used |= (1ull << bi);
    }
  }
}

// ---------------- per-(window,head) attention ----------------
__global__ __launch_bounds__(256) void attn_kernel(const unsigned short* __restrict__ qb,
                                                   const float* __restrict__ kvp,
                                                   const int* __restrict__ idx,
                                                   float* __restrict__ out) {
  __shared__ float qs[64][33], ks[64][33], vs[64][33];
  __shared__ float att[64][65];
  int bid = blockIdx.x;
  int head = bid & 7;
  int np = bid >> 3;
  int n = np / 49, p = np % 49, wr = p / 7, wc = p % 7;
  int tid = threadIdx.x;
  int h0 = wr * 8, w0 = wc * 8;
  for (int e = tid; e < 2048; e += 256) {
    int tq = e >> 5, c = e & 31;
    int h = h0 + (tq >> 3), w = w0 + (tq & 7);
    qs[tq][c] = bf2f(qb[(((size_t)n * 56 + h) * 56 + w) * 256 + head * 32 + c]) * 0.0625f;
  }
  for (int e = tid; e < 2048; e += 256) {
    int s = e >> 5, c = e & 31;
    int wi = idx[np * 4 + (s >> 4)];
    size_t off = (((size_t)n * 49 + wi) * 16 + (s & 15)) * 512 + head * 32 + c;
    ks[s][c] = kvp[off];
    vs[s][c] = kvp[off + 256];
  }
  __syncthreads();
  int r = tid >> 2, jg = (tid & 3) * 16;
  for (int jj = 0; jj < 16; jj++) {
    int j = jg + jj;
    float s = 0.f;
#pragma unroll
    for (int c = 0; c < 32; c++) s += qs[r][c] * ks[j][c];
    att[r][j] = s;
  }
  __syncthreads();
  if (tid < 64) {
    float mx = -INFINITY;
    for (int j = 0; j < 64; j++) mx = fmaxf(mx, att[tid][j]);
    float sm = 0.f;
    for (int j = 0; j < 64; j++) {
      float e = expf(att[tid][j] - mx);
      att[tid][j] = e;
      sm += e;
    }
    float inv = 1.f / sm;
    for (int j = 0; j < 64; j++) att[tid][j] *= inv;
  }
  __syncthreads();
  for (int e = tid; e < 2048; e += 256) {
    int tq = e >> 5, c = e & 31;
    float o = 0.f;
    for (int s = 0; s < 64; s++) o += att[tq][s] * vs[s][c];
    int h = h0 + (tq >> 3), w = w0 + (tq & 7);
    out[(((size_t)n * 56 + h) * 56 + w) * 256 + head * 32 + c] = o;
  }
}

// ---------------- 5x5 depthwise conv (lepe) accumulated into attn out ----------------
__global__ __launch_bounds__(256) void lepe_kernel(const unsigned short* __restrict__ vb,
                                                   const float* __restrict__ w,
                                                   const float* __restrict__ b,
                                                   float* __restrict__ out) {
  int t = blockIdx.x, c = threadIdx.x;
  int n = t / 3136, rem = t % 3136, h = rem / 56, ww = rem % 56;
  float acc = b[c];
  for (int dh = -2; dh <= 2; dh++) {
    int hh = h + dh;
    if ((unsigned)hh >= 56u) continue;
    for (int dw = -2; dw <= 2; dw++) {
      int wc = ww + dw;
      if ((unsigned)wc >= 56u) continue;
      acc += bf2f(vb[(((size_t)n * 56 + hh) * 56 + wc) * 256 + c]) *
             w[((dh + 2) * 5 + (dw + 2)) * 256 + c];
    }
  }
  out[(size_t)t * 256 + c] += acc;
}

// ---------------- launch ----------------
extern "C" void kernel_launch(void* const* d_in, const int* in_sizes, int n_in,
                              void* d_out, int out_size, void* d_ws, size_t ws_size,
                              hipStream_t stream) {
  const float* x      = (const float*)d_in[0];
  const float* pos_w  = (const float*)d_in[1];
  const float* pos_b  = (const float*)d_in[2];
  const float* ln1_g  = (const float*)d_in[3];
  const float* ln1_b  = (const float*)d_in[4];
  const float* ln2_g  = (const float*)d_in[5];
  const float* ln2_b  = (const float*)d_in[6];
  const float* qkv_w  = (const float*)d_in[7];
  const float* qkv_b  = (const float*)d_in[8];
  const float* wo_w   = (const float*)d_in[9];
  const float* wo_b   = (const float*)d_in[10];
  const float* lepe_w = (const float*)d_in[11];
  const float* lepe_b = (const float*)d_in[12];
  const float* fc1_w  = (const float*)d_in[13];
  const float* fc1_b  = (const float*)d_in[14];
  const float* fc2_w  = (const float*)d_in[15];
  const float* fc2_b  = (const float*)d_in[16];

  // d_out doubles as the r1 stream (NHWC, TC floats); safe: final transpose reads r2 only.
  float* r1 = (float*)d_out;

  // ws arena (~137 MiB total)
  float*          r2  = (float*)d_ws;                 // TC f32: residual xh
  unsigned short* qb  = (unsigned short*)(r2 + TC);   // TC bf16: per-pixel q
  unsigned short* vb  = qb + TC;                      // TC bf16: per-pixel v
  float*          kvp = (float*)(vb + TC);            // 12544 x 512 f32 pooled k|v
  float*          plx = kvp + (size_t)12544 * 512;    // 12544 x 256 f32 pooled ln1
  float*          wmx = plx + (size_t)12544 * 256;    // 784 x 256 f32 window-mean ln1
  float*          qkw = wmx + (size_t)784 * 256;      // 784 x 512 f32 qwin|kwin
  int*            idx = (int*)(qkw + (size_t)784 * 512);
  unsigned short* hbuf = qb;  // MLP hidden half (50176 x 512 bf16) reuses dead q+v region

  dim3 tb(32, 8);
  nchw2nhwc<<<dim3(2, 8, NIMG * 56), tb, 0, stream>>>(x, r1);
  posconv_kernel<<<TOK, 256, 0, stream>>>(r1, pos_w, pos_b, r2);
  ln_kernel<<<TOK, 256, 0, stream>>>(r2, ln1_g, ln1_b, r1);
  // q and v per-pixel projections (bf16 out)
  gemm_t<false, true><<<dim3(4, 784), 256, 0, stream>>>(r1, 256, qkv_w, 256, qkv_b,
                                                        nullptr, qb, 256, 256, 0);
  gemm_t<false, true><<<dim3(4, 784), 256, 0, stream>>>(r1, 256, qkv_w + (size_t)512 * 256, 256,
                                                        qkv_b + 512, nullptr, vb, 256, 256, 0);
  // pooled stats and projections (linearity of mean)
  pool_kernel<<<784, 256, 0, stream>>>(r1, plx, wmx);
  gemm_t<false, false><<<dim3(8, 196), 256, 0, stream>>>(plx, 256, qkv_w + (size_t)256 * 256, 256,
                                                         qkv_b + 256, nullptr, kvp, 512, 256, 0);
  winproj_kernel<<<784, 256, 0, stream>>>(wmx, qkv_w, qkv_b, qkw);
  topk_kernel<<<784, 64, 0, stream>>>(qkw, idx);
  attn_kernel<<<6272, 256, 0, stream>>>(qb, kvp, idx, r1);
  lepe_kernel<<<TOK, 256, 0, stream>>>(vb, lepe_w, lepe_b, r1);
  gemm_t<false, false><<<dim3(4, 784), 256, 0, stream>>>(r1, 256, wo_w, 256, wo_b,
                                                         r2, r2, 256, 256, 2);
  ln_kernel<<<TOK, 256, 0, stream>>>(r2, ln2_g, ln2_b, r1);
  // MLP in two hidden halves; fc2 accumulates in-place into r2
  gemm_t<false, true><<<dim3(8, 784), 256, 0, stream>>>(r1, 256, fc1_w, 256, fc1_b,
                                                        nullptr, hbuf, 512, 256, 1);
  gemm_t<true, false><<<dim3(4, 784), 256, 0, stream>>>(hbuf, 512, fc2_w, 1024, fc2_b,
                                                        r2, r2, 256, 512, 2);
  gemm_t<false, true><<<dim3(8, 784), 256, 0, stream>>>(r1, 256, fc1_w + (size_t)512 * 256, 256,
                                                        fc1_b + 512, nullptr, hbuf, 512, 256, 1);
  gemm_t<true, false><<<dim3(4, 784), 256, 0, stream>>>(hbuf, 512, fc2_w + 512, 1024, fc2_b,
                                                        r2, r2, 256, 512, 2 | 8);
  nhwc2nchw<<<dim3(2, 8, NIMG * 56), tb, 0, stream>>>(r2, (float*)d_out);
}

// Round 3
// 1015.148 us; speedup vs baseline: 2.2027x; 2.2027x over previous
//
#include <hip/hip_runtime.h>
#include <math.h>

// ---------------- constants ----------------
static constexpr int NIMG = 16;
static constexpr int TOK  = NIMG * 56 * 56;          // 50176
static constexpr size_t TC = (size_t)TOK * 256;      // 12,845,056
static constexpr int PTOK = 784 * 16;                // 12544 pooled tokens

typedef __bf16 bf16x8 __attribute__((ext_vector_type(8)));
typedef float  f32x4  __attribute__((ext_vector_type(4)));

__device__ inline float bf2f(unsigned short u) {
  unsigned int i = ((unsigned int)u) << 16; float f; __builtin_memcpy(&f, &i, 4); return f;
}
__device__ inline unsigned short f2bf(float f) {
  unsigned int i; __builtin_memcpy(&i, &f, 4);
  unsigned int r = i + 0x7fffu + ((i >> 16) & 1u);
  return (unsigned short)(r >> 16);
}

// ---------------- transpose NCHW -> NHWC ----------------
__global__ __launch_bounds__(256) void nchw2nhwc(const float* __restrict__ x,
                                                 float* __restrict__ y) {
  __shared__ float tile[32][33];
  int nh = blockIdx.z;
  int n = nh / 56, h = nh % 56;
  int c0 = blockIdx.y * 32, w0 = blockIdx.x * 32;
  int tx = threadIdx.x, ty = threadIdx.y;
#pragma unroll
  for (int i = 0; i < 4; i++) {
    int c = c0 + ty + i * 8, w = w0 + tx;
    if (w < 56) tile[ty + i * 8][tx] = x[(((size_t)n * 256 + c) * 56 + h) * 56 + w];
  }
  __syncthreads();
#pragma unroll
  for (int i = 0; i < 4; i++) {
    int w = w0 + ty + i * 8, c = c0 + tx;
    if (w < 56) y[(((size_t)n * 56 + h) * 56 + w) * 256 + c] = tile[tx][ty + i * 8];
  }
}

// ---------------- transpose NHWC -> NCHW ----------------
__global__ __launch_bounds__(256) void nhwc2nchw(const float* __restrict__ y,
                                                 float* __restrict__ o) {
  __shared__ float tile[32][33];
  int nh = blockIdx.z;
  int n = nh / 56, h = nh % 56;
  int w0 = blockIdx.x * 32, c0 = blockIdx.y * 32;
  int tx = threadIdx.x, ty = threadIdx.y;
#pragma unroll
  for (int i = 0; i < 4; i++) {
    int w = w0 + ty + i * 8, c = c0 + tx;
    if (w < 56) tile[ty + i * 8][tx] = y[(((size_t)n * 56 + h) * 56 + w) * 256 + c];
  }
  __syncthreads();
#pragma unroll
  for (int i = 0; i < 4; i++) {
    int c = c0 + ty + i * 8, w = w0 + tx;
    if (w < 56) o[(((size_t)n * 256 + c) * 56 + h) * 56 + w] = tile[tx][ty + i * 8];
  }
}

// ---------------- 3x3 depthwise conv residual (pos) ----------------
__global__ __launch_bounds__(256) void posconv_kernel(const float* __restrict__ xt,
                                                      const float* __restrict__ w,
                                                      const float* __restrict__ b,
                                                      float* __restrict__ xh) {
  int t = blockIdx.x, c = threadIdx.x;
  int n = t / 3136, rem = t % 3136, h = rem / 56, ww = rem % 56;
  float acc = b[c];
  for (int dh = -1; dh <= 1; dh++) {
    int hh = h + dh;
    if ((unsigned)hh >= 56u) continue;
    for (int dw = -1; dw <= 1; dw++) {
      int wc = ww + dw;
      if ((unsigned)wc >= 56u) continue;
      acc += xt[(((size_t)n * 56 + hh) * 56 + wc) * 256 + c] *
             w[((dh + 1) * 3 + (dw + 1)) * 256 + c];
    }
  }
  xh[(size_t)t * 256 + c] = xt[(size_t)t * 256 + c] + acc;
}

// ---------------- LayerNorm over C=256, optional f32 + bf16 outputs ------------
__global__ __launch_bounds__(256) void ln_kernel(const float* __restrict__ x,
                                                 const float* __restrict__ g,
                                                 const float* __restrict__ b,
                                                 float* __restrict__ of,
                                                 unsigned short* __restrict__ ob) {
  int t = blockIdx.x, c = threadIdx.x;
  float v = x[(size_t)t * 256 + c];
  __shared__ float red[256];
  red[c] = v;
  __syncthreads();
  for (int s = 128; s > 0; s >>= 1) {
    if (c < s) red[c] += red[c + s];
    __syncthreads();
  }
  float mu = red[0] * (1.f / 256.f);
  __syncthreads();
  float d = v - mu;
  red[c] = d * d;
  __syncthreads();
  for (int s = 128; s > 0; s >>= 1) {
    if (c < s) red[c] += red[c + s];
    __syncthreads();
  }
  float var = red[0] * (1.f / 256.f);
  float y = d * rsqrtf(var + 1e-6f) * g[c] + b[c];
  if (of) of[(size_t)t * 256 + c] = y;
  if (ob) ob[(size_t)t * 256 + c] = f2bf(y);
}

// ---------------- MFMA bf16 GEMM: C[M][N] = A[M][lda] * B[N][ldb]^T ----------------
// 128x128 tile, BK=64, 4 waves, global_load_lds staging with source-side XOR swizzle.
// flags: 1 = exact GELU, 2 = += R (f32, ld=N), 8 = skip bias
template <bool OUTBF>
__global__ __launch_bounds__(256) void mgemm(const unsigned short* __restrict__ A, int lda,
                                             const unsigned short* __restrict__ B, int ldb,
                                             const float* __restrict__ bias,
                                             const float* __restrict__ R,
                                             void* __restrict__ C_,
                                             int N, int K, int flags) {
  __shared__ unsigned short As[128 * 64];
  __shared__ unsigned short Bs[128 * 64];
  int tid = threadIdx.x;
  int m0 = blockIdx.y * 128, n0 = blockIdx.x * 128;
  int lane = tid & 63, wid = tid >> 6;
  int wr = (wid >> 1) * 64, wc = (wid & 1) * 64;

  f32x4 acc[4][4];
#pragma unroll
  for (int i = 0; i < 4; i++)
#pragma unroll
    for (int j = 0; j < 4; j++) acc[i][j] = (f32x4){0.f, 0.f, 0.f, 0.f};

  // precompute staging coordinates (4 chunks of 16B per tile per thread)
  int grow[4], gcol[4];
#pragma unroll
  for (int i = 0; i < 4; i++) {
    int q = tid + 256 * i;
    grow[i] = q >> 3;
    gcol[i] = (q & 7) ^ (grow[i] & 7);   // source-side swizzle (involution)
  }

  for (int k0 = 0; k0 < K; k0 += 64) {
#pragma unroll
    for (int i = 0; i < 4; i++) {
      int q = tid + 256 * i;
      const unsigned short* ga = A + (size_t)(m0 + grow[i]) * lda + k0 + gcol[i] * 8;
      const unsigned short* gb = B + (size_t)(n0 + grow[i]) * ldb + k0 + gcol[i] * 8;
      __builtin_amdgcn_global_load_lds(
          (const __attribute__((address_space(1))) unsigned int*)ga,
          (__attribute__((address_space(3))) unsigned int*)(As + q * 8), 16, 0, 0);
      __builtin_amdgcn_global_load_lds(
          (const __attribute__((address_space(1))) unsigned int*)gb,
          (__attribute__((address_space(3))) unsigned int*)(Bs + q * 8), 16, 0, 0);
    }
    __syncthreads();   // compiler drains vmcnt before barrier
#pragma unroll
    for (int ks = 0; ks < 2; ks++) {
      int cchunk = ks * 4 + (lane >> 4);
      bf16x8 af[4], bfr[4];
#pragma unroll
      for (int mi = 0; mi < 4; mi++) {
        int r = wr + mi * 16 + (lane & 15);
        __builtin_memcpy(&af[mi], As + (size_t)r * 64 + (cchunk ^ (r & 7)) * 8, 16);
      }
#pragma unroll
      for (int nj = 0; nj < 4; nj++) {
        int r = wc + nj * 16 + (lane & 15);
        __builtin_memcpy(&bfr[nj], Bs + (size_t)r * 64 + (cchunk ^ (r & 7)) * 8, 16);
      }
#pragma unroll
      for (int mi = 0; mi < 4; mi++)
#pragma unroll
        for (int nj = 0; nj < 4; nj++)
          acc[mi][nj] = __builtin_amdgcn_mfma_f32_16x16x32_bf16(af[mi], bfr[nj],
                                                                acc[mi][nj], 0, 0, 0);
    }
    __syncthreads();
  }

  // epilogue: C/D layout col=lane&15, row=(lane>>4)*4+reg
  int coln = lane & 15, rowg = (lane >> 4) * 4;
#pragma unroll
  for (int mi = 0; mi < 4; mi++) {
#pragma unroll
    for (int nj = 0; nj < 4; nj++) {
      int n = n0 + wc + nj * 16 + coln;
      float bv = (flags & 8) ? 0.f : bias[n];
#pragma unroll
      for (int j = 0; j < 4; j++) {
        int m = m0 + wr + mi * 16 + rowg + j;
        float v = acc[mi][nj][j] + bv;
        if (flags & 1) v = 0.5f * v * (1.0f + erff(v * 0.70710678118654752f));
        if (flags & 2) v += R[(size_t)m * N + n];
        if (OUTBF) ((unsigned short*)C_)[(size_t)m * N + n] = f2bf(v);
        else       ((float*)C_)[(size_t)m * N + n] = v;
      }
    }
  }
}

// ---------------- f32 -> bf16 flat convert ----------------
__global__ __launch_bounds__(256) void cvt_kernel(const float* __restrict__ s,
                                                  unsigned short* __restrict__ d, int n) {
  int i = blockIdx.x * 256 + threadIdx.x;
  if (i < n) d[i] = f2bf(s[i]);
}

// ---------------- pack qv bias ----------------
__global__ __launch_bounds__(512) void bqv_kernel(const float* __restrict__ qkv_b,
                                                  float* __restrict__ bqv) {
  int i = threadIdx.x;
  bqv[i] = qkv_b[i < 256 ? i : i + 256];
}

// ---------------- pool LN1 (f32 in): 2x2 cell means (bf16) + window means (f32) ----
__global__ __launch_bounds__(256) void pool_kernel(const float* __restrict__ x,
                                                   unsigned short* __restrict__ plx,
                                                   float* __restrict__ wmx) {
  int np = blockIdx.x, c = threadIdx.x;
  int n = np / 49, p = np % 49, wr = p / 7, wc = p % 7;
  float tot = 0.f;
  for (int s = 0; s < 16; s++) {
    int i = s >> 2, j = s & 3;
    float a = 0.f;
    for (int di = 0; di < 2; di++)
      for (int dj = 0; dj < 2; dj++) {
        size_t t = ((size_t)n * 56 + wr * 8 + i * 2 + di) * 56 + wc * 8 + j * 2 + dj;
        a += x[t * 256 + c];
      }
    a *= 0.25f;
    plx[((size_t)np * 16 + s) * 256 + c] = f2bf(a);
    tot += a;
  }
  wmx[(size_t)np * 256 + c] = tot * (1.f / 16.f);
}

// ---------------- window-mean projection (f32): qkwin = wmx @ qkv_w[0:512]^T + b ----
__global__ __launch_bounds__(256) void winproj_kernel(const float* __restrict__ wmx,
                                                      const float* __restrict__ qkv_w,
                                                      const float* __restrict__ qkv_b,
                                                      float* __restrict__ qkwin) {
  int np = blockIdx.x, t = threadIdx.x;
  __shared__ float xs[256];
  xs[t] = wmx[(size_t)np * 256 + t];
  __syncthreads();
  for (int rep = 0; rep < 2; rep++) {
    int n = t + rep * 256;
    const float* wrow = qkv_w + (size_t)n * 256;
    float s = qkv_b[n];
    for (int c = 0; c < 256; c++) s += xs[c] * wrow[c];
    qkwin[(size_t)np * 512 + n] = s;
  }
}

// ---------------- routing logits + top-4 (set semantics) ----------------
__global__ __launch_bounds__(64) void topk_kernel(const float* __restrict__ qkwin,
                                                  int* __restrict__ idx) {
  int np = blockIdx.x;
  int n = np / 49;
  int j = threadIdx.x;
  __shared__ float lg[49];
  if (j < 49) {
    const float* qp = qkwin + (size_t)np * 512;
    const float* kp = qkwin + ((size_t)n * 49 + j) * 512 + 256;
    float s = 0.f;
    for (int c = 0; c < 256; c++) s += qp[c] * kp[c];
    lg[j] = s;
  }
  __syncthreads();
  if (j == 0) {
    unsigned long long used = 0ull;
    for (int t = 0; t < 4; t++) {
      float best = -INFINITY;
      int bi = 0;
      for (int q = 0; q < 49; q++)
        if (!((used >> q) & 1ull) && lg[q] > best) { best = lg[q]; bi = q; }
      idx[np * 4 + t] = bi;
      used |= (1ull << bi);
    }
  }
}

// ---------------- per-(window,head) attention (bf16 in, bf16 out) ----------------
__global__ __launch_bounds__(256) void attn_kernel(const unsigned short* __restrict__ qvb,
                                                   const unsigned short* __restrict__ kvp,
                                                   const int* __restrict__ idx,
                                                   unsigned short* __restrict__ out) {
  __shared__ float qs[64][33], ks[64][33], vs[64][33];
  __shared__ float att[64][65];
  int bid = blockIdx.x;
  int head = bid & 7;
  int np = bid >> 3;
  int n = np / 49, p = np % 49, wr = p / 7, wc = p % 7;
  int tid = threadIdx.x;
  int h0 = wr * 8, w0 = wc * 8;
  for (int e = tid; e < 2048; e += 256) {
    int tq = e >> 5, c = e & 31;
    int h = h0 + (tq >> 3), w = w0 + (tq & 7);
    qs[tq][c] = bf2f(qvb[(((size_t)n * 56 + h) * 56 + w) * 512 + head * 32 + c]) * 0.0625f;
  }
  for (int e = tid; e < 2048; e += 256) {
    int s = e >> 5, c = e & 31;
    int wi = idx[np * 4 + (s >> 4)];
    size_t off = (((size_t)n * 49 + wi) * 16 + (s & 15)) * 512 + head * 32 + c;
    ks[s][c] = bf2f(kvp[off]);
    vs[s][c] = bf2f(kvp[off + 256]);
  }
  __syncthreads();
  int r = tid >> 2, jg = (tid & 3) * 16;
  for (int jj = 0; jj < 16; jj++) {
    int j = jg + jj;
    float s = 0.f;
#pragma unroll
    for (int c = 0; c < 32; c++) s += qs[r][c] * ks[j][c];
    att[r][j] = s;
  }
  __syncthreads();
  if (tid < 64) {
    float mx = -INFINITY;
    for (int j = 0; j < 64; j++) mx = fmaxf(mx, att[tid][j]);
    float sm = 0.f;
    for (int j = 0; j < 64; j++) {
      float e = expf(att[tid][j] - mx);
      att[tid][j] = e;
      sm += e;
    }
    float inv = 1.f / sm;
    for (int j = 0; j < 64; j++) att[tid][j] *= inv;
  }
  __syncthreads();
  for (int e = tid; e < 2048; e += 256) {
    int tq = e >> 5, c = e & 31;
    float o = 0.f;
    for (int s = 0; s < 64; s++) o += att[tq][s] * vs[s][c];
    int h = h0 + (tq >> 3), w = w0 + (tq & 7);
    out[(((size_t)n * 56 + h) * 56 + w) * 256 + head * 32 + c] = f2bf(o);
  }
}

// ---------------- 5x5 depthwise conv (lepe), RMW into attn out (bf16) ------------
__global__ __launch_bounds__(256) void lepe_kernel(const unsigned short* __restrict__ qvb,
                                                   const float* __restrict__ w,
                                                   const float* __restrict__ b,
                                                   unsigned short* __restrict__ out) {
  int t = blockIdx.x, c = threadIdx.x;
  int n = t / 3136, rem = t % 3136, h = rem / 56, ww = rem % 56;
  float acc = b[c];
  for (int dh = -2; dh <= 2; dh++) {
    int hh = h + dh;
    if ((unsigned)hh >= 56u) continue;
    for (int dw = -2; dw <= 2; dw++) {
      int wc = ww + dw;
      if ((unsigned)wc >= 56u) continue;
      acc += bf2f(qvb[(((size_t)n * 56 + hh) * 56 + wc) * 512 + 256 + c]) *
             w[((dh + 2) * 5 + (dw + 2)) * 256 + c];
    }
  }
  size_t o = (size_t)t * 256 + c;
  out[o] = f2bf(bf2f(out[o]) + acc);
}

// ---------------- launch ----------------
extern "C" void kernel_launch(void* const* d_in, const int* in_sizes, int n_in,
                              void* d_out, int out_size, void* d_ws, size_t ws_size,
                              hipStream_t stream) {
  const float* x      = (const float*)d_in[0];
  const float* pos_w  = (const float*)d_in[1];
  const float* pos_b  = (const float*)d_in[2];
  const float* ln1_g  = (const float*)d_in[3];
  const float* ln1_b  = (const float*)d_in[4];
  const float* ln2_g  = (const float*)d_in[5];
  const float* ln2_b  = (const float*)d_in[6];
  const float* qkv_w  = (const float*)d_in[7];
  const float* qkv_b  = (const float*)d_in[8];
  const float* wo_w   = (const float*)d_in[9];
  const float* wo_b   = (const float*)d_in[10];
  const float* lepe_w = (const float*)d_in[11];
  const float* lepe_b = (const float*)d_in[12];
  const float* fc1_w  = (const float*)d_in[13];
  const float* fc1_b  = (const float*)d_in[14];
  const float* fc2_w  = (const float*)d_in[15];
  const float* fc2_b  = (const float*)d_in[16];

  // d_out (TC f32 = 51.4 MB) timeline: xt -> ln1_f32 -> qvb(bf16) -> hbuf(bf16) -> final
  float*          xt   = (float*)d_out;
  float*          lnf  = (float*)d_out;
  unsigned short* qvb  = (unsigned short*)d_out;   // [TOK][512] bf16: q|v
  unsigned short* hbuf = (unsigned short*)d_out;   // [TOK][512] bf16 MLP hidden half

  // ws arena (~100 MB)
  float*          r2   = (float*)d_ws;                       // TC f32 residual
  float*          wmx  = r2 + TC;                            // 784x256 f32
  float*          qkw  = wmx + (size_t)784 * 256;            // 784x512 f32
  float*          bqv  = qkw + (size_t)784 * 512;            // 512 f32
  unsigned short* lnb  = (unsigned short*)(bqv + 512);       // [TOK][256] bf16 (-> aob -> ln2b)
  unsigned short* aob  = lnb;
  unsigned short* ln2b = lnb;
  unsigned short* plx  = lnb + TC;                           // [PTOK][256] bf16
  unsigned short* kvp  = plx + (size_t)PTOK * 256;           // [PTOK][512] bf16
  unsigned short* wqv  = kvp + (size_t)PTOK * 512;           // [512][256] bf16
  unsigned short* wkv  = wqv + (size_t)512 * 256;            // [512][256] bf16
  unsigned short* wwo  = wkv + (size_t)512 * 256;            // [256][256] bf16
  unsigned short* wfc1 = wwo + (size_t)256 * 256;            // [1024][256] bf16
  unsigned short* wfc2 = wfc1 + (size_t)1024 * 256;          // [256][1024] bf16
  int*            idx  = (int*)(wfc2 + (size_t)256 * 1024);  // 784x4

  // weight conversions (independent of data path)
  cvt_kernel<<<(65536 + 255) / 256, 256, 0, stream>>>(qkv_w, wqv, 65536);                     // q rows
  cvt_kernel<<<(65536 + 255) / 256, 256, 0, stream>>>(qkv_w + (size_t)512 * 256, wqv + 65536, 65536); // v rows
  cvt_kernel<<<(131072 + 255) / 256, 256, 0, stream>>>(qkv_w + (size_t)256 * 256, wkv, 131072);       // k|v rows
  cvt_kernel<<<(65536 + 255) / 256, 256, 0, stream>>>(wo_w, wwo, 65536);
  cvt_kernel<<<(262144 + 255) / 256, 256, 0, stream>>>(fc1_w, wfc1, 262144);
  cvt_kernel<<<(262144 + 255) / 256, 256, 0, stream>>>(fc2_w, wfc2, 262144);
  bqv_kernel<<<1, 512, 0, stream>>>(qkv_b, bqv);

  dim3 tb(32, 8);
  nchw2nhwc<<<dim3(2, 8, NIMG * 56), tb, 0, stream>>>(x, xt);
  posconv_kernel<<<TOK, 256, 0, stream>>>(xt, pos_w, pos_b, r2);
  ln_kernel<<<TOK, 256, 0, stream>>>(r2, ln1_g, ln1_b, lnf, lnb);
  pool_kernel<<<784, 256, 0, stream>>>(lnf, plx, wmx);            // last reader of lnf
  // q|v projection: [TOK][512] bf16 (overwrites lnf region)
  mgemm<true><<<dim3(4, TOK / 128), 256, 0, stream>>>(lnb, 256, wqv, 256, bqv,
                                                      nullptr, qvb, 512, 256, 0);
  // pooled k|v projection: [PTOK][512] bf16
  mgemm<true><<<dim3(4, PTOK / 128), 256, 0, stream>>>(plx, 256, wkv, 256, qkv_b + 256,
                                                       nullptr, kvp, 512, 256, 0);
  winproj_kernel<<<784, 256, 0, stream>>>(wmx, qkv_w, qkv_b, qkw);
  topk_kernel<<<784, 64, 0, stream>>>(qkw, idx);
  attn_kernel<<<6272, 256, 0, stream>>>(qvb, kvp, idx, aob);
  lepe_kernel<<<TOK, 256, 0, stream>>>(qvb, lepe_w, lepe_b, aob);
  // wo projection + residual -> r2 (f32)
  mgemm<false><<<dim3(2, TOK / 128), 256, 0, stream>>>(aob, 256, wwo, 256, wo_b,
                                                       r2, r2, 256, 256, 2);
  ln_kernel<<<TOK, 256, 0, stream>>>(r2, ln2_g, ln2_b, nullptr, ln2b);
  // MLP: two hidden halves of 512 (hbuf overwrites dead qvb)
  mgemm<true><<<dim3(4, TOK / 128), 256, 0, stream>>>(ln2b, 256, wfc1, 256, fc1_b,
                                                      nullptr, hbuf, 512, 256, 1);
  mgemm<false><<<dim3(2, TOK / 128), 256, 0, stream>>>(hbuf, 512, wfc2, 1024, fc2_b,
                                                       r2, r2, 256, 512, 2);
  mgemm<true><<<dim3(4, TOK / 128), 256, 0, stream>>>(ln2b, 256, wfc1 + (size_t)512 * 256, 256,
                                                      fc1_b + 512, nullptr, hbuf, 512, 256, 1);
  mgemm<false><<<dim3(2, TOK / 128), 256, 0, stream>>>(hbuf, 512, wfc2 + 512, 1024, fc2_b,
                                                       r2, r2, 256, 512, 2 | 8);
  nhwc2nchw<<<dim3(2, 8, NIMG * 56), tb, 0, stream>>>(r2, (float*)d_out);
}

// Round 4
// 851.566 us; speedup vs baseline: 2.6259x; 1.1921x over previous
//
#include <hip/hip_runtime.h>
#include <math.h>

// ---------------- constants ----------------
static constexpr int NIMG = 16;
static constexpr int TOK  = NIMG * 56 * 56;          // 50176
static constexpr size_t TC = (size_t)TOK * 256;      // 12,845,056
static constexpr int PTOK = 784 * 16;                // 12544 pooled tokens

typedef __bf16 bf16x8 __attribute__((ext_vector_type(8)));
typedef float  f32x4  __attribute__((ext_vector_type(4)));

__device__ inline float bf2f(unsigned short u) {
  unsigned int i = ((unsigned int)u) << 16; float f; __builtin_memcpy(&f, &i, 4); return f;
}
__device__ inline unsigned short f2bf(float f) {
  unsigned int i; __builtin_memcpy(&i, &f, 4);
  unsigned int r = i + 0x7fffu + ((i >> 16) & 1u);
  return (unsigned short)(r >> 16);
}

// ---------------- transpose NCHW -> NHWC ----------------
__global__ __launch_bounds__(256) void nchw2nhwc(const float* __restrict__ x,
                                                 float* __restrict__ y) {
  __shared__ float tile[32][33];
  int nh = blockIdx.z;
  int n = nh / 56, h = nh % 56;
  int c0 = blockIdx.y * 32, w0 = blockIdx.x * 32;
  int tx = threadIdx.x, ty = threadIdx.y;
#pragma unroll
  for (int i = 0; i < 4; i++) {
    int c = c0 + ty + i * 8, w = w0 + tx;
    if (w < 56) tile[ty + i * 8][tx] = x[(((size_t)n * 256 + c) * 56 + h) * 56 + w];
  }
  __syncthreads();
#pragma unroll
  for (int i = 0; i < 4; i++) {
    int w = w0 + ty + i * 8, c = c0 + tx;
    if (w < 56) y[(((size_t)n * 56 + h) * 56 + w) * 256 + c] = tile[tx][ty + i * 8];
  }
}

// ---------------- transpose NHWC -> NCHW ----------------
__global__ __launch_bounds__(256) void nhwc2nchw(const float* __restrict__ y,
                                                 float* __restrict__ o) {
  __shared__ float tile[32][33];
  int nh = blockIdx.z;
  int n = nh / 56, h = nh % 56;
  int w0 = blockIdx.x * 32, c0 = blockIdx.y * 32;
  int tx = threadIdx.x, ty = threadIdx.y;
#pragma unroll
  for (int i = 0; i < 4; i++) {
    int w = w0 + ty + i * 8, c = c0 + tx;
    if (w < 56) tile[ty + i * 8][tx] = y[(((size_t)n * 56 + h) * 56 + w) * 256 + c];
  }
  __syncthreads();
#pragma unroll
  for (int i = 0; i < 4; i++) {
    int c = c0 + ty + i * 8, w = w0 + tx;
    if (w < 56) o[(((size_t)n * 256 + c) * 56 + h) * 56 + w] = tile[tx][ty + i * 8];
  }
}

// ---------------- 3x3 depthwise conv residual (pos) ----------------
__global__ __launch_bounds__(256) void posconv_kernel(const float* __restrict__ xt,
                                                      const float* __restrict__ w,
                                                      const float* __restrict__ b,
                                                      float* __restrict__ xh) {
  int t = blockIdx.x, c = threadIdx.x;
  int n = t / 3136, rem = t % 3136, h = rem / 56, ww = rem % 56;
  float acc = b[c];
  for (int dh = -1; dh <= 1; dh++) {
    int hh = h + dh;
    if ((unsigned)hh >= 56u) continue;
    for (int dw = -1; dw <= 1; dw++) {
      int wc = ww + dw;
      if ((unsigned)wc >= 56u) continue;
      acc += xt[(((size_t)n * 56 + hh) * 56 + wc) * 256 + c] *
             w[((dh + 1) * 3 + (dw + 1)) * 256 + c];
    }
  }
  xh[(size_t)t * 256 + c] = xt[(size_t)t * 256 + c] + acc;
}

// ---------------- LayerNorm over C=256, optional f32 + bf16 outputs ------------
__global__ __launch_bounds__(256) void ln_kernel(const float* __restrict__ x,
                                                 const float* __restrict__ g,
                                                 const float* __restrict__ b,
                                                 float* __restrict__ of,
                                                 unsigned short* __restrict__ ob) {
  int t = blockIdx.x, c = threadIdx.x;
  float v = x[(size_t)t * 256 + c];
  __shared__ float red[256];
  red[c] = v;
  __syncthreads();
  for (int s = 128; s > 0; s >>= 1) {
    if (c < s) red[c] += red[c + s];
    __syncthreads();
  }
  float mu = red[0] * (1.f / 256.f);
  __syncthreads();
  float d = v - mu;
  red[c] = d * d;
  __syncthreads();
  for (int s = 128; s > 0; s >>= 1) {
    if (c < s) red[c] += red[c + s];
    __syncthreads();
  }
  float var = red[0] * (1.f / 256.f);
  float y = d * rsqrtf(var + 1e-6f) * g[c] + b[c];
  if (of) of[(size_t)t * 256 + c] = y;
  if (ob) ob[(size_t)t * 256 + c] = f2bf(y);
}

// ---------------- MFMA bf16 GEMM: C[M][N] = A[M][lda] * B[N][ldb]^T ----------------
// 128x128 tile, BK=64, 4 waves, global_load_lds staging with source-side XOR swizzle.
// flags: 1 = exact GELU, 2 = += R (f32, ld=N), 8 = skip bias
template <bool OUTBF>
__global__ __launch_bounds__(256) void mgemm(const unsigned short* __restrict__ A, int lda,
                                             const unsigned short* __restrict__ B, int ldb,
                                             const float* __restrict__ bias,
                                             const float* __restrict__ R,
                                             void* __restrict__ C_,
                                             int N, int K, int flags) {
  __shared__ unsigned short As[128 * 64];
  __shared__ unsigned short Bs[128 * 64];
  int tid = threadIdx.x;
  int m0 = blockIdx.y * 128, n0 = blockIdx.x * 128;
  int lane = tid & 63, wid = tid >> 6;
  int wr = (wid >> 1) * 64, wc = (wid & 1) * 64;

  f32x4 acc[4][4];
#pragma unroll
  for (int i = 0; i < 4; i++)
#pragma unroll
    for (int j = 0; j < 4; j++) acc[i][j] = (f32x4){0.f, 0.f, 0.f, 0.f};

  int grow[4], gcol[4];
#pragma unroll
  for (int i = 0; i < 4; i++) {
    int q = tid + 256 * i;
    grow[i] = q >> 3;
    gcol[i] = (q & 7) ^ (grow[i] & 7);
  }

  for (int k0 = 0; k0 < K; k0 += 64) {
#pragma unroll
    for (int i = 0; i < 4; i++) {
      int q = tid + 256 * i;
      const unsigned short* ga = A + (size_t)(m0 + grow[i]) * lda + k0 + gcol[i] * 8;
      const unsigned short* gb = B + (size_t)(n0 + grow[i]) * ldb + k0 + gcol[i] * 8;
      __builtin_amdgcn_global_load_lds(
          (const __attribute__((address_space(1))) unsigned int*)ga,
          (__attribute__((address_space(3))) unsigned int*)(As + q * 8), 16, 0, 0);
      __builtin_amdgcn_global_load_lds(
          (const __attribute__((address_space(1))) unsigned int*)gb,
          (__attribute__((address_space(3))) unsigned int*)(Bs + q * 8), 16, 0, 0);
    }
    __syncthreads();
#pragma unroll
    for (int ks = 0; ks < 2; ks++) {
      int cchunk = ks * 4 + (lane >> 4);
      bf16x8 af[4], bfr[4];
#pragma unroll
      for (int mi = 0; mi < 4; mi++) {
        int r = wr + mi * 16 + (lane & 15);
        __builtin_memcpy(&af[mi], As + (size_t)r * 64 + (cchunk ^ (r & 7)) * 8, 16);
      }
#pragma unroll
      for (int nj = 0; nj < 4; nj++) {
        int r = wc + nj * 16 + (lane & 15);
        __builtin_memcpy(&bfr[nj], Bs + (size_t)r * 64 + (cchunk ^ (r & 7)) * 8, 16);
      }
#pragma unroll
      for (int mi = 0; mi < 4; mi++)
#pragma unroll
        for (int nj = 0; nj < 4; nj++)
          acc[mi][nj] = __builtin_amdgcn_mfma_f32_16x16x32_bf16(af[mi], bfr[nj],
                                                                acc[mi][nj], 0, 0, 0);
    }
    __syncthreads();
  }

  int coln = lane & 15, rowg = (lane >> 4) * 4;
#pragma unroll
  for (int mi = 0; mi < 4; mi++) {
#pragma unroll
    for (int nj = 0; nj < 4; nj++) {
      int n = n0 + wc + nj * 16 + coln;
      float bv = (flags & 8) ? 0.f : bias[n];
#pragma unroll
      for (int j = 0; j < 4; j++) {
        int m = m0 + wr + mi * 16 + rowg + j;
        float v = acc[mi][nj][j] + bv;
        if (flags & 1) v = 0.5f * v * (1.0f + erff(v * 0.70710678118654752f));
        if (flags & 2) v += R[(size_t)m * N + n];
        if (OUTBF) ((unsigned short*)C_)[(size_t)m * N + n] = f2bf(v);
        else       ((float*)C_)[(size_t)m * N + n] = v;
      }
    }
  }
}

// ---------------- f32 -> bf16 flat convert ----------------
__global__ __launch_bounds__(256) void cvt_kernel(const float* __restrict__ s,
                                                  unsigned short* __restrict__ d, int n) {
  int i = blockIdx.x * 256 + threadIdx.x;
  if (i < n) d[i] = f2bf(s[i]);
}

// ---------------- pack qv bias ----------------
__global__ __launch_bounds__(512) void bqv_kernel(const float* __restrict__ qkv_b,
                                                  float* __restrict__ bqv) {
  int i = threadIdx.x;
  bqv[i] = qkv_b[i < 256 ? i : i + 256];
}

// ---------------- pool LN1 (f32 in): 2x2 cell means (bf16) + window means (f32) ----
__global__ __launch_bounds__(256) void pool_kernel(const float* __restrict__ x,
                                                   unsigned short* __restrict__ plx,
                                                   float* __restrict__ wmx) {
  int np = blockIdx.x, c = threadIdx.x;
  int n = np / 49, p = np % 49, wr = p / 7, wc = p % 7;
  float tot = 0.f;
  for (int s = 0; s < 16; s++) {
    int i = s >> 2, j = s & 3;
    float a = 0.f;
    for (int di = 0; di < 2; di++)
      for (int dj = 0; dj < 2; dj++) {
        size_t t = ((size_t)n * 56 + wr * 8 + i * 2 + di) * 56 + wc * 8 + j * 2 + dj;
        a += x[t * 256 + c];
      }
    a *= 0.25f;
    plx[((size_t)np * 16 + s) * 256 + c] = f2bf(a);
    tot += a;
  }
  wmx[(size_t)np * 256 + c] = tot * (1.f / 16.f);
}

// ---------------- window-mean projection (f32): qkwin = wmx @ qkv_w[0:512]^T + b ----
__global__ __launch_bounds__(256) void winproj_kernel(const float* __restrict__ wmx,
                                                      const float* __restrict__ qkv_w,
                                                      const float* __restrict__ qkv_b,
                                                      float* __restrict__ qkwin) {
  int np = blockIdx.x, t = threadIdx.x;
  __shared__ float xs[256];
  xs[t] = wmx[(size_t)np * 256 + t];
  __syncthreads();
  for (int rep = 0; rep < 2; rep++) {
    int n = t + rep * 256;
    const float* wrow = qkv_w + (size_t)n * 256;
    float s = qkv_b[n];
    for (int c = 0; c < 256; c++) s += xs[c] * wrow[c];
    qkwin[(size_t)np * 512 + n] = s;
  }
}

// ---------------- routing logits + top-4 (set semantics) ----------------
__global__ __launch_bounds__(64) void topk_kernel(const float* __restrict__ qkwin,
                                                  int* __restrict__ idx) {
  int np = blockIdx.x;
  int n = np / 49;
  int j = threadIdx.x;
  __shared__ float lg[49];
  if (j < 49) {
    const float* qp = qkwin + (size_t)np * 512;
    const float* kp = qkwin + ((size_t)n * 49 + j) * 512 + 256;
    float s = 0.f;
    for (int c = 0; c < 256; c++) s += qp[c] * kp[c];
    lg[j] = s;
  }
  __syncthreads();
  if (j == 0) {
    unsigned long long used = 0ull;
    for (int t = 0; t < 4; t++) {
      float best = -INFINITY;
      int bi = 0;
      for (int q = 0; q < 49; q++)
        if (!((used >> q) & 1ull) && lg[q] > best) { best = lg[q]; bi = q; }
      idx[np * 4 + t] = bi;
      used |= (1ull << bi);
    }
  }
}

// ---------------- MFMA attention: one 64-lane wave per (window, head) ----------------
// QK^T: 16x mfma_16x16x32 (K=32=cph, Q/K frags loaded DIRECT from global).
// softmax: wave-parallel, rows in C-layout, shfl_xor reduce over 16-lane groups.
// PV: P->LDS (bf16, stride 72), V gathered transposed to LDS; 16x mfma.
__global__ __launch_bounds__(64) void attn_mfma(const unsigned short* __restrict__ qvb,
                                                const unsigned short* __restrict__ kvp,
                                                const int* __restrict__ idx,
                                                unsigned short* __restrict__ out) {
  __shared__ unsigned short Vt[32 * 72];   // Vt[c][k], stride 72 (144B rows)
  __shared__ unsigned short Pl[64 * 72];   // P[q][k], stride 72
  int bid = blockIdx.x;
  int head = bid & 7, np = bid >> 3;
  int n = np / 49, p = np % 49;
  int h0 = (p / 7) * 8, w0 = (p % 7) * 8;
  int lane = threadIdx.x;
  int lhi = lane >> 4, llo = lane & 15;

  int wi4[4];
#pragma unroll
  for (int t = 0; t < 4; t++) wi4[t] = idx[np * 4 + t];

  // ---- V gather -> Vt (transposed), coalesced 16B global loads ----
#pragma unroll
  for (int it = 0; it < 4; it++) {
    int cell = lane >> 2;              // 0..15 within routed window
    int chunk = lane & 3;              // 16B chunk of the 64B v-slice
    int s = it * 16 + cell;            // global kv row 0..63
    const unsigned short* g = kvp + ((size_t)(n * 49 + wi4[it]) * 16 + cell) * 512
                              + 256 + head * 32 + chunk * 8;
    unsigned short vv[8];
    __builtin_memcpy(vv, g, 16);
#pragma unroll
    for (int j = 0; j < 8; j++) Vt[(chunk * 8 + j) * 72 + s] = vv[j];
  }

  // ---- Q and K fragments direct from global ----
  bf16x8 qf[4], kf[4];
#pragma unroll
  for (int mi = 0; mi < 4; mi++) {
    int row = mi * 16 + llo;
    int h = h0 + (row >> 3), w = w0 + (row & 7);
    __builtin_memcpy(&qf[mi],
                     qvb + (((size_t)n * 56 + h) * 56 + w) * 512 + head * 32 + lhi * 8, 16);
  }
#pragma unroll
  for (int nj = 0; nj < 4; nj++) {
    __builtin_memcpy(&kf[nj],
                     kvp + ((size_t)(n * 49 + wi4[nj]) * 16 + llo) * 512 + head * 32 + lhi * 8,
                     16);
  }

  // ---- QK^T ----
  f32x4 acc[4][4];
#pragma unroll
  for (int mi = 0; mi < 4; mi++)
#pragma unroll
    for (int nj = 0; nj < 4; nj++) acc[mi][nj] = (f32x4){0.f, 0.f, 0.f, 0.f};
#pragma unroll
  for (int mi = 0; mi < 4; mi++)
#pragma unroll
    for (int nj = 0; nj < 4; nj++)
      acc[mi][nj] = __builtin_amdgcn_mfma_f32_16x16x32_bf16(qf[mi], kf[nj], acc[mi][nj], 0, 0, 0);

  // ---- wave-parallel softmax; S *= C^-0.5 (scale on logits == scaled q) ----
#pragma unroll
  for (int mi = 0; mi < 4; mi++)
#pragma unroll
    for (int nj = 0; nj < 4; nj++) acc[mi][nj] *= 0.0625f;
#pragma unroll
  for (int mi = 0; mi < 4; mi++) {
#pragma unroll
    for (int reg = 0; reg < 4; reg++) {
      float m = fmaxf(fmaxf(acc[mi][0][reg], acc[mi][1][reg]),
                      fmaxf(acc[mi][2][reg], acc[mi][3][reg]));
      m = fmaxf(m, __shfl_xor(m, 1));
      m = fmaxf(m, __shfl_xor(m, 2));
      m = fmaxf(m, __shfl_xor(m, 4));
      m = fmaxf(m, __shfl_xor(m, 8));
      float sum = 0.f;
#pragma unroll
      for (int nj = 0; nj < 4; nj++) {
        float e = __expf(acc[mi][nj][reg] - m);
        acc[mi][nj][reg] = e;
        sum += e;
      }
      sum += __shfl_xor(sum, 1);
      sum += __shfl_xor(sum, 2);
      sum += __shfl_xor(sum, 4);
      sum += __shfl_xor(sum, 8);
      float inv = 1.0f / sum;
#pragma unroll
      for (int nj = 0; nj < 4; nj++) acc[mi][nj][reg] *= inv;
    }
  }

  // ---- P -> LDS (row-major bf16) ----
#pragma unroll
  for (int mi = 0; mi < 4; mi++)
#pragma unroll
    for (int nj = 0; nj < 4; nj++)
#pragma unroll
      for (int reg = 0; reg < 4; reg++) {
        int row = mi * 16 + lhi * 4 + reg;
        Pl[row * 72 + nj * 16 + llo] = f2bf(acc[mi][nj][reg]);
      }

  // ---- PV ----
  f32x4 o[4][2];
#pragma unroll
  for (int mi = 0; mi < 4; mi++)
#pragma unroll
    for (int nc = 0; nc < 2; nc++) o[mi][nc] = (f32x4){0.f, 0.f, 0.f, 0.f};
#pragma unroll
  for (int ks = 0; ks < 2; ks++) {
    bf16x8 pa[4], vb[2];
#pragma unroll
    for (int mi = 0; mi < 4; mi++)
      __builtin_memcpy(&pa[mi], Pl + (mi * 16 + llo) * 72 + ks * 32 + lhi * 8, 16);
#pragma unroll
    for (int nc = 0; nc < 2; nc++)
      __builtin_memcpy(&vb[nc], Vt + (nc * 16 + llo) * 72 + ks * 32 + lhi * 8, 16);
#pragma unroll
    for (int mi = 0; mi < 4; mi++)
#pragma unroll
      for (int nc = 0; nc < 2; nc++)
        o[mi][nc] = __builtin_amdgcn_mfma_f32_16x16x32_bf16(pa[mi], vb[nc], o[mi][nc], 0, 0, 0);
  }

  // ---- write out (bf16) ----
#pragma unroll
  for (int mi = 0; mi < 4; mi++)
#pragma unroll
    for (int nc = 0; nc < 2; nc++)
#pragma unroll
      for (int reg = 0; reg < 4; reg++) {
        int row = mi * 16 + lhi * 4 + reg;
        int h = h0 + (row >> 3), w = w0 + (row & 7);
        out[(((size_t)n * 56 + h) * 56 + w) * 256 + head * 32 + nc * 16 + llo] =
            f2bf(o[mi][nc][reg]);
      }
}

// ---------------- 5x5 depthwise conv (lepe), RMW into attn out (bf16) ------------
__global__ __launch_bounds__(256) void lepe_kernel(const unsigned short* __restrict__ qvb,
                                                   const float* __restrict__ w,
                                                   const float* __restrict__ b,
                                                   unsigned short* __restrict__ out) {
  int t = blockIdx.x, c = threadIdx.x;
  int n = t / 3136, rem = t % 3136, h = rem / 56, ww = rem % 56;
  float acc = b[c];
  for (int dh = -2; dh <= 2; dh++) {
    int hh = h + dh;
    if ((unsigned)hh >= 56u) continue;
    for (int dw = -2; dw <= 2; dw++) {
      int wc = ww + dw;
      if ((unsigned)wc >= 56u) continue;
      acc += bf2f(qvb[(((size_t)n * 56 + hh) * 56 + wc) * 512 + 256 + c]) *
             w[((dh + 2) * 5 + (dw + 2)) * 256 + c];
    }
  }
  size_t o = (size_t)t * 256 + c;
  out[o] = f2bf(bf2f(out[o]) + acc);
}

// ---------------- launch ----------------
extern "C" void kernel_launch(void* const* d_in, const int* in_sizes, int n_in,
                              void* d_out, int out_size, void* d_ws, size_t ws_size,
                              hipStream_t stream) {
  const float* x      = (const float*)d_in[0];
  const float* pos_w  = (const float*)d_in[1];
  const float* pos_b  = (const float*)d_in[2];
  const float* ln1_g  = (const float*)d_in[3];
  const float* ln1_b  = (const float*)d_in[4];
  const float* ln2_g  = (const float*)d_in[5];
  const float* ln2_b  = (const float*)d_in[6];
  const float* qkv_w  = (const float*)d_in[7];
  const float* qkv_b  = (const float*)d_in[8];
  const float* wo_w   = (const float*)d_in[9];
  const float* wo_b   = (const float*)d_in[10];
  const float* lepe_w = (const float*)d_in[11];
  const float* lepe_b = (const float*)d_in[12];
  const float* fc1_w  = (const float*)d_in[13];
  const float* fc1_b  = (const float*)d_in[14];
  const float* fc2_w  = (const float*)d_in[15];
  const float* fc2_b  = (const float*)d_in[16];

  // d_out (TC f32 = 51.4 MB) timeline: xt -> ln1_f32 -> qvb(bf16) -> hbuf(bf16) -> final
  float*          xt   = (float*)d_out;
  float*          lnf  = (float*)d_out;
  unsigned short* qvb  = (unsigned short*)d_out;   // [TOK][512] bf16: q|v
  unsigned short* hbuf = (unsigned short*)d_out;   // [TOK][512] bf16 MLP hidden half

  // ws arena (~100 MB)
  float*          r2   = (float*)d_ws;                       // TC f32 residual
  float*          wmx  = r2 + TC;                            // 784x256 f32
  float*          qkw  = wmx + (size_t)784 * 256;            // 784x512 f32
  float*          bqv  = qkw + (size_t)784 * 512;            // 512 f32
  unsigned short* lnb  = (unsigned short*)(bqv + 512);       // [TOK][256] bf16 (-> aob -> ln2b)
  unsigned short* aob  = lnb;
  unsigned short* ln2b = lnb;
  unsigned short* plx  = lnb + TC;                           // [PTOK][256] bf16
  unsigned short* kvp  = plx + (size_t)PTOK * 256;           // [PTOK][512] bf16
  unsigned short* wqv  = kvp + (size_t)PTOK * 512;           // [512][256] bf16
  unsigned short* wkv  = wqv + (size_t)512 * 256;            // [512][256] bf16
  unsigned short* wwo  = wkv + (size_t)512 * 256;            // [256][256] bf16
  unsigned short* wfc1 = wwo + (size_t)256 * 256;            // [1024][256] bf16
  unsigned short* wfc2 = wfc1 + (size_t)1024 * 256;          // [256][1024] bf16
  int*            idx  = (int*)(wfc2 + (size_t)256 * 1024);  // 784x4

  // weight conversions (independent of data path)
  cvt_kernel<<<(65536 + 255) / 256, 256, 0, stream>>>(qkv_w, wqv, 65536);
  cvt_kernel<<<(65536 + 255) / 256, 256, 0, stream>>>(qkv_w + (size_t)512 * 256, wqv + 65536, 65536);
  cvt_kernel<<<(131072 + 255) / 256, 256, 0, stream>>>(qkv_w + (size_t)256 * 256, wkv, 131072);
  cvt_kernel<<<(65536 + 255) / 256, 256, 0, stream>>>(wo_w, wwo, 65536);
  cvt_kernel<<<(262144 + 255) / 256, 256, 0, stream>>>(fc1_w, wfc1, 262144);
  cvt_kernel<<<(262144 + 255) / 256, 256, 0, stream>>>(fc2_w, wfc2, 262144);
  bqv_kernel<<<1, 512, 0, stream>>>(qkv_b, bqv);

  dim3 tb(32, 8);
  nchw2nhwc<<<dim3(2, 8, NIMG * 56), tb, 0, stream>>>(x, xt);
  posconv_kernel<<<TOK, 256, 0, stream>>>(xt, pos_w, pos_b, r2);
  ln_kernel<<<TOK, 256, 0, stream>>>(r2, ln1_g, ln1_b, lnf, lnb);
  pool_kernel<<<784, 256, 0, stream>>>(lnf, plx, wmx);            // last reader of lnf
  // q|v projection: [TOK][512] bf16 (overwrites lnf region)
  mgemm<true><<<dim3(4, TOK / 128), 256, 0, stream>>>(lnb, 256, wqv, 256, bqv,
                                                      nullptr, qvb, 512, 256, 0);
  // pooled k|v projection: [PTOK][512] bf16
  mgemm<true><<<dim3(4, PTOK / 128), 256, 0, stream>>>(plx, 256, wkv, 256, qkv_b + 256,
                                                       nullptr, kvp, 512, 256, 0);
  winproj_kernel<<<784, 256, 0, stream>>>(wmx, qkv_w, qkv_b, qkw);
  topk_kernel<<<784, 64, 0, stream>>>(qkw, idx);
  attn_mfma<<<6272, 64, 0, stream>>>(qvb, kvp, idx, aob);
  lepe_kernel<<<TOK, 256, 0, stream>>>(qvb, lepe_w, lepe_b, aob);
  // wo projection + residual -> r2 (f32)
  mgemm<false><<<dim3(2, TOK / 128), 256, 0, stream>>>(aob, 256, wwo, 256, wo_b,
                                                       r2, r2, 256, 256, 2);
  ln_kernel<<<TOK, 256, 0, stream>>>(r2, ln2_g, ln2_b, nullptr, ln2b);
  // MLP: two hidden halves of 512 (hbuf overwrites dead qvb)
  mgemm<true><<<dim3(4, TOK / 128), 256, 0, stream>>>(ln2b, 256, wfc1, 256, fc1_b,
                                                      nullptr, hbuf, 512, 256, 1);
  mgemm<false><<<dim3(2, TOK / 128), 256, 0, stream>>>(hbuf, 512, wfc2, 1024, fc2_b,
                                                       r2, r2, 256, 512, 2);
  mgemm<true><<<dim3(4, TOK / 128), 256, 0, stream>>>(ln2b, 256, wfc1 + (size_t)512 * 256, 256,
                                                      fc1_b + 512, nullptr, hbuf, 512, 256, 1);
  mgemm<false><<<dim3(2, TOK / 128), 256, 0, stream>>>(hbuf, 512, wfc2 + 512, 1024, fc2_b,
                                                       r2, r2, 256, 512, 2 | 8);
  nhwc2nchw<<<dim3(2, 8, NIMG * 56), tb, 0, stream>>>(r2, (float*)d_out);
}

// Round 5
// 635.166 us; speedup vs baseline: 3.5205x; 1.3407x over previous
//
#include <hip/hip_runtime.h>
#include <math.h>

// ---------------- constants ----------------
static constexpr int NIMG = 16;
static constexpr int TOK  = NIMG * 56 * 56;          // 50176
static constexpr size_t TC = (size_t)TOK * 256;      // 12,845,056
static constexpr int PTOK = 784 * 16;                // 12544 pooled tokens

typedef __bf16 bf16x8 __attribute__((ext_vector_type(8)));
typedef float  f32x4  __attribute__((ext_vector_type(4)));

__device__ inline float bf2f(unsigned short u) {
  unsigned int i = ((unsigned int)u) << 16; float f; __builtin_memcpy(&f, &i, 4); return f;
}
__device__ inline unsigned short f2bf(float f) {
  unsigned int i; __builtin_memcpy(&i, &f, 4);
  unsigned int r = i + 0x7fffu + ((i >> 16) & 1u);
  return (unsigned short)(r >> 16);
}

// ---------------- transpose NCHW -> NHWC ----------------
__global__ __launch_bounds__(256) void nchw2nhwc(const float* __restrict__ x,
                                                 float* __restrict__ y) {
  __shared__ float tile[32][33];
  int nh = blockIdx.z;
  int n = nh / 56, h = nh % 56;
  int c0 = blockIdx.y * 32, w0 = blockIdx.x * 32;
  int tx = threadIdx.x, ty = threadIdx.y;
#pragma unroll
  for (int i = 0; i < 4; i++) {
    int c = c0 + ty + i * 8, w = w0 + tx;
    if (w < 56) tile[ty + i * 8][tx] = x[(((size_t)n * 256 + c) * 56 + h) * 56 + w];
  }
  __syncthreads();
#pragma unroll
  for (int i = 0; i < 4; i++) {
    int w = w0 + ty + i * 8, c = c0 + tx;
    if (w < 56) y[(((size_t)n * 56 + h) * 56 + w) * 256 + c] = tile[tx][ty + i * 8];
  }
}

// ---------------- transpose NHWC -> NCHW ----------------
__global__ __launch_bounds__(256) void nhwc2nchw(const float* __restrict__ y,
                                                 float* __restrict__ o) {
  __shared__ float tile[32][33];
  int nh = blockIdx.z;
  int n = nh / 56, h = nh % 56;
  int w0 = blockIdx.x * 32, c0 = blockIdx.y * 32;
  int tx = threadIdx.x, ty = threadIdx.y;
#pragma unroll
  for (int i = 0; i < 4; i++) {
    int w = w0 + ty + i * 8, c = c0 + tx;
    if (w < 56) tile[ty + i * 8][tx] = y[(((size_t)n * 56 + h) * 56 + w) * 256 + c];
  }
  __syncthreads();
#pragma unroll
  for (int i = 0; i < 4; i++) {
    int c = c0 + ty + i * 8, w = w0 + tx;
    if (w < 56) o[(((size_t)n * 256 + c) * 56 + h) * 56 + w] = tile[tx][ty + i * 8];
  }
}

// ---------------- 3x3 depthwise conv residual, wave/pixel, float4/lane ----------
__global__ __launch_bounds__(256) void posconv_kernel(const float* __restrict__ xt,
                                                      const float* __restrict__ w,
                                                      const float* __restrict__ b,
                                                      float* __restrict__ xh) {
  int t = blockIdx.x * 4 + (threadIdx.x >> 6);
  int lane = threadIdx.x & 63;
  int c = lane * 4;
  int n = t / 3136, rem = t % 3136, h = rem / 56, ww = rem % 56;
  f32x4 acc = *(const f32x4*)&b[c];
  for (int dh = -1; dh <= 1; dh++) {
    int hh = h + dh;
    if ((unsigned)hh >= 56u) continue;
    for (int dw = -1; dw <= 1; dw++) {
      int wc = ww + dw;
      if ((unsigned)wc >= 56u) continue;
      f32x4 xx = *(const f32x4*)&xt[(((size_t)n * 56 + hh) * 56 + wc) * 256 + c];
      f32x4 wv = *(const f32x4*)&w[((dh + 1) * 3 + (dw + 1)) * 256 + c];
      acc += xx * wv;
    }
  }
  f32x4 xv = *(const f32x4*)&xt[(size_t)t * 256 + c];
  *(f32x4*)&xh[(size_t)t * 256 + c] = xv + acc;
}

// ---------------- LayerNorm, wave/token, float4/lane, shfl reduce ---------------
__global__ __launch_bounds__(256) void lnw_kernel(const float* __restrict__ x,
                                                  const float* __restrict__ g,
                                                  const float* __restrict__ b,
                                                  float* __restrict__ of,
                                                  unsigned short* __restrict__ ob) {
  int t = blockIdx.x * 4 + (threadIdx.x >> 6);
  int lane = threadIdx.x & 63;
  int c = lane * 4;
  f32x4 v = *(const f32x4*)&x[(size_t)t * 256 + c];
  float s = v[0] + v[1] + v[2] + v[3];
#pragma unroll
  for (int m = 1; m < 64; m <<= 1) s += __shfl_xor(s, m);
  float mu = s * (1.f / 256.f);
  f32x4 d = v - mu;
  float ss = d[0] * d[0] + d[1] * d[1] + d[2] * d[2] + d[3] * d[3];
#pragma unroll
  for (int m = 1; m < 64; m <<= 1) ss += __shfl_xor(ss, m);
  float rs = rsqrtf(ss * (1.f / 256.f) + 1e-6f);
  f32x4 gg = *(const f32x4*)&g[c];
  f32x4 bb = *(const f32x4*)&b[c];
  f32x4 y = d * rs * gg + bb;
  if (of) *(f32x4*)&of[(size_t)t * 256 + c] = y;
  if (ob) {
    unsigned short yb[4];
#pragma unroll
    for (int j = 0; j < 4; j++) yb[j] = f2bf(y[j]);
    __builtin_memcpy(ob + (size_t)t * 256 + c, yb, 8);
  }
}

// ---------------- MFMA bf16 GEMM: C[M][N] = A[M][lda] * B[N][ldb]^T ----------------
// 128x128 tile, BK=64, 4 waves, global_load_lds staging with source-side XOR swizzle.
// flags: 1 = exact GELU, 2 = += R (f32, ld=N), 8 = skip bias
template <bool OUTBF>
__global__ __launch_bounds__(256) void mgemm(const unsigned short* __restrict__ A, int lda,
                                             const unsigned short* __restrict__ B, int ldb,
                                             const float* __restrict__ bias,
                                             const float* __restrict__ R,
                                             void* __restrict__ C_,
                                             int N, int K, int flags) {
  __shared__ unsigned short As[128 * 64];
  __shared__ unsigned short Bs[128 * 64];
  int tid = threadIdx.x;
  int m0 = blockIdx.y * 128, n0 = blockIdx.x * 128;
  int lane = tid & 63, wid = tid >> 6;
  int wr = (wid >> 1) * 64, wc = (wid & 1) * 64;

  f32x4 acc[4][4];
#pragma unroll
  for (int i = 0; i < 4; i++)
#pragma unroll
    for (int j = 0; j < 4; j++) acc[i][j] = (f32x4){0.f, 0.f, 0.f, 0.f};

  int grow[4], gcol[4];
#pragma unroll
  for (int i = 0; i < 4; i++) {
    int q = tid + 256 * i;
    grow[i] = q >> 3;
    gcol[i] = (q & 7) ^ (grow[i] & 7);
  }

  for (int k0 = 0; k0 < K; k0 += 64) {
#pragma unroll
    for (int i = 0; i < 4; i++) {
      int q = tid + 256 * i;
      const unsigned short* ga = A + (size_t)(m0 + grow[i]) * lda + k0 + gcol[i] * 8;
      const unsigned short* gb = B + (size_t)(n0 + grow[i]) * ldb + k0 + gcol[i] * 8;
      __builtin_amdgcn_global_load_lds(
          (const __attribute__((address_space(1))) unsigned int*)ga,
          (__attribute__((address_space(3))) unsigned int*)(As + q * 8), 16, 0, 0);
      __builtin_amdgcn_global_load_lds(
          (const __attribute__((address_space(1))) unsigned int*)gb,
          (__attribute__((address_space(3))) unsigned int*)(Bs + q * 8), 16, 0, 0);
    }
    __syncthreads();
#pragma unroll
    for (int ks = 0; ks < 2; ks++) {
      int cchunk = ks * 4 + (lane >> 4);
      bf16x8 af[4], bfr[4];
#pragma unroll
      for (int mi = 0; mi < 4; mi++) {
        int r = wr + mi * 16 + (lane & 15);
        __builtin_memcpy(&af[mi], As + (size_t)r * 64 + (cchunk ^ (r & 7)) * 8, 16);
      }
#pragma unroll
      for (int nj = 0; nj < 4; nj++) {
        int r = wc + nj * 16 + (lane & 15);
        __builtin_memcpy(&bfr[nj], Bs + (size_t)r * 64 + (cchunk ^ (r & 7)) * 8, 16);
      }
#pragma unroll
      for (int mi = 0; mi < 4; mi++)
#pragma unroll
        for (int nj = 0; nj < 4; nj++)
          acc[mi][nj] = __builtin_amdgcn_mfma_f32_16x16x32_bf16(af[mi], bfr[nj],
                                                                acc[mi][nj], 0, 0, 0);
    }
    __syncthreads();
  }

  int coln = lane & 15, rowg = (lane >> 4) * 4;
#pragma unroll
  for (int mi = 0; mi < 4; mi++) {
#pragma unroll
    for (int nj = 0; nj < 4; nj++) {
      int n = n0 + wc + nj * 16 + coln;
      float bv = (flags & 8) ? 0.f : bias[n];
#pragma unroll
      for (int j = 0; j < 4; j++) {
        int m = m0 + wr + mi * 16 + rowg + j;
        float v = acc[mi][nj][j] + bv;
        if (flags & 1) v = 0.5f * v * (1.0f + erff(v * 0.70710678118654752f));
        if (flags & 2) v += R[(size_t)m * N + n];
        if (OUTBF) ((unsigned short*)C_)[(size_t)m * N + n] = f2bf(v);
        else       ((float*)C_)[(size_t)m * N + n] = v;
      }
    }
  }
}

// ---------------- f32 -> bf16 flat convert ----------------
__global__ __launch_bounds__(256) void cvt_kernel(const float* __restrict__ s,
                                                  unsigned short* __restrict__ d, int n) {
  int i = blockIdx.x * 256 + threadIdx.x;
  if (i < n) d[i] = f2bf(s[i]);
}

// ---------------- pack qv bias ----------------
__global__ __launch_bounds__(512) void bqv_kernel(const float* __restrict__ qkv_b,
                                                  float* __restrict__ bqv) {
  int i = threadIdx.x;
  bqv[i] = qkv_b[i < 256 ? i : i + 256];
}

// ---------------- pool LN1 (f32 in): 2x2 cell means (bf16) + window means (f32) ----
__global__ __launch_bounds__(256) void pool_kernel(const float* __restrict__ x,
                                                   unsigned short* __restrict__ plx,
                                                   float* __restrict__ wmx) {
  int np = blockIdx.x, c = threadIdx.x;
  int n = np / 49, p = np % 49, wr = p / 7, wc = p % 7;
  float tot = 0.f;
  for (int s = 0; s < 16; s++) {
    int i = s >> 2, j = s & 3;
    float a = 0.f;
    for (int di = 0; di < 2; di++)
      for (int dj = 0; dj < 2; dj++) {
        size_t t = ((size_t)n * 56 + wr * 8 + i * 2 + di) * 56 + wc * 8 + j * 2 + dj;
        a += x[t * 256 + c];
      }
    a *= 0.25f;
    plx[((size_t)np * 16 + s) * 256 + c] = f2bf(a);
    tot += a;
  }
  wmx[(size_t)np * 256 + c] = tot * (1.f / 16.f);
}

// ---------------- window-mean projection (f32): qkwin = wmx @ qkv_w[0:512]^T + b ----
__global__ __launch_bounds__(256) void winproj_kernel(const float* __restrict__ wmx,
                                                      const float* __restrict__ qkv_w,
                                                      const float* __restrict__ qkv_b,
                                                      float* __restrict__ qkwin) {
  int np = blockIdx.x, t = threadIdx.x;
  __shared__ float xs[256];
  xs[t] = wmx[(size_t)np * 256 + t];
  __syncthreads();
  for (int rep = 0; rep < 2; rep++) {
    int n = t + rep * 256;
    const float* wrow = qkv_w + (size_t)n * 256;
    float s = qkv_b[n];
    for (int c = 0; c < 256; c++) s += xs[c] * wrow[c];
    qkwin[(size_t)np * 512 + n] = s;
  }
}

// ---------------- routing logits + top-4 (set semantics) ----------------
__global__ __launch_bounds__(64) void topk_kernel(const float* __restrict__ qkwin,
                                                  int* __restrict__ idx) {
  int np = blockIdx.x;
  int n = np / 49;
  int j = threadIdx.x;
  __shared__ float lg[49];
  if (j < 49) {
    const float* qp = qkwin + (size_t)np * 512;
    const float* kp = qkwin + ((size_t)n * 49 + j) * 512 + 256;
    float s = 0.f;
    for (int c = 0; c < 256; c++) s += qp[c] * kp[c];
    lg[j] = s;
  }
  __syncthreads();
  if (j == 0) {
    unsigned long long used = 0ull;
    for (int t = 0; t < 4; t++) {
      float best = -INFINITY;
      int bi = 0;
      for (int q = 0; q < 49; q++)
        if (!((used >> q) & 1ull) && lg[q] > best) { best = lg[q]; bi = q; }
      idx[np * 4 + t] = bi;
      used |= (1ull << bi);
    }
  }
}

// ---------------- MFMA attention: one 64-lane wave per (window, head) ----------------
__global__ __launch_bounds__(64) void attn_mfma(const unsigned short* __restrict__ qvb,
                                                const unsigned short* __restrict__ kvp,
                                                const int* __restrict__ idx,
                                                unsigned short* __restrict__ out) {
  __shared__ unsigned short Vt[32 * 72];   // Vt[c][k], stride 72 (144B rows)
  __shared__ unsigned short Pl[64 * 72];   // P[q][k], stride 72
  int bid = blockIdx.x;
  int head = bid & 7, np = bid >> 3;
  int n = np / 49, p = np % 49;
  int h0 = (p / 7) * 8, w0 = (p % 7) * 8;
  int lane = threadIdx.x;
  int lhi = lane >> 4, llo = lane & 15;

  int wi4[4];
#pragma unroll
  for (int t = 0; t < 4; t++) wi4[t] = idx[np * 4 + t];

#pragma unroll
  for (int it = 0; it < 4; it++) {
    int cell = lane >> 2;
    int chunk = lane & 3;
    int s = it * 16 + cell;
    const unsigned short* g = kvp + ((size_t)(n * 49 + wi4[it]) * 16 + cell) * 512
                              + 256 + head * 32 + chunk * 8;
    unsigned short vv[8];
    __builtin_memcpy(vv, g, 16);
#pragma unroll
    for (int j = 0; j < 8; j++) Vt[(chunk * 8 + j) * 72 + s] = vv[j];
  }

  bf16x8 qf[4], kf[4];
#pragma unroll
  for (int mi = 0; mi < 4; mi++) {
    int row = mi * 16 + llo;
    int h = h0 + (row >> 3), w = w0 + (row & 7);
    __builtin_memcpy(&qf[mi],
                     qvb + (((size_t)n * 56 + h) * 56 + w) * 512 + head * 32 + lhi * 8, 16);
  }
#pragma unroll
  for (int nj = 0; nj < 4; nj++) {
    __builtin_memcpy(&kf[nj],
                     kvp + ((size_t)(n * 49 + wi4[nj]) * 16 + llo) * 512 + head * 32 + lhi * 8,
                     16);
  }

  f32x4 acc[4][4];
#pragma unroll
  for (int mi = 0; mi < 4; mi++)
#pragma unroll
    for (int nj = 0; nj < 4; nj++) acc[mi][nj] = (f32x4){0.f, 0.f, 0.f, 0.f};
#pragma unroll
  for (int mi = 0; mi < 4; mi++)
#pragma unroll
    for (int nj = 0; nj < 4; nj++)
      acc[mi][nj] = __builtin_amdgcn_mfma_f32_16x16x32_bf16(qf[mi], kf[nj], acc[mi][nj], 0, 0, 0);

#pragma unroll
  for (int mi = 0; mi < 4; mi++)
#pragma unroll
    for (int nj = 0; nj < 4; nj++) acc[mi][nj] *= 0.0625f;
#pragma unroll
  for (int mi = 0; mi < 4; mi++) {
#pragma unroll
    for (int reg = 0; reg < 4; reg++) {
      float m = fmaxf(fmaxf(acc[mi][0][reg], acc[mi][1][reg]),
                      fmaxf(acc[mi][2][reg], acc[mi][3][reg]));
      m = fmaxf(m, __shfl_xor(m, 1));
      m = fmaxf(m, __shfl_xor(m, 2));
      m = fmaxf(m, __shfl_xor(m, 4));
      m = fmaxf(m, __shfl_xor(m, 8));
      float sum = 0.f;
#pragma unroll
      for (int nj = 0; nj < 4; nj++) {
        float e = __expf(acc[mi][nj][reg] - m);
        acc[mi][nj][reg] = e;
        sum += e;
      }
      sum += __shfl_xor(sum, 1);
      sum += __shfl_xor(sum, 2);
      sum += __shfl_xor(sum, 4);
      sum += __shfl_xor(sum, 8);
      float inv = 1.0f / sum;
#pragma unroll
      for (int nj = 0; nj < 4; nj++) acc[mi][nj][reg] *= inv;
    }
  }

#pragma unroll
  for (int mi = 0; mi < 4; mi++)
#pragma unroll
    for (int nj = 0; nj < 4; nj++)
#pragma unroll
      for (int reg = 0; reg < 4; reg++) {
        int row = mi * 16 + lhi * 4 + reg;
        Pl[row * 72 + nj * 16 + llo] = f2bf(acc[mi][nj][reg]);
      }

  f32x4 o[4][2];
#pragma unroll
  for (int mi = 0; mi < 4; mi++)
#pragma unroll
    for (int nc = 0; nc < 2; nc++) o[mi][nc] = (f32x4){0.f, 0.f, 0.f, 0.f};
#pragma unroll
  for (int ks = 0; ks < 2; ks++) {
    bf16x8 pa[4], vb[2];
#pragma unroll
    for (int mi = 0; mi < 4; mi++)
      __builtin_memcpy(&pa[mi], Pl + (mi * 16 + llo) * 72 + ks * 32 + lhi * 8, 16);
#pragma unroll
    for (int nc = 0; nc < 2; nc++)
      __builtin_memcpy(&vb[nc], Vt + (nc * 16 + llo) * 72 + ks * 32 + lhi * 8, 16);
#pragma unroll
    for (int mi = 0; mi < 4; mi++)
#pragma unroll
      for (int nc = 0; nc < 2; nc++)
        o[mi][nc] = __builtin_amdgcn_mfma_f32_16x16x32_bf16(pa[mi], vb[nc], o[mi][nc], 0, 0, 0);
  }

#pragma unroll
  for (int mi = 0; mi < 4; mi++)
#pragma unroll
    for (int nc = 0; nc < 2; nc++)
#pragma unroll
      for (int reg = 0; reg < 4; reg++) {
        int row = mi * 16 + lhi * 4 + reg;
        int h = h0 + (row >> 3), w = w0 + (row & 7);
        out[(((size_t)n * 56 + h) * 56 + w) * 256 + head * 32 + nc * 16 + llo] =
            f2bf(o[mi][nc][reg]);
      }
}

// ---------------- 5x5 depthwise conv (lepe), 8ch/thread bf16x8, RMW ------------
__global__ __launch_bounds__(256) void lepe_kernel(const unsigned short* __restrict__ qvb,
                                                   const float* __restrict__ w,
                                                   const float* __restrict__ b,
                                                   unsigned short* __restrict__ out) {
  int t = blockIdx.x * 8 + (threadIdx.x >> 5);
  int cg = threadIdx.x & 31;         // channel group, c = cg*8
  int c = cg * 8;
  int n = t / 3136, rem = t % 3136, h = rem / 56, ww = rem % 56;
  float acc[8];
#pragma unroll
  for (int j = 0; j < 8; j++) acc[j] = b[c + j];
  for (int dh = -2; dh <= 2; dh++) {
    int hh = h + dh;
    if ((unsigned)hh >= 56u) continue;
    for (int dw = -2; dw <= 2; dw++) {
      int wc = ww + dw;
      if ((unsigned)wc >= 56u) continue;
      unsigned short vv[8];
      __builtin_memcpy(vv, qvb + (((size_t)n * 56 + hh) * 56 + wc) * 512 + 256 + c, 16);
      const float* wp = w + ((dh + 2) * 5 + (dw + 2)) * 256 + c;
#pragma unroll
      for (int j = 0; j < 8; j++) acc[j] += bf2f(vv[j]) * wp[j];
    }
  }
  size_t o = (size_t)t * 256 + c;
  unsigned short ov[8];
  __builtin_memcpy(ov, out + o, 16);
#pragma unroll
  for (int j = 0; j < 8; j++) ov[j] = f2bf(bf2f(ov[j]) + acc[j]);
  __builtin_memcpy(out + o, ov, 16);
}

// ---------------- launch ----------------
extern "C" void kernel_launch(void* const* d_in, const int* in_sizes, int n_in,
                              void* d_out, int out_size, void* d_ws, size_t ws_size,
                              hipStream_t stream) {
  const float* x      = (const float*)d_in[0];
  const float* pos_w  = (const float*)d_in[1];
  const float* pos_b  = (const float*)d_in[2];
  const float* ln1_g  = (const float*)d_in[3];
  const float* ln1_b  = (const float*)d_in[4];
  const float* ln2_g  = (const float*)d_in[5];
  const float* ln2_b  = (const float*)d_in[6];
  const float* qkv_w  = (const float*)d_in[7];
  const float* qkv_b  = (const float*)d_in[8];
  const float* wo_w   = (const float*)d_in[9];
  const float* wo_b   = (const float*)d_in[10];
  const float* lepe_w = (const float*)d_in[11];
  const float* lepe_b = (const float*)d_in[12];
  const float* fc1_w  = (const float*)d_in[13];
  const float* fc1_b  = (const float*)d_in[14];
  const float* fc2_w  = (const float*)d_in[15];
  const float* fc2_b  = (const float*)d_in[16];

  // d_out (TC f32 = 51.4 MB) timeline: xt -> ln1_f32 -> qvb(bf16) -> hbuf(bf16) -> final
  float*          xt   = (float*)d_out;
  float*          lnf  = (float*)d_out;
  unsigned short* qvb  = (unsigned short*)d_out;   // [TOK][512] bf16: q|v
  unsigned short* hbuf = (unsigned short*)d_out;   // [TOK][512] bf16 MLP hidden half

  // ws arena (~100 MB)
  float*          r2   = (float*)d_ws;                       // TC f32 residual
  float*          wmx  = r2 + TC;                            // 784x256 f32
  float*          qkw  = wmx + (size_t)784 * 256;            // 784x512 f32
  float*          bqv  = qkw + (size_t)784 * 512;            // 512 f32
  unsigned short* lnb  = (unsigned short*)(bqv + 512);       // [TOK][256] bf16 (-> aob -> ln2b)
  unsigned short* aob  = lnb;
  unsigned short* ln2b = lnb;
  unsigned short* plx  = lnb + TC;                           // [PTOK][256] bf16
  unsigned short* kvp  = plx + (size_t)PTOK * 256;           // [PTOK][512] bf16
  unsigned short* wqv  = kvp + (size_t)PTOK * 512;           // [512][256] bf16
  unsigned short* wkv  = wqv + (size_t)512 * 256;            // [512][256] bf16
  unsigned short* wwo  = wkv + (size_t)512 * 256;            // [256][256] bf16
  unsigned short* wfc1 = wwo + (size_t)256 * 256;            // [1024][256] bf16
  unsigned short* wfc2 = wfc1 + (size_t)1024 * 256;          // [256][1024] bf16
  int*            idx  = (int*)(wfc2 + (size_t)256 * 1024);  // 784x4

  // weight conversions (independent of data path)
  cvt_kernel<<<(65536 + 255) / 256, 256, 0, stream>>>(qkv_w, wqv, 65536);
  cvt_kernel<<<(65536 + 255) / 256, 256, 0, stream>>>(qkv_w + (size_t)512 * 256, wqv + 65536, 65536);
  cvt_kernel<<<(131072 + 255) / 256, 256, 0, stream>>>(qkv_w + (size_t)256 * 256, wkv, 131072);
  cvt_kernel<<<(65536 + 255) / 256, 256, 0, stream>>>(wo_w, wwo, 65536);
  cvt_kernel<<<(262144 + 255) / 256, 256, 0, stream>>>(fc1_w, wfc1, 262144);
  cvt_kernel<<<(262144 + 255) / 256, 256, 0, stream>>>(fc2_w, wfc2, 262144);
  bqv_kernel<<<1, 512, 0, stream>>>(qkv_b, bqv);

  dim3 tb(32, 8);
  nchw2nhwc<<<dim3(2, 8, NIMG * 56), tb, 0, stream>>>(x, xt);
  posconv_kernel<<<TOK / 4, 256, 0, stream>>>(xt, pos_w, pos_b, r2);
  lnw_kernel<<<TOK / 4, 256, 0, stream>>>(r2, ln1_g, ln1_b, lnf, lnb);
  pool_kernel<<<784, 256, 0, stream>>>(lnf, plx, wmx);            // last reader of lnf
  // q|v projection: [TOK][512] bf16 (overwrites lnf region)
  mgemm<true><<<dim3(4, TOK / 128), 256, 0, stream>>>(lnb, 256, wqv, 256, bqv,
                                                      nullptr, qvb, 512, 256, 0);
  // pooled k|v projection: [PTOK][512] bf16
  mgemm<true><<<dim3(4, PTOK / 128), 256, 0, stream>>>(plx, 256, wkv, 256, qkv_b + 256,
                                                       nullptr, kvp, 512, 256, 0);
  winproj_kernel<<<784, 256, 0, stream>>>(wmx, qkv_w, qkv_b, qkw);
  topk_kernel<<<784, 64, 0, stream>>>(qkw, idx);
  attn_mfma<<<6272, 64, 0, stream>>>(qvb, kvp, idx, aob);
  lepe_kernel<<<TOK / 8, 256, 0, stream>>>(qvb, lepe_w, lepe_b, aob);
  // wo projection + residual -> r2 (f32)
  mgemm<false><<<dim3(2, TOK / 128), 256, 0, stream>>>(aob, 256, wwo, 256, wo_b,
                                                       r2, r2, 256, 256, 2);
  lnw_kernel<<<TOK / 4, 256, 0, stream>>>(r2, ln2_g, ln2_b, nullptr, ln2b);
  // MLP: two hidden halves of 512 (hbuf overwrites dead qvb)
  mgemm<true><<<dim3(4, TOK / 128), 256, 0, stream>>>(ln2b, 256, wfc1, 256, fc1_b,
                                                      nullptr, hbuf, 512, 256, 1);
  mgemm<false><<<dim3(2, TOK / 128), 256, 0, stream>>>(hbuf, 512, wfc2, 1024, fc2_b,
                                                       r2, r2, 256, 512, 2);
  mgemm<true><<<dim3(4, TOK / 128), 256, 0, stream>>>(ln2b, 256, wfc1 + (size_t)512 * 256, 256,
                                                      fc1_b + 512, nullptr, hbuf, 512, 256, 1);
  mgemm<false><<<dim3(2, TOK / 128), 256, 0, stream>>>(hbuf, 512, wfc2 + 512, 1024, fc2_b,
                                                       r2, r2, 256, 512, 2 | 8);
  nhwc2nchw<<<dim3(2, 8, NIMG * 56), tb, 0, stream>>>(r2, (float*)d_out);
}

// Round 6
// 527.764 us; speedup vs baseline: 4.2369x; 1.2035x over previous
//
#include <hip/hip_runtime.h>
#include <math.h>

// ---------------- constants ----------------
static constexpr int NIMG = 16;
static constexpr int TOK  = NIMG * 56 * 56;          // 50176
static constexpr size_t TC = (size_t)TOK * 256;      // 12,845,056
static constexpr int PTOK = 784 * 16;                // 12544 pooled tokens

typedef __bf16 bf16x8 __attribute__((ext_vector_type(8)));
typedef float  f32x4  __attribute__((ext_vector_type(4)));

__device__ inline float bf2f(unsigned short u) {
  unsigned int i = ((unsigned int)u) << 16; float f; __builtin_memcpy(&f, &i, 4); return f;
}
__device__ inline unsigned short f2bf(float f) {
  unsigned int i; __builtin_memcpy(&i, &f, 4);
  unsigned int r = i + 0x7fffu + ((i >> 16) & 1u);
  return (unsigned short)(r >> 16);
}

// ---------------- transpose NCHW -> NHWC ----------------
__global__ __launch_bounds__(256) void nchw2nhwc(const float* __restrict__ x,
                                                 float* __restrict__ y) {
  __shared__ float tile[32][33];
  int nh = blockIdx.z;
  int n = nh / 56, h = nh % 56;
  int c0 = blockIdx.y * 32, w0 = blockIdx.x * 32;
  int tx = threadIdx.x, ty = threadIdx.y;
#pragma unroll
  for (int i = 0; i < 4; i++) {
    int c = c0 + ty + i * 8, w = w0 + tx;
    if (w < 56) tile[ty + i * 8][tx] = x[(((size_t)n * 256 + c) * 56 + h) * 56 + w];
  }
  __syncthreads();
#pragma unroll
  for (int i = 0; i < 4; i++) {
    int w = w0 + ty + i * 8, c = c0 + tx;
    if (w < 56) y[(((size_t)n * 56 + h) * 56 + w) * 256 + c] = tile[tx][ty + i * 8];
  }
}

// ---------------- transpose NHWC -> NCHW ----------------
__global__ __launch_bounds__(256) void nhwc2nchw(const float* __restrict__ y,
                                                 float* __restrict__ o) {
  __shared__ float tile[32][33];
  int nh = blockIdx.z;
  int n = nh / 56, h = nh % 56;
  int w0 = blockIdx.x * 32, c0 = blockIdx.y * 32;
  int tx = threadIdx.x, ty = threadIdx.y;
#pragma unroll
  for (int i = 0; i < 4; i++) {
    int w = w0 + ty + i * 8, c = c0 + tx;
    if (w < 56) tile[ty + i * 8][tx] = y[(((size_t)n * 56 + h) * 56 + w) * 256 + c];
  }
  __syncthreads();
#pragma unroll
  for (int i = 0; i < 4; i++) {
    int c = c0 + ty + i * 8, w = w0 + tx;
    if (w < 56) o[(((size_t)n * 256 + c) * 56 + h) * 56 + w] = tile[tx][ty + i * 8];
  }
}

// ---------------- 3x3 depthwise conv residual, wave/pixel, float4/lane ----------
__global__ __launch_bounds__(256) void posconv_kernel(const float* __restrict__ xt,
                                                      const float* __restrict__ w,
                                                      const float* __restrict__ b,
                                                      float* __restrict__ xh) {
  int t = blockIdx.x * 4 + (threadIdx.x >> 6);
  int lane = threadIdx.x & 63;
  int c = lane * 4;
  int n = t / 3136, rem = t % 3136, h = rem / 56, ww = rem % 56;
  f32x4 acc = *(const f32x4*)&b[c];
  for (int dh = -1; dh <= 1; dh++) {
    int hh = h + dh;
    if ((unsigned)hh >= 56u) continue;
    for (int dw = -1; dw <= 1; dw++) {
      int wc = ww + dw;
      if ((unsigned)wc >= 56u) continue;
      f32x4 xx = *(const f32x4*)&xt[(((size_t)n * 56 + hh) * 56 + wc) * 256 + c];
      f32x4 wv = *(const f32x4*)&w[((dh + 1) * 3 + (dw + 1)) * 256 + c];
      acc += xx * wv;
    }
  }
  f32x4 xv = *(const f32x4*)&xt[(size_t)t * 256 + c];
  *(f32x4*)&xh[(size_t)t * 256 + c] = xv + acc;
}

// ---------------- LayerNorm, wave/token, float4/lane, shfl reduce ---------------
__global__ __launch_bounds__(256) void lnw_kernel(const float* __restrict__ x,
                                                  const float* __restrict__ g,
                                                  const float* __restrict__ b,
                                                  float* __restrict__ of,
                                                  unsigned short* __restrict__ ob) {
  int t = blockIdx.x * 4 + (threadIdx.x >> 6);
  int lane = threadIdx.x & 63;
  int c = lane * 4;
  f32x4 v = *(const f32x4*)&x[(size_t)t * 256 + c];
  float s = v[0] + v[1] + v[2] + v[3];
#pragma unroll
  for (int m = 1; m < 64; m <<= 1) s += __shfl_xor(s, m);
  float mu = s * (1.f / 256.f);
  f32x4 d = v - mu;
  float ss = d[0] * d[0] + d[1] * d[1] + d[2] * d[2] + d[3] * d[3];
#pragma unroll
  for (int m = 1; m < 64; m <<= 1) ss += __shfl_xor(ss, m);
  float rs = rsqrtf(ss * (1.f / 256.f) + 1e-6f);
  f32x4 gg = *(const f32x4*)&g[c];
  f32x4 bb = *(const f32x4*)&b[c];
  f32x4 y = d * rs * gg + bb;
  if (of) *(f32x4*)&of[(size_t)t * 256 + c] = y;
  if (ob) {
    unsigned short yb[4];
#pragma unroll
    for (int j = 0; j < 4; j++) yb[j] = f2bf(y[j]);
    __builtin_memcpy(ob + (size_t)t * 256 + c, yb, 8);
  }
}

// ---------------- MFMA bf16 GEMM v2: C[M][N] = A[M][lda] * B[N][ldb]^T -------------
// BM=128, BN=256, BK=64, 512 threads (8 waves, 2x4), 1-D grid with bijective XCD
// chunking (n fastest within chunk -> A-slab per XCD fits L2).
// flags: 1 = exact GELU, 2 = += R (f32, ld=N), 8 = skip bias
// LN2F: fused LayerNorm epilogue (requires N == 256, gx == 1, flags&2):
//   writes v (pre-LN, f32) to C_ and LN(v) (bf16) to ob2.
template <bool OUTBF, bool LN2F>
__global__ __launch_bounds__(512, 4) void mgemm2(const unsigned short* __restrict__ A, int lda,
                                                 const unsigned short* __restrict__ B, int ldb,
                                                 const float* __restrict__ bias,
                                                 const float* __restrict__ R,
                                                 void* __restrict__ C_,
                                                 int N, int K, int flags, int gx,
                                                 const float* __restrict__ g2,
                                                 const float* __restrict__ b2,
                                                 unsigned short* __restrict__ ob2) {
  __shared__ unsigned short As[128 * 64];
  __shared__ unsigned short Bs[256 * 64];
  __shared__ float redS[4][128];
  __shared__ float redQ[4][128];
  int tid = threadIdx.x;
  int nwg = gridDim.x, bid = blockIdx.x;
  int q8 = nwg >> 3, r8 = nwg & 7;
  int xcd = bid & 7, pos = bid >> 3;
  int wgid = (xcd < r8 ? xcd * (q8 + 1) : r8 * (q8 + 1) + (xcd - r8) * q8) + pos;
  int m0 = (wgid / gx) * 128;
  int n0 = (wgid % gx) * 256;

  int lane = tid & 63, wid = tid >> 6;
  int wr = (wid >> 2) * 64, wc = (wid & 3) * 64;
  int llo = lane & 15, lhi = lane >> 4;

  f32x4 acc[4][4];
#pragma unroll
  for (int i = 0; i < 4; i++)
#pragma unroll
    for (int j = 0; j < 4; j++) acc[i][j] = (f32x4){0.f, 0.f, 0.f, 0.f};

  for (int k0 = 0; k0 < K; k0 += 64) {
#pragma unroll
    for (int i = 0; i < 2; i++) {
      int qa = tid + 512 * i;
      int row = qa >> 3, col = (qa & 7) ^ (row & 7);
      __builtin_amdgcn_global_load_lds(
          (const __attribute__((address_space(1))) unsigned int*)
              (A + (size_t)(m0 + row) * lda + k0 + col * 8),
          (__attribute__((address_space(3))) unsigned int*)(As + qa * 8), 16, 0, 0);
    }
#pragma unroll
    for (int i = 0; i < 4; i++) {
      int qb = tid + 512 * i;
      int row = qb >> 3, col = (qb & 7) ^ (row & 7);
      __builtin_amdgcn_global_load_lds(
          (const __attribute__((address_space(1))) unsigned int*)
              (B + (size_t)(n0 + row) * ldb + k0 + col * 8),
          (__attribute__((address_space(3))) unsigned int*)(Bs + qb * 8), 16, 0, 0);
    }
    __syncthreads();
#pragma unroll
    for (int ks = 0; ks < 2; ks++) {
      int cchunk = ks * 4 + lhi;
      bf16x8 af[4], bfr[4];
#pragma unroll
      for (int mi = 0; mi < 4; mi++) {
        int r = wr + mi * 16 + llo;
        __builtin_memcpy(&af[mi], As + (size_t)r * 64 + (cchunk ^ (r & 7)) * 8, 16);
      }
#pragma unroll
      for (int nj = 0; nj < 4; nj++) {
        int r = wc + nj * 16 + llo;
        __builtin_memcpy(&bfr[nj], Bs + (size_t)r * 64 + (cchunk ^ (r & 7)) * 8, 16);
      }
#pragma unroll
      for (int mi = 0; mi < 4; mi++)
#pragma unroll
        for (int nj = 0; nj < 4; nj++)
          acc[mi][nj] = __builtin_amdgcn_mfma_f32_16x16x32_bf16(af[mi], bfr[nj],
                                                                acc[mi][nj], 0, 0, 0);
    }
    __syncthreads();
  }

  if constexpr (LN2F) {
    // v = acc + bias + R; accumulate row sum / sumsq (rows of 256 = full N)
    float sr[4][4], qr[4][4];
#pragma unroll
    for (int mi = 0; mi < 4; mi++)
#pragma unroll
      for (int j = 0; j < 4; j++) { sr[mi][j] = 0.f; qr[mi][j] = 0.f; }
#pragma unroll
    for (int mi = 0; mi < 4; mi++)
#pragma unroll
      for (int nj = 0; nj < 4; nj++) {
        int n = wc + nj * 16 + llo;
        float bv = bias[n];
#pragma unroll
        for (int j = 0; j < 4; j++) {
          int m = m0 + wr + mi * 16 + lhi * 4 + j;
          float v = acc[mi][nj][j] + bv + R[(size_t)m * 256 + n];
          acc[mi][nj][j] = v;
          sr[mi][j] += v;
          qr[mi][j] += v * v;
        }
      }
#pragma unroll
    for (int mi = 0; mi < 4; mi++)
#pragma unroll
      for (int j = 0; j < 4; j++)
#pragma unroll
        for (int d = 1; d < 16; d <<= 1) {
          sr[mi][j] += __shfl_xor(sr[mi][j], d);
          qr[mi][j] += __shfl_xor(qr[mi][j], d);
        }
    if (llo == 0) {
#pragma unroll
      for (int mi = 0; mi < 4; mi++)
#pragma unroll
        for (int j = 0; j < 4; j++) {
          int lr = wr + mi * 16 + lhi * 4 + j;
          redS[wid & 3][lr] = sr[mi][j];
          redQ[wid & 3][lr] = qr[mi][j];
        }
    }
    __syncthreads();
#pragma unroll
    for (int mi = 0; mi < 4; mi++)
#pragma unroll
      for (int j = 0; j < 4; j++) {
        int lr = wr + mi * 16 + lhi * 4 + j;
        float S = redS[0][lr] + redS[1][lr] + redS[2][lr] + redS[3][lr];
        float Q = redQ[0][lr] + redQ[1][lr] + redQ[2][lr] + redQ[3][lr];
        float mu = S * (1.f / 256.f);
        float var = Q * (1.f / 256.f) - mu * mu;
        float rs = rsqrtf(var + 1e-6f);
        size_t mrow = (size_t)(m0 + lr) * 256;
#pragma unroll
        for (int nj = 0; nj < 4; nj++) {
          int n = wc + nj * 16 + llo;
          float v = acc[mi][nj][j];
          ((float*)C_)[mrow + n] = v;
          ob2[mrow + n] = f2bf((v - mu) * rs * g2[n] + b2[n]);
        }
      }
  } else {
    int coln = llo, rowg = lhi * 4;
#pragma unroll
    for (int mi = 0; mi < 4; mi++) {
#pragma unroll
      for (int nj = 0; nj < 4; nj++) {
        int n = n0 + wc + nj * 16 + coln;
        float bv = (flags & 8) ? 0.f : bias[n];
#pragma unroll
        for (int j = 0; j < 4; j++) {
          int m = m0 + wr + mi * 16 + rowg + j;
          float v = acc[mi][nj][j] + bv;
          if (flags & 1) v = 0.5f * v * (1.0f + erff(v * 0.70710678118654752f));
          if (flags & 2) v += R[(size_t)m * N + n];
          if (OUTBF) ((unsigned short*)C_)[(size_t)m * N + n] = f2bf(v);
          else       ((float*)C_)[(size_t)m * N + n] = v;
        }
      }
    }
  }
}

// ---------------- f32 -> bf16 flat convert ----------------
__global__ __launch_bounds__(256) void cvt_kernel(const float* __restrict__ s,
                                                  unsigned short* __restrict__ d, int n) {
  int i = blockIdx.x * 256 + threadIdx.x;
  if (i < n) d[i] = f2bf(s[i]);
}

// ---------------- pack qv bias ----------------
__global__ __launch_bounds__(512) void bqv_kernel(const float* __restrict__ qkv_b,
                                                  float* __restrict__ bqv) {
  int i = threadIdx.x;
  bqv[i] = qkv_b[i < 256 ? i : i + 256];
}

// ---------------- pool LN1 (f32 in): 2x2 cell means (bf16) + window means (f32) ----
__global__ __launch_bounds__(256) void pool_kernel(const float* __restrict__ x,
                                                   unsigned short* __restrict__ plx,
                                                   float* __restrict__ wmx) {
  int np = blockIdx.x, c = threadIdx.x;
  int n = np / 49, p = np % 49, wr = p / 7, wc = p % 7;
  float tot = 0.f;
  for (int s = 0; s < 16; s++) {
    int i = s >> 2, j = s & 3;
    float a = 0.f;
    for (int di = 0; di < 2; di++)
      for (int dj = 0; dj < 2; dj++) {
        size_t t = ((size_t)n * 56 + wr * 8 + i * 2 + di) * 56 + wc * 8 + j * 2 + dj;
        a += x[t * 256 + c];
      }
    a *= 0.25f;
    plx[((size_t)np * 16 + s) * 256 + c] = f2bf(a);
    tot += a;
  }
  wmx[(size_t)np * 256 + c] = tot * (1.f / 16.f);
}

// ---------------- window-mean projection (f32): qkwin = wmx @ qkv_w[0:512]^T + b ----
__global__ __launch_bounds__(256) void winproj_kernel(const float* __restrict__ wmx,
                                                      const float* __restrict__ qkv_w,
                                                      const float* __restrict__ qkv_b,
                                                      float* __restrict__ qkwin) {
  int np = blockIdx.x, t = threadIdx.x;
  __shared__ float xs[256];
  xs[t] = wmx[(size_t)np * 256 + t];
  __syncthreads();
  for (int rep = 0; rep < 2; rep++) {
    int n = t + rep * 256;
    const float* wrow = qkv_w + (size_t)n * 256;
    float s = qkv_b[n];
    for (int c = 0; c < 256; c++) s += xs[c] * wrow[c];
    qkwin[(size_t)np * 512 + n] = s;
  }
}

// ---------------- routing logits + top-4 (set semantics) ----------------
__global__ __launch_bounds__(64) void topk_kernel(const float* __restrict__ qkwin,
                                                  int* __restrict__ idx) {
  int np = blockIdx.x;
  int n = np / 49;
  int j = threadIdx.x;
  __shared__ float lg[49];
  if (j < 49) {
    const float* qp = qkwin + (size_t)np * 512;
    const float* kp = qkwin + ((size_t)n * 49 + j) * 512 + 256;
    float s = 0.f;
    for (int c = 0; c < 256; c++) s += qp[c] * kp[c];
    lg[j] = s;
  }
  __syncthreads();
  if (j == 0) {
    unsigned long long used = 0ull;
    for (int t = 0; t < 4; t++) {
      float best = -INFINITY;
      int bi = 0;
      for (int q = 0; q < 49; q++)
        if (!((used >> q) & 1ull) && lg[q] > best) { best = lg[q]; bi = q; }
      idx[np * 4 + t] = bi;
      used |= (1ull << bi);
    }
  }
}

// ---------------- MFMA attention: one 64-lane wave per (window, head) ----------------
__global__ __launch_bounds__(64) void attn_mfma(const unsigned short* __restrict__ qvb,
                                                const unsigned short* __restrict__ kvp,
                                                const int* __restrict__ idx,
                                                unsigned short* __restrict__ out) {
  __shared__ unsigned short Vt[32 * 72];   // Vt[c][k], stride 72 (144B rows)
  __shared__ unsigned short Pl[64 * 72];   // P[q][k], stride 72
  int bid = blockIdx.x;
  int head = bid & 7, np = bid >> 3;
  int n = np / 49, p = np % 49;
  int h0 = (p / 7) * 8, w0 = (p % 7) * 8;
  int lane = threadIdx.x;
  int lhi = lane >> 4, llo = lane & 15;

  int wi4[4];
#pragma unroll
  for (int t = 0; t < 4; t++) wi4[t] = idx[np * 4 + t];

#pragma unroll
  for (int it = 0; it < 4; it++) {
    int cell = lane >> 2;
    int chunk = lane & 3;
    int s = it * 16 + cell;
    const unsigned short* g = kvp + ((size_t)(n * 49 + wi4[it]) * 16 + cell) * 512
                              + 256 + head * 32 + chunk * 8;
    unsigned short vv[8];
    __builtin_memcpy(vv, g, 16);
#pragma unroll
    for (int j = 0; j < 8; j++) Vt[(chunk * 8 + j) * 72 + s] = vv[j];
  }

  bf16x8 qf[4], kf[4];
#pragma unroll
  for (int mi = 0; mi < 4; mi++) {
    int row = mi * 16 + llo;
    int h = h0 + (row >> 3), w = w0 + (row & 7);
    __builtin_memcpy(&qf[mi],
                     qvb + (((size_t)n * 56 + h) * 56 + w) * 512 + head * 32 + lhi * 8, 16);
  }
#pragma unroll
  for (int nj = 0; nj < 4; nj++) {
    __builtin_memcpy(&kf[nj],
                     kvp + ((size_t)(n * 49 + wi4[nj]) * 16 + llo) * 512 + head * 32 + lhi * 8,
                     16);
  }

  f32x4 acc[4][4];
#pragma unroll
  for (int mi = 0; mi < 4; mi++)
#pragma unroll
    for (int nj = 0; nj < 4; nj++) acc[mi][nj] = (f32x4){0.f, 0.f, 0.f, 0.f};
#pragma unroll
  for (int mi = 0; mi < 4; mi++)
#pragma unroll
    for (int nj = 0; nj < 4; nj++)
      acc[mi][nj] = __builtin_amdgcn_mfma_f32_16x16x32_bf16(qf[mi], kf[nj], acc[mi][nj], 0, 0, 0);

#pragma unroll
  for (int mi = 0; mi < 4; mi++)
#pragma unroll
    for (int nj = 0; nj < 4; nj++) acc[mi][nj] *= 0.0625f;
#pragma unroll
  for (int mi = 0; mi < 4; mi++) {
#pragma unroll
    for (int reg = 0; reg < 4; reg++) {
      float m = fmaxf(fmaxf(acc[mi][0][reg], acc[mi][1][reg]),
                      fmaxf(acc[mi][2][reg], acc[mi][3][reg]));
      m = fmaxf(m, __shfl_xor(m, 1));
      m = fmaxf(m, __shfl_xor(m, 2));
      m = fmaxf(m, __shfl_xor(m, 4));
      m = fmaxf(m, __shfl_xor(m, 8));
      float sum = 0.f;
#pragma unroll
      for (int nj = 0; nj < 4; nj++) {
        float e = __expf(acc[mi][nj][reg] - m);
        acc[mi][nj][reg] = e;
        sum += e;
      }
      sum += __shfl_xor(sum, 1);
      sum += __shfl_xor(sum, 2);
      sum += __shfl_xor(sum, 4);
      sum += __shfl_xor(sum, 8);
      float inv = 1.0f / sum;
#pragma unroll
      for (int nj = 0; nj < 4; nj++) acc[mi][nj][reg] *= inv;
    }
  }

#pragma unroll
  for (int mi = 0; mi < 4; mi++)
#pragma unroll
    for (int nj = 0; nj < 4; nj++)
#pragma unroll
      for (int reg = 0; reg < 4; reg++) {
        int row = mi * 16 + lhi * 4 + reg;
        Pl[row * 72 + nj * 16 + llo] = f2bf(acc[mi][nj][reg]);
      }

  f32x4 o[4][2];
#pragma unroll
  for (int mi = 0; mi < 4; mi++)
#pragma unroll
    for (int nc = 0; nc < 2; nc++) o[mi][nc] = (f32x4){0.f, 0.f, 0.f, 0.f};
#pragma unroll
  for (int ks = 0; ks < 2; ks++) {
    bf16x8 pa[4], vb[2];
#pragma unroll
    for (int mi = 0; mi < 4; mi++)
      __builtin_memcpy(&pa[mi], Pl + (mi * 16 + llo) * 72 + ks * 32 + lhi * 8, 16);
#pragma unroll
    for (int nc = 0; nc < 2; nc++)
      __builtin_memcpy(&vb[nc], Vt + (nc * 16 + llo) * 72 + ks * 32 + lhi * 8, 16);
#pragma unroll
    for (int mi = 0; mi < 4; mi++)
#pragma unroll
      for (int nc = 0; nc < 2; nc++)
        o[mi][nc] = __builtin_amdgcn_mfma_f32_16x16x32_bf16(pa[mi], vb[nc], o[mi][nc], 0, 0, 0);
  }

#pragma unroll
  for (int mi = 0; mi < 4; mi++)
#pragma unroll
    for (int nc = 0; nc < 2; nc++)
#pragma unroll
      for (int reg = 0; reg < 4; reg++) {
        int row = mi * 16 + lhi * 4 + reg;
        int h = h0 + (row >> 3), w = w0 + (row & 7);
        out[(((size_t)n * 56 + h) * 56 + w) * 256 + head * 32 + nc * 16 + llo] =
            f2bf(o[mi][nc][reg]);
      }
}

// ---------------- 5x5 depthwise conv (lepe), 8ch/thread bf16x8, RMW ------------
__global__ __launch_bounds__(256) void lepe_kernel(const unsigned short* __restrict__ qvb,
                                                   const float* __restrict__ w,
                                                   const float* __restrict__ b,
                                                   unsigned short* __restrict__ out) {
  int t = blockIdx.x * 8 + (threadIdx.x >> 5);
  int cg = threadIdx.x & 31;
  int c = cg * 8;
  int n = t / 3136, rem = t % 3136, h = rem / 56, ww = rem % 56;
  float acc[8];
#pragma unroll
  for (int j = 0; j < 8; j++) acc[j] = b[c + j];
  for (int dh = -2; dh <= 2; dh++) {
    int hh = h + dh;
    if ((unsigned)hh >= 56u) continue;
    for (int dw = -2; dw <= 2; dw++) {
      int wc = ww + dw;
      if ((unsigned)wc >= 56u) continue;
      unsigned short vv[8];
      __builtin_memcpy(vv, qvb + (((size_t)n * 56 + hh) * 56 + wc) * 512 + 256 + c, 16);
      const float* wp = w + ((dh + 2) * 5 + (dw + 2)) * 256 + c;
#pragma unroll
      for (int j = 0; j < 8; j++) acc[j] += bf2f(vv[j]) * wp[j];
    }
  }
  size_t o = (size_t)t * 256 + c;
  unsigned short ov[8];
  __builtin_memcpy(ov, out + o, 16);
#pragma unroll
  for (int j = 0; j < 8; j++) ov[j] = f2bf(bf2f(ov[j]) + acc[j]);
  __builtin_memcpy(out + o, ov, 16);
}

// ---------------- launch ----------------
extern "C" void kernel_launch(void* const* d_in, const int* in_sizes, int n_in,
                              void* d_out, int out_size, void* d_ws, size_t ws_size,
                              hipStream_t stream) {
  const float* x      = (const float*)d_in[0];
  const float* pos_w  = (const float*)d_in[1];
  const float* pos_b  = (const float*)d_in[2];
  const float* ln1_g  = (const float*)d_in[3];
  const float* ln1_b  = (const float*)d_in[4];
  const float* ln2_g  = (const float*)d_in[5];
  const float* ln2_b  = (const float*)d_in[6];
  const float* qkv_w  = (const float*)d_in[7];
  const float* qkv_b  = (const float*)d_in[8];
  const float* wo_w   = (const float*)d_in[9];
  const float* wo_b   = (const float*)d_in[10];
  const float* lepe_w = (const float*)d_in[11];
  const float* lepe_b = (const float*)d_in[12];
  const float* fc1_w  = (const float*)d_in[13];
  const float* fc1_b  = (const float*)d_in[14];
  const float* fc2_w  = (const float*)d_in[15];
  const float* fc2_b  = (const float*)d_in[16];

  // d_out (TC f32 = 51.4 MB) timeline: xt -> ln1_f32 -> qvb(bf16) -> hbuf(bf16) -> final
  float*          xt   = (float*)d_out;
  float*          lnf  = (float*)d_out;
  unsigned short* qvb  = (unsigned short*)d_out;   // [TOK][512] bf16: q|v
  unsigned short* hbuf = (unsigned short*)d_out;   // [TOK][512] bf16 MLP hidden half

  // ws arena (~100 MB)
  float*          r2   = (float*)d_ws;                       // TC f32 residual
  float*          wmx  = r2 + TC;                            // 784x256 f32
  float*          qkw  = wmx + (size_t)784 * 256;            // 784x512 f32
  float*          bqv  = qkw + (size_t)784 * 512;            // 512 f32
  unsigned short* lnb  = (unsigned short*)(bqv + 512);       // [TOK][256] bf16 (-> aob -> ln2b)
  unsigned short* aob  = lnb;
  unsigned short* ln2b = lnb;
  unsigned short* plx  = lnb + TC;                           // [PTOK][256] bf16
  unsigned short* kvp  = plx + (size_t)PTOK * 256;           // [PTOK][512] bf16
  unsigned short* wqv  = kvp + (size_t)PTOK * 512;           // [512][256] bf16
  unsigned short* wkv  = wqv + (size_t)512 * 256;            // [512][256] bf16
  unsigned short* wwo  = wkv + (size_t)512 * 256;            // [256][256] bf16
  unsigned short* wfc1 = wwo + (size_t)256 * 256;            // [1024][256] bf16
  unsigned short* wfc2 = wfc1 + (size_t)1024 * 256;          // [256][1024] bf16
  int*            idx  = (int*)(wfc2 + (size_t)256 * 1024);  // 784x4

  // weight conversions (independent of data path)
  cvt_kernel<<<(65536 + 255) / 256, 256, 0, stream>>>(qkv_w, wqv, 65536);
  cvt_kernel<<<(65536 + 255) / 256, 256, 0, stream>>>(qkv_w + (size_t)512 * 256, wqv + 65536, 65536);
  cvt_kernel<<<(131072 + 255) / 256, 256, 0, stream>>>(qkv_w + (size_t)256 * 256, wkv, 131072);
  cvt_kernel<<<(65536 + 255) / 256, 256, 0, stream>>>(wo_w, wwo, 65536);
  cvt_kernel<<<(262144 + 255) / 256, 256, 0, stream>>>(fc1_w, wfc1, 262144);
  cvt_kernel<<<(262144 + 255) / 256, 256, 0, stream>>>(fc2_w, wfc2, 262144);
  bqv_kernel<<<1, 512, 0, stream>>>(qkv_b, bqv);

  dim3 tb(32, 8);
  nchw2nhwc<<<dim3(2, 8, NIMG * 56), tb, 0, stream>>>(x, xt);
  posconv_kernel<<<TOK / 4, 256, 0, stream>>>(xt, pos_w, pos_b, r2);
  lnw_kernel<<<TOK / 4, 256, 0, stream>>>(r2, ln1_g, ln1_b, lnf, lnb);
  pool_kernel<<<784, 256, 0, stream>>>(lnf, plx, wmx);            // last reader of lnf
  // q|v projection: [TOK][512] bf16 (overwrites lnf region)
  mgemm2<true, false><<<784, 512, 0, stream>>>(lnb, 256, wqv, 256, bqv, nullptr,
                                               qvb, 512, 256, 0, 2,
                                               nullptr, nullptr, nullptr);
  // pooled k|v projection: [PTOK][512] bf16
  mgemm2<true, false><<<196, 512, 0, stream>>>(plx, 256, wkv, 256, qkv_b + 256, nullptr,
                                               kvp, 512, 256, 0, 2,
                                               nullptr, nullptr, nullptr);
  winproj_kernel<<<784, 256, 0, stream>>>(wmx, qkv_w, qkv_b, qkw);
  topk_kernel<<<784, 64, 0, stream>>>(qkw, idx);
  attn_mfma<<<6272, 64, 0, stream>>>(qvb, kvp, idx, aob);
  lepe_kernel<<<TOK / 8, 256, 0, stream>>>(qvb, lepe_w, lepe_b, aob);
  // wo projection + residual + fused LN2 -> r2 (f32 v) and ln2b (bf16 LN out)
  mgemm2<false, true><<<392, 512, 0, stream>>>(aob, 256, wwo, 256, wo_b, r2,
                                               r2, 256, 256, 2, 1,
                                               ln2_g, ln2_b, ln2b);
  // MLP: two hidden halves of 512 (hbuf overwrites dead qvb)
  mgemm2<true, false><<<784, 512, 0, stream>>>(ln2b, 256, wfc1, 256, fc1_b, nullptr,
                                               hbuf, 512, 256, 1, 2,
                                               nullptr, nullptr, nullptr);
  mgemm2<false, false><<<392, 512, 0, stream>>>(hbuf, 512, wfc2, 1024, fc2_b, r2,
                                                r2, 256, 512, 2, 1,
                                                nullptr, nullptr, nullptr);
  mgemm2<true, false><<<784, 512, 0, stream>>>(ln2b, 256, wfc1 + (size_t)512 * 256, 256,
                                               fc1_b + 512, nullptr,
                                               hbuf, 512, 256, 1, 2,
                                               nullptr, nullptr, nullptr);
  mgemm2<false, false><<<392, 512, 0, stream>>>(hbuf, 512, wfc2 + 512, 1024, fc2_b, r2,
                                                r2, 256, 512, 2 | 8, 1,
                                                nullptr, nullptr, nullptr);
  nhwc2nchw<<<dim3(2, 8, NIMG * 56), tb, 0, stream>>>(r2, (float*)d_out);
}

// Round 7
// 508.062 us; speedup vs baseline: 4.4012x; 1.0388x over previous
//
#include <hip/hip_runtime.h>
#include <math.h>

// ---------------- constants ----------------
static constexpr int NIMG = 16;
static constexpr int TOK  = NIMG * 56 * 56;          // 50176
static constexpr size_t TC = (size_t)TOK * 256;      // 12,845,056
static constexpr int PTOK = 784 * 16;                // 12544 pooled tokens

typedef __bf16 bf16x8 __attribute__((ext_vector_type(8)));
typedef float  f32x4  __attribute__((ext_vector_type(4)));

__device__ inline float bf2f(unsigned short u) {
  unsigned int i = ((unsigned int)u) << 16; float f; __builtin_memcpy(&f, &i, 4); return f;
}
__device__ inline unsigned short f2bf(float f) {
  unsigned int i; __builtin_memcpy(&i, &f, 4);
  unsigned int r = i + 0x7fffu + ((i >> 16) & 1u);
  return (unsigned short)(r >> 16);
}

// ---------------- transpose NCHW -> NHWC (float4 both sides) ----------------
__global__ __launch_bounds__(256) void nchw2nhwc(const float* __restrict__ x,
                                                 float* __restrict__ y) {
  __shared__ float T[32][37];
  int nh = blockIdx.z;
  int n = nh / 56, h = nh % 56;
  int c0 = blockIdx.y * 32, w0 = blockIdx.x * 32;
  int tid = threadIdx.x;
  int wlim = 56 - w0; if (wlim > 32) wlim = 32;
  {
    int ci = tid >> 3, w = (tid & 7) * 4;
    if (w < wlim) {
      f32x4 v = *(const f32x4*)&x[(((size_t)n * 256 + c0 + ci) * 56 + h) * 56 + w0 + w];
#pragma unroll
      for (int j = 0; j < 4; j++) T[ci][w + j] = v[j];
    }
  }
  __syncthreads();
  {
    int wi = tid >> 3, cq = tid & 7;
    if (wi < wlim) {
      f32x4 o;
#pragma unroll
      for (int k = 0; k < 4; k++) o[k] = T[cq * 4 + k][wi];
      *(f32x4*)&y[(((size_t)n * 56 + h) * 56 + w0 + wi) * 256 + c0 + cq * 4] = o;
    }
  }
}

// ---------------- transpose NHWC -> NCHW (float4 both sides) ----------------
__global__ __launch_bounds__(256) void nhwc2nchw(const float* __restrict__ y,
                                                 float* __restrict__ o) {
  __shared__ float T[32][37];
  int nh = blockIdx.z;
  int n = nh / 56, h = nh % 56;
  int w0 = blockIdx.x * 32, c0 = blockIdx.y * 32;
  int tid = threadIdx.x;
  int wlim = 56 - w0; if (wlim > 32) wlim = 32;
  {
    int wi = tid >> 3, cq = tid & 7;
    if (wi < wlim) {
      f32x4 v = *(const f32x4*)&y[(((size_t)n * 56 + h) * 56 + w0 + wi) * 256 + c0 + cq * 4];
#pragma unroll
      for (int k = 0; k < 4; k++) T[wi][cq * 4 + k] = v[k];
    }
  }
  __syncthreads();
  {
    int ci = tid >> 3, w = (tid & 7) * 4;
    if (w < wlim) {
      f32x4 ov;
#pragma unroll
      for (int j = 0; j < 4; j++) ov[j] = T[w + j][ci];
      *(f32x4*)&o[(((size_t)n * 256 + c0 + ci) * 56 + h) * 56 + w0 + w] = ov;
    }
  }
}

// ---------------- 3x3 depthwise conv residual, wave/pixel, float4/lane ----------
// XCD-chunked: each XCD owns 2 contiguous images (halo rows stay in its L2).
__global__ __launch_bounds__(256) void posconv_kernel(const float* __restrict__ xt,
                                                      const float* __restrict__ w,
                                                      const float* __restrict__ b,
                                                      float* __restrict__ xh) {
  int bid = blockIdx.x;
  int wgid = (bid & 7) * 1568 + (bid >> 3);     // grid 12544 = 8*1568
  int t = wgid * 4 + (threadIdx.x >> 6);
  int lane = threadIdx.x & 63;
  int c = lane * 4;
  int n = t / 3136, rem = t % 3136, h = rem / 56, ww = rem % 56;
  f32x4 acc = *(const f32x4*)&b[c];
  for (int dh = -1; dh <= 1; dh++) {
    int hh = h + dh;
    if ((unsigned)hh >= 56u) continue;
    for (int dw = -1; dw <= 1; dw++) {
      int wc = ww + dw;
      if ((unsigned)wc >= 56u) continue;
      f32x4 xx = *(const f32x4*)&xt[(((size_t)n * 56 + hh) * 56 + wc) * 256 + c];
      f32x4 wv = *(const f32x4*)&w[((dh + 1) * 3 + (dw + 1)) * 256 + c];
      acc += xx * wv;
    }
  }
  f32x4 xv = *(const f32x4*)&xt[(size_t)t * 256 + c];
  *(f32x4*)&xh[(size_t)t * 256 + c] = xv + acc;
}

// ---------------- LayerNorm, wave/token, float4/lane, shfl reduce ---------------
__global__ __launch_bounds__(256) void lnw_kernel(const float* __restrict__ x,
                                                  const float* __restrict__ g,
                                                  const float* __restrict__ b,
                                                  float* __restrict__ of,
                                                  unsigned short* __restrict__ ob) {
  int t = blockIdx.x * 4 + (threadIdx.x >> 6);
  int lane = threadIdx.x & 63;
  int c = lane * 4;
  f32x4 v = *(const f32x4*)&x[(size_t)t * 256 + c];
  float s = v[0] + v[1] + v[2] + v[3];
#pragma unroll
  for (int m = 1; m < 64; m <<= 1) s += __shfl_xor(s, m);
  float mu = s * (1.f / 256.f);
  f32x4 d = v - mu;
  float ss = d[0] * d[0] + d[1] * d[1] + d[2] * d[2] + d[3] * d[3];
#pragma unroll
  for (int m = 1; m < 64; m <<= 1) ss += __shfl_xor(ss, m);
  float rs = rsqrtf(ss * (1.f / 256.f) + 1e-6f);
  f32x4 gg = *(const f32x4*)&g[c];
  f32x4 bb = *(const f32x4*)&b[c];
  f32x4 y = d * rs * gg + bb;
  if (of) *(f32x4*)&of[(size_t)t * 256 + c] = y;
  if (ob) {
    unsigned short yb[4];
#pragma unroll
    for (int j = 0; j < 4; j++) yb[j] = f2bf(y[j]);
    __builtin_memcpy(ob + (size_t)t * 256 + c, yb, 8);
  }
}

// ---------------- MFMA bf16 GEMM v2: C[M][N] = A[M][lda] * B[N][ldb]^T -------------
// BM=128, BN=256, BK=64, 512 threads (8 waves, 2x4), bijective XCD chunking.
// flags: 1 = exact GELU, 2 = += R (f32, ld=N), 8 = skip bias
// LN2F: fused LayerNorm epilogue (N == 256, gx == 1, flags&2).
template <bool OUTBF, bool LN2F>
__global__ __launch_bounds__(512, 4) void mgemm2(const unsigned short* __restrict__ A, int lda,
                                                 const unsigned short* __restrict__ B, int ldb,
                                                 const float* __restrict__ bias,
                                                 const float* __restrict__ R,
                                                 void* __restrict__ C_,
                                                 int N, int K, int flags, int gx,
                                                 const float* __restrict__ g2,
                                                 const float* __restrict__ b2,
                                                 unsigned short* __restrict__ ob2) {
  __shared__ unsigned short As[128 * 64];
  __shared__ unsigned short Bs[256 * 64];
  __shared__ float redS[4][128];
  __shared__ float redQ[4][128];
  int tid = threadIdx.x;
  int nwg = gridDim.x, bid = blockIdx.x;
  int q8 = nwg >> 3, r8 = nwg & 7;
  int xcd = bid & 7, pos = bid >> 3;
  int wgid = (xcd < r8 ? xcd * (q8 + 1) : r8 * (q8 + 1) + (xcd - r8) * q8) + pos;
  int m0 = (wgid / gx) * 128;
  int n0 = (wgid % gx) * 256;

  int lane = tid & 63, wid = tid >> 6;
  int wr = (wid >> 2) * 64, wc = (wid & 3) * 64;
  int llo = lane & 15, lhi = lane >> 4;

  f32x4 acc[4][4];
#pragma unroll
  for (int i = 0; i < 4; i++)
#pragma unroll
    for (int j = 0; j < 4; j++) acc[i][j] = (f32x4){0.f, 0.f, 0.f, 0.f};

  for (int k0 = 0; k0 < K; k0 += 64) {
#pragma unroll
    for (int i = 0; i < 2; i++) {
      int qa = tid + 512 * i;
      int row = qa >> 3, col = (qa & 7) ^ (row & 7);
      __builtin_amdgcn_global_load_lds(
          (const __attribute__((address_space(1))) unsigned int*)
              (A + (size_t)(m0 + row) * lda + k0 + col * 8),
          (__attribute__((address_space(3))) unsigned int*)(As + qa * 8), 16, 0, 0);
    }
#pragma unroll
    for (int i = 0; i < 4; i++) {
      int qb = tid + 512 * i;
      int row = qb >> 3, col = (qb & 7) ^ (row & 7);
      __builtin_amdgcn_global_load_lds(
          (const __attribute__((address_space(1))) unsigned int*)
              (B + (size_t)(n0 + row) * ldb + k0 + col * 8),
          (__attribute__((address_space(3))) unsigned int*)(Bs + qb * 8), 16, 0, 0);
    }
    __syncthreads();
#pragma unroll
    for (int ks = 0; ks < 2; ks++) {
      int cchunk = ks * 4 + lhi;
      bf16x8 af[4], bfr[4];
#pragma unroll
      for (int mi = 0; mi < 4; mi++) {
        int r = wr + mi * 16 + llo;
        __builtin_memcpy(&af[mi], As + (size_t)r * 64 + (cchunk ^ (r & 7)) * 8, 16);
      }
#pragma unroll
      for (int nj = 0; nj < 4; nj++) {
        int r = wc + nj * 16 + llo;
        __builtin_memcpy(&bfr[nj], Bs + (size_t)r * 64 + (cchunk ^ (r & 7)) * 8, 16);
      }
#pragma unroll
      for (int mi = 0; mi < 4; mi++)
#pragma unroll
        for (int nj = 0; nj < 4; nj++)
          acc[mi][nj] = __builtin_amdgcn_mfma_f32_16x16x32_bf16(af[mi], bfr[nj],
                                                                acc[mi][nj], 0, 0, 0);
    }
    __syncthreads();
  }

  if constexpr (LN2F) {
    float sr[4][4], qr[4][4];
#pragma unroll
    for (int mi = 0; mi < 4; mi++)
#pragma unroll
      for (int j = 0; j < 4; j++) { sr[mi][j] = 0.f; qr[mi][j] = 0.f; }
#pragma unroll
    for (int mi = 0; mi < 4; mi++)
#pragma unroll
      for (int nj = 0; nj < 4; nj++) {
        int n = wc + nj * 16 + llo;
        float bv = bias[n];
#pragma unroll
        for (int j = 0; j < 4; j++) {
          int m = m0 + wr + mi * 16 + lhi * 4 + j;
          float v = acc[mi][nj][j] + bv + R[(size_t)m * 256 + n];
          acc[mi][nj][j] = v;
          sr[mi][j] += v;
          qr[mi][j] += v * v;
        }
      }
#pragma unroll
    for (int mi = 0; mi < 4; mi++)
#pragma unroll
      for (int j = 0; j < 4; j++)
#pragma unroll
        for (int d = 1; d < 16; d <<= 1) {
          sr[mi][j] += __shfl_xor(sr[mi][j], d);
          qr[mi][j] += __shfl_xor(qr[mi][j], d);
        }
    if (llo == 0) {
#pragma unroll
      for (int mi = 0; mi < 4; mi++)
#pragma unroll
        for (int j = 0; j < 4; j++) {
          int lr = wr + mi * 16 + lhi * 4 + j;
          redS[wid & 3][lr] = sr[mi][j];
          redQ[wid & 3][lr] = qr[mi][j];
        }
    }
    __syncthreads();
#pragma unroll
    for (int mi = 0; mi < 4; mi++)
#pragma unroll
      for (int j = 0; j < 4; j++) {
        int lr = wr + mi * 16 + lhi * 4 + j;
        float S = redS[0][lr] + redS[1][lr] + redS[2][lr] + redS[3][lr];
        float Q = redQ[0][lr] + redQ[1][lr] + redQ[2][lr] + redQ[3][lr];
        float mu = S * (1.f / 256.f);
        float var = Q * (1.f / 256.f) - mu * mu;
        float rs = rsqrtf(var + 1e-6f);
        size_t mrow = (size_t)(m0 + lr) * 256;
#pragma unroll
        for (int nj = 0; nj < 4; nj++) {
          int n = wc + nj * 16 + llo;
          float v = acc[mi][nj][j];
          ((float*)C_)[mrow + n] = v;
          ob2[mrow + n] = f2bf((v - mu) * rs * g2[n] + b2[n]);
        }
      }
  } else {
    int coln = llo, rowg = lhi * 4;
#pragma unroll
    for (int mi = 0; mi < 4; mi++) {
#pragma unroll
      for (int nj = 0; nj < 4; nj++) {
        int n = n0 + wc + nj * 16 + coln;
        float bv = (flags & 8) ? 0.f : bias[n];
#pragma unroll
        for (int j = 0; j < 4; j++) {
          int m = m0 + wr + mi * 16 + rowg + j;
          float v = acc[mi][nj][j] + bv;
          if (flags & 1) v = 0.5f * v * (1.0f + erff(v * 0.70710678118654752f));
          if (flags & 2) v += R[(size_t)m * N + n];
          if (OUTBF) ((unsigned short*)C_)[(size_t)m * N + n] = f2bf(v);
          else       ((float*)C_)[(size_t)m * N + n] = v;
        }
      }
    }
  }
}

// ---------------- f32 -> bf16 flat convert ----------------
__global__ __launch_bounds__(256) void cvt_kernel(const float* __restrict__ s,
                                                  unsigned short* __restrict__ d, int n) {
  int i = blockIdx.x * 256 + threadIdx.x;
  if (i < n) d[i] = f2bf(s[i]);
}

// ---------------- pack qv bias ----------------
__global__ __launch_bounds__(512) void bqv_kernel(const float* __restrict__ qkv_b,
                                                  float* __restrict__ bqv) {
  int i = threadIdx.x;
  bqv[i] = qkv_b[i < 256 ? i : i + 256];
}

// ---------------- pool LN1 (f32x4/lane): 2x2 cell means (bf16) + window means ----
__global__ __launch_bounds__(256) void pool_kernel(const float* __restrict__ x,
                                                   unsigned short* __restrict__ plx,
                                                   float* __restrict__ wmx) {
  int np = blockIdx.x * 4 + (threadIdx.x >> 6);
  int lane = threadIdx.x & 63;
  int c = lane * 4;
  int n = np / 49, p = np % 49, wr = p / 7, wc = p % 7;
  f32x4 tot = (f32x4){0.f, 0.f, 0.f, 0.f};
  for (int s = 0; s < 16; s++) {
    int i = s >> 2, j = s & 3;
    f32x4 a = (f32x4){0.f, 0.f, 0.f, 0.f};
    for (int di = 0; di < 2; di++)
      for (int dj = 0; dj < 2; dj++) {
        size_t t = ((size_t)n * 56 + wr * 8 + i * 2 + di) * 56 + wc * 8 + j * 2 + dj;
        a += *(const f32x4*)&x[t * 256 + c];
      }
    a *= 0.25f;
    unsigned short ab[4];
#pragma unroll
    for (int k = 0; k < 4; k++) ab[k] = f2bf(a[k]);
    __builtin_memcpy(plx + ((size_t)np * 16 + s) * 256 + c, ab, 8);
    tot += a;
  }
  *(f32x4*)&wmx[(size_t)np * 256 + c] = tot * (1.f / 16.f);
}

// ---------------- window-mean projection (f32): qkwin = wmx @ qkv_w[0:512]^T + b ----
__global__ __launch_bounds__(256) void winproj_kernel(const float* __restrict__ wmx,
                                                      const float* __restrict__ qkv_w,
                                                      const float* __restrict__ qkv_b,
                                                      float* __restrict__ qkwin) {
  int np = blockIdx.x, t = threadIdx.x;
  __shared__ float xs[256];
  xs[t] = wmx[(size_t)np * 256 + t];
  __syncthreads();
  for (int rep = 0; rep < 2; rep++) {
    int n = t + rep * 256;
    const float* wrow = qkv_w + (size_t)n * 256;
    float s = qkv_b[n];
    for (int c = 0; c < 256; c++) s += xs[c] * wrow[c];
    qkwin[(size_t)np * 512 + n] = s;
  }
}

// ---------------- routing logits + top-4 (set semantics) ----------------
__global__ __launch_bounds__(64) void topk_kernel(const float* __restrict__ qkwin,
                                                  int* __restrict__ idx) {
  int np = blockIdx.x;
  int n = np / 49;
  int j = threadIdx.x;
  __shared__ float lg[49];
  if (j < 49) {
    const float* qp = qkwin + (size_t)np * 512;
    const float* kp = qkwin + ((size_t)n * 49 + j) * 512 + 256;
    float s = 0.f;
    for (int c = 0; c < 256; c++) s += qp[c] * kp[c];
    lg[j] = s;
  }
  __syncthreads();
  if (j == 0) {
    unsigned long long used = 0ull;
    for (int t = 0; t < 4; t++) {
      float best = -INFINITY;
      int bi = 0;
      for (int q = 0; q < 49; q++)
        if (!((used >> q) & 1ull) && lg[q] > best) { best = lg[q]; bi = q; }
      idx[np * 4 + t] = bi;
      used |= (1ull << bi);
    }
  }
}

// ---------------- MFMA attention: one 64-lane wave per (window, head) ----------------
__global__ __launch_bounds__(64) void attn_mfma(const unsigned short* __restrict__ qvb,
                                                const unsigned short* __restrict__ kvp,
                                                const int* __restrict__ idx,
                                                unsigned short* __restrict__ out) {
  __shared__ unsigned short Vt[32 * 72];   // Vt[c][k], stride 72 (144B rows)
  __shared__ unsigned short Pl[64 * 72];   // P[q][k], stride 72
  int bid = blockIdx.x;
  int head = bid & 7, np = bid >> 3;
  int n = np / 49, p = np % 49;
  int h0 = (p / 7) * 8, w0 = (p % 7) * 8;
  int lane = threadIdx.x;
  int lhi = lane >> 4, llo = lane & 15;

  int wi4[4];
#pragma unroll
  for (int t = 0; t < 4; t++) wi4[t] = idx[np * 4 + t];

#pragma unroll
  for (int it = 0; it < 4; it++) {
    int cell = lane >> 2;
    int chunk = lane & 3;
    int s = it * 16 + cell;
    const unsigned short* g = kvp + ((size_t)(n * 49 + wi4[it]) * 16 + cell) * 512
                              + 256 + head * 32 + chunk * 8;
    unsigned short vv[8];
    __builtin_memcpy(vv, g, 16);
#pragma unroll
    for (int j = 0; j < 8; j++) Vt[(chunk * 8 + j) * 72 + s] = vv[j];
  }

  bf16x8 qf[4], kf[4];
#pragma unroll
  for (int mi = 0; mi < 4; mi++) {
    int row = mi * 16 + llo;
    int h = h0 + (row >> 3), w = w0 + (row & 7);
    __builtin_memcpy(&qf[mi],
                     qvb + (((size_t)n * 56 + h) * 56 + w) * 512 + head * 32 + lhi * 8, 16);
  }
#pragma unroll
  for (int nj = 0; nj < 4; nj++) {
    __builtin_memcpy(&kf[nj],
                     kvp + ((size_t)(n * 49 + wi4[nj]) * 16 + llo) * 512 + head * 32 + lhi * 8,
                     16);
  }

  f32x4 acc[4][4];
#pragma unroll
  for (int mi = 0; mi < 4; mi++)
#pragma unroll
    for (int nj = 0; nj < 4; nj++) acc[mi][nj] = (f32x4){0.f, 0.f, 0.f, 0.f};
#pragma unroll
  for (int mi = 0; mi < 4; mi++)
#pragma unroll
    for (int nj = 0; nj < 4; nj++)
      acc[mi][nj] = __builtin_amdgcn_mfma_f32_16x16x32_bf16(qf[mi], kf[nj], acc[mi][nj], 0, 0, 0);

#pragma unroll
  for (int mi = 0; mi < 4; mi++)
#pragma unroll
    for (int nj = 0; nj < 4; nj++) acc[mi][nj] *= 0.0625f;
#pragma unroll
  for (int mi = 0; mi < 4; mi++) {
#pragma unroll
    for (int reg = 0; reg < 4; reg++) {
      float m = fmaxf(fmaxf(acc[mi][0][reg], acc[mi][1][reg]),
                      fmaxf(acc[mi][2][reg], acc[mi][3][reg]));
      m = fmaxf(m, __shfl_xor(m, 1));
      m = fmaxf(m, __shfl_xor(m, 2));
      m = fmaxf(m, __shfl_xor(m, 4));
      m = fmaxf(m, __shfl_xor(m, 8));
      float sum = 0.f;
#pragma unroll
      for (int nj = 0; nj < 4; nj++) {
        float e = __expf(acc[mi][nj][reg] - m);
        acc[mi][nj][reg] = e;
        sum += e;
      }
      sum += __shfl_xor(sum, 1);
      sum += __shfl_xor(sum, 2);
      sum += __shfl_xor(sum, 4);
      sum += __shfl_xor(sum, 8);
      float inv = 1.0f / sum;
#pragma unroll
      for (int nj = 0; nj < 4; nj++) acc[mi][nj][reg] *= inv;
    }
  }

#pragma unroll
  for (int mi = 0; mi < 4; mi++)
#pragma unroll
    for (int nj = 0; nj < 4; nj++)
#pragma unroll
      for (int reg = 0; reg < 4; reg++) {
        int row = mi * 16 + lhi * 4 + reg;
        Pl[row * 72 + nj * 16 + llo] = f2bf(acc[mi][nj][reg]);
      }

  f32x4 o[4][2];
#pragma unroll
  for (int mi = 0; mi < 4; mi++)
#pragma unroll
    for (int nc = 0; nc < 2; nc++) o[mi][nc] = (f32x4){0.f, 0.f, 0.f, 0.f};
#pragma unroll
  for (int ks = 0; ks < 2; ks++) {
    bf16x8 pa[4], vb[2];
#pragma unroll
    for (int mi = 0; mi < 4; mi++)
      __builtin_memcpy(&pa[mi], Pl + (mi * 16 + llo) * 72 + ks * 32 + lhi * 8, 16);
#pragma unroll
    for (int nc = 0; nc < 2; nc++)
      __builtin_memcpy(&vb[nc], Vt + (nc * 16 + llo) * 72 + ks * 32 + lhi * 8, 16);
#pragma unroll
    for (int mi = 0; mi < 4; mi++)
#pragma unroll
      for (int nc = 0; nc < 2; nc++)
        o[mi][nc] = __builtin_amdgcn_mfma_f32_16x16x32_bf16(pa[mi], vb[nc], o[mi][nc], 0, 0, 0);
  }

#pragma unroll
  for (int mi = 0; mi < 4; mi++)
#pragma unroll
    for (int nc = 0; nc < 2; nc++)
#pragma unroll
      for (int reg = 0; reg < 4; reg++) {
        int row = mi * 16 + lhi * 4 + reg;
        int h = h0 + (row >> 3), w = w0 + (row & 7);
        out[(((size_t)n * 56 + h) * 56 + w) * 256 + head * 32 + nc * 16 + llo] =
            f2bf(o[mi][nc][reg]);
      }
}

// ---------------- 5x5 depthwise conv (lepe), 8ch/thread bf16x8, RMW ------------
// XCD-chunked: each XCD owns 2 contiguous images (5-row halo stays in its L2).
__global__ __launch_bounds__(256) void lepe_kernel(const unsigned short* __restrict__ qvb,
                                                   const float* __restrict__ w,
                                                   const float* __restrict__ b,
                                                   unsigned short* __restrict__ out) {
  int bid = blockIdx.x;
  int wgid = (bid & 7) * 784 + (bid >> 3);      // grid 6272 = 8*784
  int t = wgid * 8 + (threadIdx.x >> 5);
  int cg = threadIdx.x & 31;
  int c = cg * 8;
  int n = t / 3136, rem = t % 3136, h = rem / 56, ww = rem % 56;
  float acc[8];
#pragma unroll
  for (int j = 0; j < 8; j++) acc[j] = b[c + j];
  for (int dh = -2; dh <= 2; dh++) {
    int hh = h + dh;
    if ((unsigned)hh >= 56u) continue;
    for (int dw = -2; dw <= 2; dw++) {
      int wc = ww + dw;
      if ((unsigned)wc >= 56u) continue;
      unsigned short vv[8];
      __builtin_memcpy(vv, qvb + (((size_t)n * 56 + hh) * 56 + wc) * 512 + 256 + c, 16);
      const float* wp = w + ((dh + 2) * 5 + (dw + 2)) * 256 + c;
#pragma unroll
      for (int j = 0; j < 8; j++) acc[j] += bf2f(vv[j]) * wp[j];
    }
  }
  size_t o = (size_t)t * 256 + c;
  unsigned short ov[8];
  __builtin_memcpy(ov, out + o, 16);
#pragma unroll
  for (int j = 0; j < 8; j++) ov[j] = f2bf(bf2f(ov[j]) + acc[j]);
  __builtin_memcpy(out + o, ov, 16);
}

// ---------------- launch ----------------
extern "C" void kernel_launch(void* const* d_in, const int* in_sizes, int n_in,
                              void* d_out, int out_size, void* d_ws, size_t ws_size,
                              hipStream_t stream) {
  const float* x      = (const float*)d_in[0];
  const float* pos_w  = (const float*)d_in[1];
  const float* pos_b  = (const float*)d_in[2];
  const float* ln1_g  = (const float*)d_in[3];
  const float* ln1_b  = (const float*)d_in[4];
  const float* ln2_g  = (const float*)d_in[5];
  const float* ln2_b  = (const float*)d_in[6];
  const float* qkv_w  = (const float*)d_in[7];
  const float* qkv_b  = (const float*)d_in[8];
  const float* wo_w   = (const float*)d_in[9];
  const float* wo_b   = (const float*)d_in[10];
  const float* lepe_w = (const float*)d_in[11];
  const float* lepe_b = (const float*)d_in[12];
  const float* fc1_w  = (const float*)d_in[13];
  const float* fc1_b  = (const float*)d_in[14];
  const float* fc2_w  = (const float*)d_in[15];
  const float* fc2_b  = (const float*)d_in[16];

  // d_out (TC f32 = 51.4 MB) timeline: xt -> ln1_f32 -> qvb(bf16) -> hbuf(bf16) -> final
  float*          xt   = (float*)d_out;
  float*          lnf  = (float*)d_out;
  unsigned short* qvb  = (unsigned short*)d_out;   // [TOK][512] bf16: q|v
  unsigned short* hbuf = (unsigned short*)d_out;   // [TOK][512] bf16 MLP hidden half

  // ws arena (~100 MB)
  float*          r2   = (float*)d_ws;                       // TC f32 residual
  float*          wmx  = r2 + TC;                            // 784x256 f32
  float*          qkw  = wmx + (size_t)784 * 256;            // 784x512 f32
  float*          bqv  = qkw + (size_t)784 * 512;            // 512 f32
  unsigned short* lnb  = (unsigned short*)(bqv + 512);       // [TOK][256] bf16 (-> aob -> ln2b)
  unsigned short* aob  = lnb;
  unsigned short* ln2b = lnb;
  unsigned short* plx  = lnb + TC;                           // [PTOK][256] bf16
  unsigned short* kvp  = plx + (size_t)PTOK * 256;           // [PTOK][512] bf16
  unsigned short* wqv  = kvp + (size_t)PTOK * 512;           // [512][256] bf16
  unsigned short* wkv  = wqv + (size_t)512 * 256;            // [512][256] bf16
  unsigned short* wwo  = wkv + (size_t)512 * 256;            // [256][256] bf16
  unsigned short* wfc1 = wwo + (size_t)256 * 256;            // [1024][256] bf16
  unsigned short* wfc2 = wfc1 + (size_t)1024 * 256;          // [256][1024] bf16
  int*            idx  = (int*)(wfc2 + (size_t)256 * 1024);  // 784x4

  // weight conversions (independent of data path)
  cvt_kernel<<<(65536 + 255) / 256, 256, 0, stream>>>(qkv_w, wqv, 65536);
  cvt_kernel<<<(65536 + 255) / 256, 256, 0, stream>>>(qkv_w + (size_t)512 * 256, wqv + 65536, 65536);
  cvt_kernel<<<(131072 + 255) / 256, 256, 0, stream>>>(qkv_w + (size_t)256 * 256, wkv, 131072);
  cvt_kernel<<<(65536 + 255) / 256, 256, 0, stream>>>(wo_w, wwo, 65536);
  cvt_kernel<<<(262144 + 255) / 256, 256, 0, stream>>>(fc1_w, wfc1, 262144);
  cvt_kernel<<<(262144 + 255) / 256, 256, 0, stream>>>(fc2_w, wfc2, 262144);
  bqv_kernel<<<1, 512, 0, stream>>>(qkv_b, bqv);

  dim3 tb(32, 8);
  nchw2nhwc<<<dim3(2, 8, NIMG * 56), 256, 0, stream>>>(x, xt);
  posconv_kernel<<<TOK / 4, 256, 0, stream>>>(xt, pos_w, pos_b, r2);
  lnw_kernel<<<TOK / 4, 256, 0, stream>>>(r2, ln1_g, ln1_b, lnf, lnb);
  pool_kernel<<<196, 256, 0, stream>>>(lnf, plx, wmx);            // last reader of lnf
  // q|v projection: [TOK][512] bf16 (overwrites lnf region)
  mgemm2<true, false><<<784, 512, 0, stream>>>(lnb, 256, wqv, 256, bqv, nullptr,
                                               qvb, 512, 256, 0, 2,
                                               nullptr, nullptr, nullptr);
  // pooled k|v projection: [PTOK][512] bf16
  mgemm2<true, false><<<196, 512, 0, stream>>>(plx, 256, wkv, 256, qkv_b + 256, nullptr,
                                               kvp, 512, 256, 0, 2,
                                               nullptr, nullptr, nullptr);
  winproj_kernel<<<784, 256, 0, stream>>>(wmx, qkv_w, qkv_b, qkw);
  topk_kernel<<<784, 64, 0, stream>>>(qkw, idx);
  attn_mfma<<<6272, 64, 0, stream>>>(qvb, kvp, idx, aob);
  lepe_kernel<<<TOK / 8, 256, 0, stream>>>(qvb, lepe_w, lepe_b, aob);
  // wo projection + residual + fused LN2 -> r2 (f32 v) and ln2b (bf16 LN out)
  mgemm2<false, true><<<392, 512, 0, stream>>>(aob, 256, wwo, 256, wo_b, r2,
                                               r2, 256, 256, 2, 1,
                                               ln2_g, ln2_b, ln2b);
  // MLP: two hidden halves of 512 (hbuf overwrites dead qvb)
  mgemm2<true, false><<<784, 512, 0, stream>>>(ln2b, 256, wfc1, 256, fc1_b, nullptr,
                                               hbuf, 512, 256, 1, 2,
                                               nullptr, nullptr, nullptr);
  mgemm2<false, false><<<392, 512, 0, stream>>>(hbuf, 512, wfc2, 1024, fc2_b, r2,
                                                r2, 256, 512, 2, 1,
                                                nullptr, nullptr, nullptr);
  mgemm2<true, false><<<784, 512, 0, stream>>>(ln2b, 256, wfc1 + (size_t)512 * 256, 256,
                                               fc1_b + 512, nullptr,
                                               hbuf, 512, 256, 1, 2,
                                               nullptr, nullptr, nullptr);
  mgemm2<false, false><<<392, 512, 0, stream>>>(hbuf, 512, wfc2 + 512, 1024, fc2_b, r2,
                                                r2, 256, 512, 2 | 8, 1,
                                                nullptr, nullptr, nullptr);
  nhwc2nchw<<<dim3(2, 8, NIMG * 56), 256, 0, stream>>>(r2, (float*)d_out);
}

// Round 8
// 479.464 us; speedup vs baseline: 4.6638x; 1.0596x over previous
//
#include <hip/hip_runtime.h>
#include <math.h>

// ---------------- constants ----------------
static constexpr int NIMG = 16;
static constexpr int TOK  = NIMG * 56 * 56;          // 50176
static constexpr size_t TC = (size_t)TOK * 256;      // 12,845,056
static constexpr int PTOK = 784 * 16;                // 12544 pooled tokens

typedef __bf16 bf16x8 __attribute__((ext_vector_type(8)));
typedef float  f32x4  __attribute__((ext_vector_type(4)));

__device__ inline float bf2f(unsigned short u) {
  unsigned int i = ((unsigned int)u) << 16; float f; __builtin_memcpy(&f, &i, 4); return f;
}
__device__ inline unsigned short f2bf(float f) {
  unsigned int i; __builtin_memcpy(&i, &f, 4);
  unsigned int r = i + 0x7fffu + ((i >> 16) & 1u);
  return (unsigned short)(r >> 16);
}

// ---------------- transpose NCHW -> NHWC (float4 both sides) ----------------
__global__ __launch_bounds__(256) void nchw2nhwc(const float* __restrict__ x,
                                                 float* __restrict__ y) {
  __shared__ float T[32][37];
  int nh = blockIdx.z;
  int n = nh / 56, h = nh % 56;
  int c0 = blockIdx.y * 32, w0 = blockIdx.x * 32;
  int tid = threadIdx.x;
  int wlim = 56 - w0; if (wlim > 32) wlim = 32;
  {
    int ci = tid >> 3, w = (tid & 7) * 4;
    if (w < wlim) {
      f32x4 v = *(const f32x4*)&x[(((size_t)n * 256 + c0 + ci) * 56 + h) * 56 + w0 + w];
#pragma unroll
      for (int j = 0; j < 4; j++) T[ci][w + j] = v[j];
    }
  }
  __syncthreads();
  {
    int wi = tid >> 3, cq = tid & 7;
    if (wi < wlim) {
      f32x4 o;
#pragma unroll
      for (int k = 0; k < 4; k++) o[k] = T[cq * 4 + k][wi];
      *(f32x4*)&y[(((size_t)n * 56 + h) * 56 + w0 + wi) * 256 + c0 + cq * 4] = o;
    }
  }
}

// ---------------- transpose NHWC -> NCHW (float4 both sides) ----------------
__global__ __launch_bounds__(256) void nhwc2nchw(const float* __restrict__ y,
                                                 float* __restrict__ o) {
  __shared__ float T[32][37];
  int nh = blockIdx.z;
  int n = nh / 56, h = nh % 56;
  int w0 = blockIdx.x * 32, c0 = blockIdx.y * 32;
  int tid = threadIdx.x;
  int wlim = 56 - w0; if (wlim > 32) wlim = 32;
  {
    int wi = tid >> 3, cq = tid & 7;
    if (wi < wlim) {
      f32x4 v = *(const f32x4*)&y[(((size_t)n * 56 + h) * 56 + w0 + wi) * 256 + c0 + cq * 4];
#pragma unroll
      for (int k = 0; k < 4; k++) T[wi][cq * 4 + k] = v[k];
    }
  }
  __syncthreads();
  {
    int ci = tid >> 3, w = (tid & 7) * 4;
    if (w < wlim) {
      f32x4 ov;
#pragma unroll
      for (int j = 0; j < 4; j++) ov[j] = T[w + j][ci];
      *(f32x4*)&o[(((size_t)n * 256 + c0 + ci) * 56 + h) * 56 + w0 + w] = ov;
    }
  }
}

// ---------------- fused 3x3 dwconv residual + LayerNorm1 ----------------
// wave per token (64 lanes x 4ch). Batched branchless taps. XCD-chunked.
// outputs: xh (f32 residual), lnb (bf16 LN), murs (mu, rsigma per token).
__global__ __launch_bounds__(256) void posln_kernel(const float* __restrict__ xt,
                                                    const float* __restrict__ w,
                                                    const float* __restrict__ bb,
                                                    const float* __restrict__ g1,
                                                    const float* __restrict__ b1,
                                                    float* __restrict__ xh,
                                                    unsigned short* __restrict__ lnb,
                                                    float* __restrict__ murs) {
  int bid = blockIdx.x;
  int wgid = (bid & 7) * 1568 + (bid >> 3);     // grid 12544 = 8*1568
  int t = wgid * 4 + (threadIdx.x >> 6);
  int lane = threadIdx.x & 63;
  int c = lane * 4;
  int n = t / 3136, rem = t % 3136, h = rem / 56, ww = rem % 56;
  const float* base = xt + (size_t)n * 3136 * 256 + c;

  f32x4 xx[9]; float msk[9];
#pragma unroll
  for (int k = 0; k < 9; k++) {
    int dh = k / 3 - 1, dw = k % 3 - 1;
    int hh = h + dh, wc = ww + dw;
    msk[k] = ((unsigned)hh < 56u && (unsigned)wc < 56u) ? 1.f : 0.f;
    int hcl = hh < 0 ? 0 : (hh > 55 ? 55 : hh);
    int wcl = wc < 0 ? 0 : (wc > 55 ? 55 : wc);
    xx[k] = *(const f32x4*)&base[(size_t)(hcl * 56 + wcl) * 256];
  }
  f32x4 acc = *(const f32x4*)&bb[c];
#pragma unroll
  for (int k = 0; k < 9; k++) {
    f32x4 wv = *(const f32x4*)&w[k * 256 + c];
    acc += xx[k] * (wv * msk[k]);
  }
  f32x4 v = xx[4] + acc;   // xx[4] == center pixel (dh=0,dw=0)
  *(f32x4*)&xh[(size_t)t * 256 + c] = v;

  // LayerNorm over the wave
  float s = v[0] + v[1] + v[2] + v[3];
#pragma unroll
  for (int m = 1; m < 64; m <<= 1) s += __shfl_xor(s, m);
  float mu = s * (1.f / 256.f);
  f32x4 d = v - mu;
  float ss = d[0] * d[0] + d[1] * d[1] + d[2] * d[2] + d[3] * d[3];
#pragma unroll
  for (int m = 1; m < 64; m <<= 1) ss += __shfl_xor(ss, m);
  float rs = rsqrtf(ss * (1.f / 256.f) + 1e-6f);
  f32x4 gg = *(const f32x4*)&g1[c];
  f32x4 b4 = *(const f32x4*)&b1[c];
  f32x4 y = d * rs * gg + b4;
  unsigned short yb[4];
#pragma unroll
  for (int j = 0; j < 4; j++) yb[j] = f2bf(y[j]);
  __builtin_memcpy(lnb + (size_t)t * 256 + c, yb, 8);
  if (lane == 0) {
    murs[2 * (size_t)t] = mu;
    murs[2 * (size_t)t + 1] = rs;
  }
}

// ---------------- MFMA bf16 GEMM v2 (BM=128,BN=256,BK=64, XCD-chunked) ------------
// flags: 1 = exact GELU, 2 = += R (f32, ld=N), 8 = skip bias
// LN2F: fused LayerNorm epilogue (N == 256, gx == 1, flags&2).
template <bool OUTBF, bool LN2F>
__global__ __launch_bounds__(512, 4) void mgemm2(const unsigned short* __restrict__ A, int lda,
                                                 const unsigned short* __restrict__ B, int ldb,
                                                 const float* __restrict__ bias,
                                                 const float* __restrict__ R,
                                                 void* __restrict__ C_,
                                                 int N, int K, int flags, int gx,
                                                 const float* __restrict__ g2,
                                                 const float* __restrict__ b2,
                                                 unsigned short* __restrict__ ob2) {
  __shared__ unsigned short As[128 * 64];
  __shared__ unsigned short Bs[256 * 64];
  __shared__ float redS[4][128];
  __shared__ float redQ[4][128];
  int tid = threadIdx.x;
  int nwg = gridDim.x, bid = blockIdx.x;
  int q8 = nwg >> 3, r8 = nwg & 7;
  int xcd = bid & 7, pos = bid >> 3;
  int wgid = (xcd < r8 ? xcd * (q8 + 1) : r8 * (q8 + 1) + (xcd - r8) * q8) + pos;
  int m0 = (wgid / gx) * 128;
  int n0 = (wgid % gx) * 256;

  int lane = tid & 63, wid = tid >> 6;
  int wr = (wid >> 2) * 64, wc = (wid & 3) * 64;
  int llo = lane & 15, lhi = lane >> 4;

  f32x4 acc[4][4];
#pragma unroll
  for (int i = 0; i < 4; i++)
#pragma unroll
    for (int j = 0; j < 4; j++) acc[i][j] = (f32x4){0.f, 0.f, 0.f, 0.f};

  for (int k0 = 0; k0 < K; k0 += 64) {
#pragma unroll
    for (int i = 0; i < 2; i++) {
      int qa = tid + 512 * i;
      int row = qa >> 3, col = (qa & 7) ^ (row & 7);
      __builtin_amdgcn_global_load_lds(
          (const __attribute__((address_space(1))) unsigned int*)
              (A + (size_t)(m0 + row) * lda + k0 + col * 8),
          (__attribute__((address_space(3))) unsigned int*)(As + qa * 8), 16, 0, 0);
    }
#pragma unroll
    for (int i = 0; i < 4; i++) {
      int qb = tid + 512 * i;
      int row = qb >> 3, col = (qb & 7) ^ (row & 7);
      __builtin_amdgcn_global_load_lds(
          (const __attribute__((address_space(1))) unsigned int*)
              (B + (size_t)(n0 + row) * ldb + k0 + col * 8),
          (__attribute__((address_space(3))) unsigned int*)(Bs + qb * 8), 16, 0, 0);
    }
    __syncthreads();
#pragma unroll
    for (int ks = 0; ks < 2; ks++) {
      int cchunk = ks * 4 + lhi;
      bf16x8 af[4], bfr[4];
#pragma unroll
      for (int mi = 0; mi < 4; mi++) {
        int r = wr + mi * 16 + llo;
        __builtin_memcpy(&af[mi], As + (size_t)r * 64 + (cchunk ^ (r & 7)) * 8, 16);
      }
#pragma unroll
      for (int nj = 0; nj < 4; nj++) {
        int r = wc + nj * 16 + llo;
        __builtin_memcpy(&bfr[nj], Bs + (size_t)r * 64 + (cchunk ^ (r & 7)) * 8, 16);
      }
#pragma unroll
      for (int mi = 0; mi < 4; mi++)
#pragma unroll
        for (int nj = 0; nj < 4; nj++)
          acc[mi][nj] = __builtin_amdgcn_mfma_f32_16x16x32_bf16(af[mi], bfr[nj],
                                                                acc[mi][nj], 0, 0, 0);
    }
    __syncthreads();
  }

  if constexpr (LN2F) {
    float sr[4][4], qr[4][4];
#pragma unroll
    for (int mi = 0; mi < 4; mi++)
#pragma unroll
      for (int j = 0; j < 4; j++) { sr[mi][j] = 0.f; qr[mi][j] = 0.f; }
#pragma unroll
    for (int mi = 0; mi < 4; mi++)
#pragma unroll
      for (int nj = 0; nj < 4; nj++) {
        int n = wc + nj * 16 + llo;
        float bv = bias[n];
#pragma unroll
        for (int j = 0; j < 4; j++) {
          int m = m0 + wr + mi * 16 + lhi * 4 + j;
          float v = acc[mi][nj][j] + bv + R[(size_t)m * 256 + n];
          acc[mi][nj][j] = v;
          sr[mi][j] += v;
          qr[mi][j] += v * v;
        }
      }
#pragma unroll
    for (int mi = 0; mi < 4; mi++)
#pragma unroll
      for (int j = 0; j < 4; j++)
#pragma unroll
        for (int d = 1; d < 16; d <<= 1) {
          sr[mi][j] += __shfl_xor(sr[mi][j], d);
          qr[mi][j] += __shfl_xor(qr[mi][j], d);
        }
    if (llo == 0) {
#pragma unroll
      for (int mi = 0; mi < 4; mi++)
#pragma unroll
        for (int j = 0; j < 4; j++) {
          int lr = wr + mi * 16 + lhi * 4 + j;
          redS[wid & 3][lr] = sr[mi][j];
          redQ[wid & 3][lr] = qr[mi][j];
        }
    }
    __syncthreads();
#pragma unroll
    for (int mi = 0; mi < 4; mi++)
#pragma unroll
      for (int j = 0; j < 4; j++) {
        int lr = wr + mi * 16 + lhi * 4 + j;
        float S = redS[0][lr] + redS[1][lr] + redS[2][lr] + redS[3][lr];
        float Q = redQ[0][lr] + redQ[1][lr] + redQ[2][lr] + redQ[3][lr];
        float mu = S * (1.f / 256.f);
        float var = Q * (1.f / 256.f) - mu * mu;
        float rs = rsqrtf(var + 1e-6f);
        size_t mrow = (size_t)(m0 + lr) * 256;
#pragma unroll
        for (int nj = 0; nj < 4; nj++) {
          int n = wc + nj * 16 + llo;
          float v = acc[mi][nj][j];
          ((float*)C_)[mrow + n] = v;
          ob2[mrow + n] = f2bf((v - mu) * rs * g2[n] + b2[n]);
        }
      }
  } else {
    int coln = llo, rowg = lhi * 4;
#pragma unroll
    for (int mi = 0; mi < 4; mi++) {
#pragma unroll
      for (int nj = 0; nj < 4; nj++) {
        int n = n0 + wc + nj * 16 + coln;
        float bv = (flags & 8) ? 0.f : bias[n];
#pragma unroll
        for (int j = 0; j < 4; j++) {
          int m = m0 + wr + mi * 16 + rowg + j;
          float v = acc[mi][nj][j] + bv;
          if (flags & 1) v = 0.5f * v * (1.0f + erff(v * 0.70710678118654752f));
          if (flags & 2) v += R[(size_t)m * N + n];
          if (OUTBF) ((unsigned short*)C_)[(size_t)m * N + n] = f2bf(v);
          else       ((float*)C_)[(size_t)m * N + n] = v;
        }
      }
    }
  }
}

// ---------------- one-shot weight prep (all f32->bf16 conversions + bqv pack) ------
__global__ __launch_bounds__(256) void prep_kernel(const float* __restrict__ qkv_w,
                                                   const float* __restrict__ qkv_b,
                                                   const float* __restrict__ wo_w,
                                                   const float* __restrict__ fc1_w,
                                                   const float* __restrict__ fc2_w,
                                                   unsigned short* __restrict__ wqv,
                                                   unsigned short* __restrict__ wkv,
                                                   unsigned short* __restrict__ wwo,
                                                   unsigned short* __restrict__ wfc1,
                                                   unsigned short* __restrict__ wfc2,
                                                   float* __restrict__ bqv) {
  int i = blockIdx.x * 256 + threadIdx.x;
  if (i < 65536) { wqv[i] = f2bf(qkv_w[i]); }
  else if (i < 131072) { int j = i - 65536; wqv[65536 + j] = f2bf(qkv_w[512 * 256 + j]); }
  else if (i < 262144) { int j = i - 131072; wkv[j] = f2bf(qkv_w[256 * 256 + j]); }
  else if (i < 327680) { int j = i - 262144; wwo[j] = f2bf(wo_w[j]); }
  else if (i < 589824) { int j = i - 327680; wfc1[j] = f2bf(fc1_w[j]); }
  else if (i < 851968) { int j = i - 589824; wfc2[j] = f2bf(fc2_w[j]); }
  else if (i < 852480) { int j = i - 851968; bqv[j] = qkv_b[j < 256 ? j : j + 256]; }
}

// ---------------- pool: LN applied on the fly from (xh, murs) ----------------
__global__ __launch_bounds__(256) void pool_kernel(const float* __restrict__ xh,
                                                   const float* __restrict__ murs,
                                                   const float* __restrict__ g1,
                                                   const float* __restrict__ b1,
                                                   unsigned short* __restrict__ plx,
                                                   float* __restrict__ wmx) {
  int np = blockIdx.x * 4 + (threadIdx.x >> 6);
  int lane = threadIdx.x & 63;
  int c = lane * 4;
  int n = np / 49, p = np % 49, wr = p / 7, wcq = p % 7;
  f32x4 g4 = *(const f32x4*)&g1[c];
  f32x4 b4 = *(const f32x4*)&b1[c];
  f32x4 tot = (f32x4){0.f, 0.f, 0.f, 0.f};
  for (int s = 0; s < 16; s++) {
    int i = s >> 2, j = s & 3;
    f32x4 z = (f32x4){0.f, 0.f, 0.f, 0.f};
    for (int di = 0; di < 2; di++)
      for (int dj = 0; dj < 2; dj++) {
        size_t t = ((size_t)n * 56 + wr * 8 + i * 2 + di) * 56 + wcq * 8 + j * 2 + dj;
        float mu = murs[2 * t], rs = murs[2 * t + 1];
        f32x4 v = *(const f32x4*)&xh[t * 256 + c];
        z += (v - mu) * rs;
      }
    z *= 0.25f;
    f32x4 cell = z * g4 + b4;
    unsigned short ab[4];
#pragma unroll
    for (int k = 0; k < 4; k++) ab[k] = f2bf(cell[k]);
    __builtin_memcpy(plx + ((size_t)np * 16 + s) * 256 + c, ab, 8);
    tot += z;
  }
  f32x4 wm = tot * (1.f / 16.f) * g4 + b4;
  *(f32x4*)&wmx[(size_t)np * 256 + c] = wm;
}

// ---------------- window-mean projection (f32): qkwin = wmx @ qkv_w[0:512]^T + b ----
__global__ __launch_bounds__(256) void winproj_kernel(const float* __restrict__ wmx,
                                                      const float* __restrict__ qkv_w,
                                                      const float* __restrict__ qkv_b,
                                                      float* __restrict__ qkwin) {
  int np = blockIdx.x, t = threadIdx.x;
  __shared__ float xs[256];
  xs[t] = wmx[(size_t)np * 256 + t];
  __syncthreads();
  for (int rep = 0; rep < 2; rep++) {
    int n = t + rep * 256;
    const float* wrow = qkv_w + (size_t)n * 256;
    float s = qkv_b[n];
    for (int c = 0; c < 256; c++) s += xs[c] * wrow[c];
    qkwin[(size_t)np * 512 + n] = s;
  }
}

// ---------------- routing logits + top-4 (set semantics) ----------------
__global__ __launch_bounds__(64) void topk_kernel(const float* __restrict__ qkwin,
                                                  int* __restrict__ idx) {
  int np = blockIdx.x;
  int n = np / 49;
  int j = threadIdx.x;
  __shared__ float lg[49];
  if (j < 49) {
    const float* qp = qkwin + (size_t)np * 512;
    const float* kp = qkwin + ((size_t)n * 49 + j) * 512 + 256;
    float s = 0.f;
    for (int c = 0; c < 256; c++) s += qp[c] * kp[c];
    lg[j] = s;
  }
  __syncthreads();
  if (j == 0) {
    unsigned long long used = 0ull;
    for (int t = 0; t < 4; t++) {
      float best = -INFINITY;
      int bi = 0;
      for (int q = 0; q < 49; q++)
        if (!((used >> q) & 1ull) && lg[q] > best) { best = lg[q]; bi = q; }
      idx[np * 4 + t] = bi;
      used |= (1ull << bi);
    }
  }
}

// ---------------- MFMA attention: one 64-lane wave per (window, head) ----------------
__global__ __launch_bounds__(64) void attn_mfma(const unsigned short* __restrict__ qvb,
                                                const unsigned short* __restrict__ kvp,
                                                const int* __restrict__ idx,
                                                unsigned short* __restrict__ out) {
  __shared__ unsigned short Vt[32 * 72];   // Vt[c][k], stride 72 (144B rows)
  __shared__ unsigned short Pl[64 * 72];   // P[q][k], stride 72
  int bid = blockIdx.x;
  int head = bid & 7, np = bid >> 3;
  int n = np / 49, p = np % 49;
  int h0 = (p / 7) * 8, w0 = (p % 7) * 8;
  int lane = threadIdx.x;
  int lhi = lane >> 4, llo = lane & 15;

  int wi4[4];
#pragma unroll
  for (int t = 0; t < 4; t++) wi4[t] = idx[np * 4 + t];

#pragma unroll
  for (int it = 0; it < 4; it++) {
    int cell = lane >> 2;
    int chunk = lane & 3;
    int s = it * 16 + cell;
    const unsigned short* g = kvp + ((size_t)(n * 49 + wi4[it]) * 16 + cell) * 512
                              + 256 + head * 32 + chunk * 8;
    unsigned short vv[8];
    __builtin_memcpy(vv, g, 16);
#pragma unroll
    for (int j = 0; j < 8; j++) Vt[(chunk * 8 + j) * 72 + s] = vv[j];
  }

  bf16x8 qf[4], kf[4];
#pragma unroll
  for (int mi = 0; mi < 4; mi++) {
    int row = mi * 16 + llo;
    int h = h0 + (row >> 3), w = w0 + (row & 7);
    __builtin_memcpy(&qf[mi],
                     qvb + (((size_t)n * 56 + h) * 56 + w) * 512 + head * 32 + lhi * 8, 16);
  }
#pragma unroll
  for (int nj = 0; nj < 4; nj++) {
    __builtin_memcpy(&kf[nj],
                     kvp + ((size_t)(n * 49 + wi4[nj]) * 16 + llo) * 512 + head * 32 + lhi * 8,
                     16);
  }

  f32x4 acc[4][4];
#pragma unroll
  for (int mi = 0; mi < 4; mi++)
#pragma unroll
    for (int nj = 0; nj < 4; nj++) acc[mi][nj] = (f32x4){0.f, 0.f, 0.f, 0.f};
#pragma unroll
  for (int mi = 0; mi < 4; mi++)
#pragma unroll
    for (int nj = 0; nj < 4; nj++)
      acc[mi][nj] = __builtin_amdgcn_mfma_f32_16x16x32_bf16(qf[mi], kf[nj], acc[mi][nj], 0, 0, 0);

#pragma unroll
  for (int mi = 0; mi < 4; mi++)
#pragma unroll
    for (int nj = 0; nj < 4; nj++) acc[mi][nj] *= 0.0625f;
#pragma unroll
  for (int mi = 0; mi < 4; mi++) {
#pragma unroll
    for (int reg = 0; reg < 4; reg++) {
      float m = fmaxf(fmaxf(acc[mi][0][reg], acc[mi][1][reg]),
                      fmaxf(acc[mi][2][reg], acc[mi][3][reg]));
      m = fmaxf(m, __shfl_xor(m, 1));
      m = fmaxf(m, __shfl_xor(m, 2));
      m = fmaxf(m, __shfl_xor(m, 4));
      m = fmaxf(m, __shfl_xor(m, 8));
      float sum = 0.f;
#pragma unroll
      for (int nj = 0; nj < 4; nj++) {
        float e = __expf(acc[mi][nj][reg] - m);
        acc[mi][nj][reg] = e;
        sum += e;
      }
      sum += __shfl_xor(sum, 1);
      sum += __shfl_xor(sum, 2);
      sum += __shfl_xor(sum, 4);
      sum += __shfl_xor(sum, 8);
      float inv = 1.0f / sum;
#pragma unroll
      for (int nj = 0; nj < 4; nj++) acc[mi][nj][reg] *= inv;
    }
  }

#pragma unroll
  for (int mi = 0; mi < 4; mi++)
#pragma unroll
    for (int nj = 0; nj < 4; nj++)
#pragma unroll
      for (int reg = 0; reg < 4; reg++) {
        int row = mi * 16 + lhi * 4 + reg;
        Pl[row * 72 + nj * 16 + llo] = f2bf(acc[mi][nj][reg]);
      }

  f32x4 o[4][2];
#pragma unroll
  for (int mi = 0; mi < 4; mi++)
#pragma unroll
    for (int nc = 0; nc < 2; nc++) o[mi][nc] = (f32x4){0.f, 0.f, 0.f, 0.f};
#pragma unroll
  for (int ks = 0; ks < 2; ks++) {
    bf16x8 pa[4], vb[2];
#pragma unroll
    for (int mi = 0; mi < 4; mi++)
      __builtin_memcpy(&pa[mi], Pl + (mi * 16 + llo) * 72 + ks * 32 + lhi * 8, 16);
#pragma unroll
    for (int nc = 0; nc < 2; nc++)
      __builtin_memcpy(&vb[nc], Vt + (nc * 16 + llo) * 72 + ks * 32 + lhi * 8, 16);
#pragma unroll
    for (int mi = 0; mi < 4; mi++)
#pragma unroll
      for (int nc = 0; nc < 2; nc++)
        o[mi][nc] = __builtin_amdgcn_mfma_f32_16x16x32_bf16(pa[mi], vb[nc], o[mi][nc], 0, 0, 0);
  }

#pragma unroll
  for (int mi = 0; mi < 4; mi++)
#pragma unroll
    for (int nc = 0; nc < 2; nc++)
#pragma unroll
      for (int reg = 0; reg < 4; reg++) {
        int row = mi * 16 + lhi * 4 + reg;
        int h = h0 + (row >> 3), w = w0 + (row & 7);
        out[(((size_t)n * 56 + h) * 56 + w) * 256 + head * 32 + nc * 16 + llo] =
            f2bf(o[mi][nc][reg]);
      }
}

// ---------------- 5x5 dwconv (lepe): two-phase batched loads, branchless --------
// XCD-chunked. Stage all 25 clamped v-loads in regs, then straight-line FMA.
__global__ __launch_bounds__(256) void lepe_kernel(const unsigned short* __restrict__ qvb,
                                                   const float* __restrict__ w,
                                                   const float* __restrict__ b,
                                                   unsigned short* __restrict__ out) {
  int bid = blockIdx.x;
  int wgid = (bid & 7) * 784 + (bid >> 3);      // grid 6272 = 8*784
  int t = wgid * 8 + (threadIdx.x >> 5);
  int cg = threadIdx.x & 31;
  int c = cg * 8;
  int n = t / 3136, rem = t % 3136, h = rem / 56, ww = rem % 56;
  const unsigned short* vbase = qvb + (size_t)n * 3136 * 512 + 256 + c;

  unsigned short vv[25][8];
  float msk[25];
#pragma unroll
  for (int k = 0; k < 25; k++) {
    int dh = k / 5 - 2, dw = k % 5 - 2;
    int hh = h + dh, wc = ww + dw;
    msk[k] = ((unsigned)hh < 56u && (unsigned)wc < 56u) ? 1.f : 0.f;
    int hcl = hh < 0 ? 0 : (hh > 55 ? 55 : hh);
    int wcl = wc < 0 ? 0 : (wc > 55 ? 55 : wc);
    __builtin_memcpy(&vv[k][0], vbase + (size_t)(hcl * 56 + wcl) * 512, 16);
  }

  float acc[8];
#pragma unroll
  for (int j = 0; j < 8; j++) acc[j] = b[c + j];
#pragma unroll
  for (int k = 0; k < 25; k++) {
    const float* wp = w + k * 256 + c;
#pragma unroll
    for (int j = 0; j < 8; j++) acc[j] += bf2f(vv[k][j]) * (wp[j] * msk[k]);
  }

  size_t o = (size_t)t * 256 + c;
  unsigned short ov[8];
  __builtin_memcpy(ov, out + o, 16);
#pragma unroll
  for (int j = 0; j < 8; j++) ov[j] = f2bf(bf2f(ov[j]) + acc[j]);
  __builtin_memcpy(out + o, ov, 16);
}

// ---------------- launch ----------------
extern "C" void kernel_launch(void* const* d_in, const int* in_sizes, int n_in,
                              void* d_out, int out_size, void* d_ws, size_t ws_size,
                              hipStream_t stream) {
  const float* x      = (const float*)d_in[0];
  const float* pos_w  = (const float*)d_in[1];
  const float* pos_b  = (const float*)d_in[2];
  const float* ln1_g  = (const float*)d_in[3];
  const float* ln1_b  = (const float*)d_in[4];
  const float* ln2_g  = (const float*)d_in[5];
  const float* ln2_b  = (const float*)d_in[6];
  const float* qkv_w  = (const float*)d_in[7];
  const float* qkv_b  = (const float*)d_in[8];
  const float* wo_w   = (const float*)d_in[9];
  const float* wo_b   = (const float*)d_in[10];
  const float* lepe_w = (const float*)d_in[11];
  const float* lepe_b = (const float*)d_in[12];
  const float* fc1_w  = (const float*)d_in[13];
  const float* fc1_b  = (const float*)d_in[14];
  const float* fc2_w  = (const float*)d_in[15];
  const float* fc2_b  = (const float*)d_in[16];

  // d_out (TC f32 = 51.4 MB) timeline: xt -> qvb(bf16) -> hbuf(bf16) -> final
  float*          xt   = (float*)d_out;
  unsigned short* qvb  = (unsigned short*)d_out;   // [TOK][512] bf16: q|v
  unsigned short* hbuf = (unsigned short*)d_out;   // [TOK][512] bf16 MLP hidden half

  // ws arena (~101 MB)
  float*          r2   = (float*)d_ws;                       // TC f32 residual
  float*          wmx  = r2 + TC;                            // 784x256 f32
  float*          qkw  = wmx + (size_t)784 * 256;            // 784x512 f32
  float*          bqv  = qkw + (size_t)784 * 512;            // 512 f32
  unsigned short* lnb  = (unsigned short*)(bqv + 512);       // [TOK][256] bf16 (-> aob -> ln2b)
  unsigned short* aob  = lnb;
  unsigned short* ln2b = lnb;
  unsigned short* plx  = lnb + TC;                           // [PTOK][256] bf16
  unsigned short* kvp  = plx + (size_t)PTOK * 256;           // [PTOK][512] bf16
  unsigned short* wqv  = kvp + (size_t)PTOK * 512;           // [512][256] bf16
  unsigned short* wkv  = wqv + (size_t)512 * 256;            // [512][256] bf16
  unsigned short* wwo  = wkv + (size_t)512 * 256;            // [256][256] bf16
  unsigned short* wfc1 = wwo + (size_t)256 * 256;            // [1024][256] bf16
  unsigned short* wfc2 = wfc1 + (size_t)1024 * 256;          // [256][1024] bf16
  int*            idx  = (int*)(wfc2 + (size_t)256 * 1024);  // 784x4
  float*          murs = (float*)(idx + 784 * 4);            // [TOK][2] f32 (mu, rsigma)

  prep_kernel<<<3330, 256, 0, stream>>>(qkv_w, qkv_b, wo_w, fc1_w, fc2_w,
                                        wqv, wkv, wwo, wfc1, wfc2, bqv);
  nchw2nhwc<<<dim3(2, 8, NIMG * 56), 256, 0, stream>>>(x, xt);
  // fused 3x3 dwconv + LN1: r2 (residual), lnb (bf16 LN), murs
  posln_kernel<<<TOK / 4, 256, 0, stream>>>(xt, pos_w, pos_b, ln1_g, ln1_b,
                                            r2, lnb, murs);
  pool_kernel<<<196, 256, 0, stream>>>(r2, murs, ln1_g, ln1_b, plx, wmx);
  // q|v projection: [TOK][512] bf16 (overwrites dead xt region)
  mgemm2<true, false><<<784, 512, 0, stream>>>(lnb, 256, wqv, 256, bqv, nullptr,
                                               qvb, 512, 256, 0, 2,
                                               nullptr, nullptr, nullptr);
  // pooled k|v projection: [PTOK][512] bf16
  mgemm2<true, false><<<196, 512, 0, stream>>>(plx, 256, wkv, 256, qkv_b + 256, nullptr,
                                               kvp, 512, 256, 0, 2,
                                               nullptr, nullptr, nullptr);
  winproj_kernel<<<784, 256, 0, stream>>>(wmx, qkv_w, qkv_b, qkw);
  topk_kernel<<<784, 64, 0, stream>>>(qkw, idx);
  attn_mfma<<<6272, 64, 0, stream>>>(qvb, kvp, idx, aob);
  lepe_kernel<<<TOK / 8, 256, 0, stream>>>(qvb, lepe_w, lepe_b, aob);
  // wo projection + residual + fused LN2 -> r2 (f32 v) and ln2b (bf16 LN out)
  mgemm2<false, true><<<392, 512, 0, stream>>>(aob, 256, wwo, 256, wo_b, r2,
                                               r2, 256, 256, 2, 1,
                                               ln2_g, ln2_b, ln2b);
  // MLP: two hidden halves of 512 (hbuf overwrites dead qvb)
  mgemm2<true, false><<<784, 512, 0, stream>>>(ln2b, 256, wfc1, 256, fc1_b, nullptr,
                                               hbuf, 512, 256, 1, 2,
                                               nullptr, nullptr, nullptr);
  mgemm2<false, false><<<392, 512, 0, stream>>>(hbuf, 512, wfc2, 1024, fc2_b, r2,
                                                r2, 256, 512, 2, 1,
                                                nullptr, nullptr, nullptr);
  mgemm2<true, false><<<784, 512, 0, stream>>>(ln2b, 256, wfc1 + (size_t)512 * 256, 256,
                                               fc1_b + 512, nullptr,
                                               hbuf, 512, 256, 1, 2,
                                               nullptr, nullptr, nullptr);
  mgemm2<false, false><<<392, 512, 0, stream>>>(hbuf, 512, wfc2 + 512, 1024, fc2_b, r2,
                                                r2, 256, 512, 2 | 8, 1,
                                                nullptr, nullptr, nullptr);
  nhwc2nchw<<<dim3(2, 8, NIMG * 56), 256, 0, stream>>>(r2, (float*)d_out);
}

// Round 9
// 447.257 us; speedup vs baseline: 4.9996x; 1.0720x over previous
//
#include <hip/hip_runtime.h>
#include <math.h>

// ---------------- constants ----------------
static constexpr int NIMG = 16;
static constexpr int TOK  = NIMG * 56 * 56;          // 50176
static constexpr size_t TC = (size_t)TOK * 256;      // 12,845,056
static constexpr int PTOK = 784 * 16;                // 12544 pooled tokens

typedef __bf16 bf16x8 __attribute__((ext_vector_type(8)));
typedef float  f32x4  __attribute__((ext_vector_type(4)));

__device__ inline float bf2f(unsigned short u) {
  unsigned int i = ((unsigned int)u) << 16; float f; __builtin_memcpy(&f, &i, 4); return f;
}
__device__ inline unsigned short f2bf(float f) {
  unsigned int i; __builtin_memcpy(&i, &f, 4);
  unsigned int r = i + 0x7fffu + ((i >> 16) & 1u);
  return (unsigned short)(r >> 16);
}

// ---------------- transpose NCHW -> NHWC (float4 both sides) ----------------
__global__ __launch_bounds__(256) void nchw2nhwc(const float* __restrict__ x,
                                                 float* __restrict__ y) {
  __shared__ float T[32][37];
  int nh = blockIdx.z;
  int n = nh / 56, h = nh % 56;
  int c0 = blockIdx.y * 32, w0 = blockIdx.x * 32;
  int tid = threadIdx.x;
  int wlim = 56 - w0; if (wlim > 32) wlim = 32;
  {
    int ci = tid >> 3, w = (tid & 7) * 4;
    if (w < wlim) {
      f32x4 v = *(const f32x4*)&x[(((size_t)n * 256 + c0 + ci) * 56 + h) * 56 + w0 + w];
#pragma unroll
      for (int j = 0; j < 4; j++) T[ci][w + j] = v[j];
    }
  }
  __syncthreads();
  {
    int wi = tid >> 3, cq = tid & 7;
    if (wi < wlim) {
      f32x4 o;
#pragma unroll
      for (int k = 0; k < 4; k++) o[k] = T[cq * 4 + k][wi];
      *(f32x4*)&y[(((size_t)n * 56 + h) * 56 + w0 + wi) * 256 + c0 + cq * 4] = o;
    }
  }
}

// ---------------- transpose NHWC -> NCHW (float4 both sides) ----------------
__global__ __launch_bounds__(256) void nhwc2nchw(const float* __restrict__ y,
                                                 float* __restrict__ o) {
  __shared__ float T[32][37];
  int nh = blockIdx.z;
  int n = nh / 56, h = nh % 56;
  int w0 = blockIdx.x * 32, c0 = blockIdx.y * 32;
  int tid = threadIdx.x;
  int wlim = 56 - w0; if (wlim > 32) wlim = 32;
  {
    int wi = tid >> 3, cq = tid & 7;
    if (wi < wlim) {
      f32x4 v = *(const f32x4*)&y[(((size_t)n * 56 + h) * 56 + w0 + wi) * 256 + c0 + cq * 4];
#pragma unroll
      for (int k = 0; k < 4; k++) T[wi][cq * 4 + k] = v[k];
    }
  }
  __syncthreads();
  {
    int ci = tid >> 3, w = (tid & 7) * 4;
    if (w < wlim) {
      f32x4 ov;
#pragma unroll
      for (int j = 0; j < 4; j++) ov[j] = T[w + j][ci];
      *(f32x4*)&o[(((size_t)n * 256 + c0 + ci) * 56 + h) * 56 + w0 + w] = ov;
    }
  }
}

// ---------------- fused 3x3 dwconv residual + LayerNorm1 ----------------
__global__ __launch_bounds__(256) void posln_kernel(const float* __restrict__ xt,
                                                    const float* __restrict__ w,
                                                    const float* __restrict__ bb,
                                                    const float* __restrict__ g1,
                                                    const float* __restrict__ b1,
                                                    float* __restrict__ xh,
                                                    unsigned short* __restrict__ lnb,
                                                    float* __restrict__ murs) {
  int bid = blockIdx.x;
  int wgid = (bid & 7) * 1568 + (bid >> 3);     // grid 12544 = 8*1568
  int t = wgid * 4 + (threadIdx.x >> 6);
  int lane = threadIdx.x & 63;
  int c = lane * 4;
  int n = t / 3136, rem = t % 3136, h = rem / 56, ww = rem % 56;
  const float* base = xt + (size_t)n * 3136 * 256 + c;

  f32x4 xx[9]; float msk[9];
#pragma unroll
  for (int k = 0; k < 9; k++) {
    int dh = k / 3 - 1, dw = k % 3 - 1;
    int hh = h + dh, wc = ww + dw;
    msk[k] = ((unsigned)hh < 56u && (unsigned)wc < 56u) ? 1.f : 0.f;
    int hcl = hh < 0 ? 0 : (hh > 55 ? 55 : hh);
    int wcl = wc < 0 ? 0 : (wc > 55 ? 55 : wc);
    xx[k] = *(const f32x4*)&base[(size_t)(hcl * 56 + wcl) * 256];
  }
  f32x4 acc = *(const f32x4*)&bb[c];
#pragma unroll
  for (int k = 0; k < 9; k++) {
    f32x4 wv = *(const f32x4*)&w[k * 256 + c];
    acc += xx[k] * (wv * msk[k]);
  }
  f32x4 v = xx[4] + acc;
  *(f32x4*)&xh[(size_t)t * 256 + c] = v;

  float s = v[0] + v[1] + v[2] + v[3];
#pragma unroll
  for (int m = 1; m < 64; m <<= 1) s += __shfl_xor(s, m);
  float mu = s * (1.f / 256.f);
  f32x4 d = v - mu;
  float ss = d[0] * d[0] + d[1] * d[1] + d[2] * d[2] + d[3] * d[3];
#pragma unroll
  for (int m = 1; m < 64; m <<= 1) ss += __shfl_xor(ss, m);
  float rs = rsqrtf(ss * (1.f / 256.f) + 1e-6f);
  f32x4 gg = *(const f32x4*)&g1[c];
  f32x4 b4 = *(const f32x4*)&b1[c];
  f32x4 y = d * rs * gg + b4;
  unsigned short yb[4];
#pragma unroll
  for (int j = 0; j < 4; j++) yb[j] = f2bf(y[j]);
  __builtin_memcpy(lnb + (size_t)t * 256 + c, yb, 8);
  if (lane == 0) {
    murs[2 * (size_t)t] = mu;
    murs[2 * (size_t)t + 1] = rs;
  }
}

// ---------------- MFMA bf16 GEMM v2 (BM=128,BN=256,BK=64, XCD-chunked) ------------
// flags: 1 = exact GELU, 2 = += R (f32, ld=N), 8 = skip bias
// LN2F: fused LayerNorm epilogue (N == 256, gx == 1, flags&2).
// Epilogue transposes acc through LDS (4 slabs of 32 rows x 256 cols f32) so all
// global R/C/ob2 accesses are float4 / 16B coalesced, and LN2 rows are wave-local.
template <bool OUTBF, bool LN2F>
__global__ __launch_bounds__(512, 4) void mgemm2(const unsigned short* __restrict__ A, int lda,
                                                 const unsigned short* __restrict__ B, int ldb,
                                                 const float* __restrict__ bias,
                                                 const float* __restrict__ R,
                                                 void* __restrict__ C_,
                                                 int N, int K, int flags, int gx,
                                                 const float* __restrict__ g2,
                                                 const float* __restrict__ b2,
                                                 unsigned short* __restrict__ ob2) {
  __shared__ __attribute__((aligned(16))) char smraw[49152];
  unsigned short* As = (unsigned short*)smraw;                 // 128*64*2 = 16KB
  unsigned short* Bs = (unsigned short*)(smraw + 16384);       // 256*64*2 = 32KB
  float* slab = (float*)smraw;                                 // 32*260*4 = 33.3KB (epilogue)
  constexpr int SSTR = 260;

  int tid = threadIdx.x;
  int nwg = gridDim.x, bid = blockIdx.x;
  int q8 = nwg >> 3, r8 = nwg & 7;
  int xcd = bid & 7, pos = bid >> 3;
  int wgid = (xcd < r8 ? xcd * (q8 + 1) : r8 * (q8 + 1) + (xcd - r8) * q8) + pos;
  int m0 = (wgid / gx) * 128;
  int n0 = (wgid % gx) * 256;

  int lane = tid & 63, wid = tid >> 6;
  int wr = (wid >> 2) * 64, wc = (wid & 3) * 64;
  int llo = lane & 15, lhi = lane >> 4;

  f32x4 acc[4][4];
#pragma unroll
  for (int i = 0; i < 4; i++)
#pragma unroll
    for (int j = 0; j < 4; j++) acc[i][j] = (f32x4){0.f, 0.f, 0.f, 0.f};

  for (int k0 = 0; k0 < K; k0 += 64) {
#pragma unroll
    for (int i = 0; i < 2; i++) {
      int qa = tid + 512 * i;
      int row = qa >> 3, col = (qa & 7) ^ (row & 7);
      __builtin_amdgcn_global_load_lds(
          (const __attribute__((address_space(1))) unsigned int*)
              (A + (size_t)(m0 + row) * lda + k0 + col * 8),
          (__attribute__((address_space(3))) unsigned int*)(As + qa * 8), 16, 0, 0);
    }
#pragma unroll
    for (int i = 0; i < 4; i++) {
      int qb = tid + 512 * i;
      int row = qb >> 3, col = (qb & 7) ^ (row & 7);
      __builtin_amdgcn_global_load_lds(
          (const __attribute__((address_space(1))) unsigned int*)
              (B + (size_t)(n0 + row) * ldb + k0 + col * 8),
          (__attribute__((address_space(3))) unsigned int*)(Bs + qb * 8), 16, 0, 0);
    }
    __syncthreads();
#pragma unroll
    for (int ks = 0; ks < 2; ks++) {
      int cchunk = ks * 4 + lhi;
      bf16x8 af[4], bfr[4];
#pragma unroll
      for (int mi = 0; mi < 4; mi++) {
        int r = wr + mi * 16 + llo;
        __builtin_memcpy(&af[mi], As + (size_t)r * 64 + (cchunk ^ (r & 7)) * 8, 16);
      }
#pragma unroll
      for (int nj = 0; nj < 4; nj++) {
        int r = wc + nj * 16 + llo;
        __builtin_memcpy(&bfr[nj], Bs + (size_t)r * 64 + (cchunk ^ (r & 7)) * 8, 16);
      }
#pragma unroll
      for (int mi = 0; mi < 4; mi++)
#pragma unroll
        for (int nj = 0; nj < 4; nj++)
          acc[mi][nj] = __builtin_amdgcn_mfma_f32_16x16x32_bf16(af[mi], bfr[nj],
                                                                acc[mi][nj], 0, 0, 0);
    }
    __syncthreads();
  }

  // ---- epilogue: 4 slabs of 32 rows ----
#pragma unroll
  for (int s = 0; s < 4; s++) {
    if (wr == (s >> 1) * 64) {
#pragma unroll
      for (int mi2 = 0; mi2 < 2; mi2++) {
        int mi = (s & 1) * 2 + mi2;
#pragma unroll
        for (int nj = 0; nj < 4; nj++) {
          int col = wc + nj * 16 + llo;
#pragma unroll
          for (int j = 0; j < 4; j++)
            slab[(mi2 * 16 + lhi * 4 + j) * SSTR + col] = acc[mi][nj][j];
        }
      }
    }
    __syncthreads();
    int gmBase = m0 + s * 32;
    if (OUTBF) {
#pragma unroll
      for (int i2 = 0; i2 < 2; i2++) {
        int rr = wid * 4 + i2 * 2 + (lane >> 5);
        int col = (lane & 31) * 8;
        f32x4 v0 = *(f32x4*)&slab[rr * SSTR + col];
        f32x4 v1 = *(f32x4*)&slab[rr * SSTR + col + 4];
        if (!(flags & 8)) {
          v0 += *(const f32x4*)&bias[n0 + col];
          v1 += *(const f32x4*)&bias[n0 + col + 4];
        }
        if (flags & 1) {
#pragma unroll
          for (int j = 0; j < 4; j++) {
            v0[j] = 0.5f * v0[j] * (1.0f + erff(v0[j] * 0.70710678118654752f));
            v1[j] = 0.5f * v1[j] * (1.0f + erff(v1[j] * 0.70710678118654752f));
          }
        }
        unsigned short ob[8];
#pragma unroll
        for (int j = 0; j < 4; j++) { ob[j] = f2bf(v0[j]); ob[4 + j] = f2bf(v1[j]); }
        __builtin_memcpy((unsigned short*)C_ + (size_t)(gmBase + rr) * N + n0 + col, ob, 16);
      }
    } else {
#pragma unroll
      for (int i = 0; i < 4; i++) {
        int rr = wid * 4 + i;
        int gm = gmBase + rr;
        int col = lane * 4;
        f32x4 v = *(f32x4*)&slab[rr * SSTR + col];
        if (!(flags & 8)) v += *(const f32x4*)&bias[n0 + col];
        if (flags & 1) {
#pragma unroll
          for (int j = 0; j < 4; j++)
            v[j] = 0.5f * v[j] * (1.0f + erff(v[j] * 0.70710678118654752f));
        }
        if (flags & 2) v += *(const f32x4*)&R[(size_t)gm * N + n0 + col];
        if (LN2F) {
          float sv = v[0] + v[1] + v[2] + v[3];
          float qv = v[0] * v[0] + v[1] * v[1] + v[2] * v[2] + v[3] * v[3];
#pragma unroll
          for (int d = 1; d < 64; d <<= 1) {
            sv += __shfl_xor(sv, d);
            qv += __shfl_xor(qv, d);
          }
          float mu = sv * (1.f / 256.f);
          float var = qv * (1.f / 256.f) - mu * mu;
          float rs = rsqrtf(var + 1e-6f);
          f32x4 g4 = *(const f32x4*)&g2[col];
          f32x4 b4 = *(const f32x4*)&b2[col];
          f32x4 y = (v - mu) * rs * g4 + b4;
          unsigned short yb[4];
#pragma unroll
          for (int j = 0; j < 4; j++) yb[j] = f2bf(y[j]);
          __builtin_memcpy(ob2 + (size_t)gm * 256 + col, yb, 8);
        }
        *(f32x4*)&((float*)C_)[(size_t)gm * N + n0 + col] = v;
      }
    }
    __syncthreads();
  }
}

// ---------------- one-shot weight prep ----------------
__global__ __launch_bounds__(256) void prep_kernel(const float* __restrict__ qkv_w,
                                                   const float* __restrict__ qkv_b,
                                                   const float* __restrict__ wo_w,
                                                   const float* __restrict__ fc1_w,
                                                   const float* __restrict__ fc2_w,
                                                   unsigned short* __restrict__ wqv,
                                                   unsigned short* __restrict__ wkv,
                                                   unsigned short* __restrict__ wwo,
                                                   unsigned short* __restrict__ wfc1,
                                                   unsigned short* __restrict__ wfc2,
                                                   float* __restrict__ bqv) {
  int i = blockIdx.x * 256 + threadIdx.x;
  if (i < 65536) { wqv[i] = f2bf(qkv_w[i]); }
  else if (i < 131072) { int j = i - 65536; wqv[65536 + j] = f2bf(qkv_w[512 * 256 + j]); }
  else if (i < 262144) { int j = i - 131072; wkv[j] = f2bf(qkv_w[256 * 256 + j]); }
  else if (i < 327680) { int j = i - 262144; wwo[j] = f2bf(wo_w[j]); }
  else if (i < 589824) { int j = i - 327680; wfc1[j] = f2bf(fc1_w[j]); }
  else if (i < 851968) { int j = i - 589824; wfc2[j] = f2bf(fc2_w[j]); }
  else if (i < 852480) { int j = i - 851968; bqv[j] = qkv_b[j < 256 ? j : j + 256]; }
}

// ---------------- pool: LN applied on the fly from (xh, murs) ----------------
__global__ __launch_bounds__(256) void pool_kernel(const float* __restrict__ xh,
                                                   const float* __restrict__ murs,
                                                   const float* __restrict__ g1,
                                                   const float* __restrict__ b1,
                                                   unsigned short* __restrict__ plx,
                                                   float* __restrict__ wmx) {
  int np = blockIdx.x * 4 + (threadIdx.x >> 6);
  int lane = threadIdx.x & 63;
  int c = lane * 4;
  int n = np / 49, p = np % 49, wr = p / 7, wcq = p % 7;
  f32x4 g4 = *(const f32x4*)&g1[c];
  f32x4 b4 = *(const f32x4*)&b1[c];
  f32x4 tot = (f32x4){0.f, 0.f, 0.f, 0.f};
  for (int s = 0; s < 16; s++) {
    int i = s >> 2, j = s & 3;
    f32x4 z = (f32x4){0.f, 0.f, 0.f, 0.f};
    for (int di = 0; di < 2; di++)
      for (int dj = 0; dj < 2; dj++) {
        size_t t = ((size_t)n * 56 + wr * 8 + i * 2 + di) * 56 + wcq * 8 + j * 2 + dj;
        float mu = murs[2 * t], rs = murs[2 * t + 1];
        f32x4 v = *(const f32x4*)&xh[t * 256 + c];
        z += (v - mu) * rs;
      }
    z *= 0.25f;
    f32x4 cell = z * g4 + b4;
    unsigned short ab[4];
#pragma unroll
    for (int k = 0; k < 4; k++) ab[k] = f2bf(cell[k]);
    __builtin_memcpy(plx + ((size_t)np * 16 + s) * 256 + c, ab, 8);
    tot += z;
  }
  f32x4 wm = tot * (1.f / 16.f) * g4 + b4;
  *(f32x4*)&wmx[(size_t)np * 256 + c] = wm;
}

// ---------------- window-mean projection (f32) ----------------
__global__ __launch_bounds__(256) void winproj_kernel(const float* __restrict__ wmx,
                                                      const float* __restrict__ qkv_w,
                                                      const float* __restrict__ qkv_b,
                                                      float* __restrict__ qkwin) {
  int np = blockIdx.x, t = threadIdx.x;
  __shared__ float xs[256];
  xs[t] = wmx[(size_t)np * 256 + t];
  __syncthreads();
  for (int rep = 0; rep < 2; rep++) {
    int n = t + rep * 256;
    const float* wrow = qkv_w + (size_t)n * 256;
    float s = qkv_b[n];
    for (int c = 0; c < 256; c++) s += xs[c] * wrow[c];
    qkwin[(size_t)np * 512 + n] = s;
  }
}

// ---------------- routing logits + top-4 (set semantics) ----------------
__global__ __launch_bounds__(64) void topk_kernel(const float* __restrict__ qkwin,
                                                  int* __restrict__ idx) {
  int np = blockIdx.x;
  int n = np / 49;
  int j = threadIdx.x;
  __shared__ float lg[49];
  if (j < 49) {
    const float* qp = qkwin + (size_t)np * 512;
    const float* kp = qkwin + ((size_t)n * 49 + j) * 512 + 256;
    float s = 0.f;
    for (int c = 0; c < 256; c++) s += qp[c] * kp[c];
    lg[j] = s;
  }
  __syncthreads();
  if (j == 0) {
    unsigned long long used = 0ull;
    for (int t = 0; t < 4; t++) {
      float best = -INFINITY;
      int bi = 0;
      for (int q = 0; q < 49; q++)
        if (!((used >> q) & 1ull) && lg[q] > best) { best = lg[q]; bi = q; }
      idx[np * 4 + t] = bi;
      used |= (1ull << bi);
    }
  }
}

// ---------------- MFMA attention: one 64-lane wave per (window, head) ----------------
__global__ __launch_bounds__(64) void attn_mfma(const unsigned short* __restrict__ qvb,
                                                const unsigned short* __restrict__ kvp,
                                                const int* __restrict__ idx,
                                                unsigned short* __restrict__ out) {
  __shared__ unsigned short Vt[32 * 72];   // Vt[c][k], stride 72 (144B rows)
  __shared__ unsigned short Pl[64 * 72];   // P[q][k] stride 72; reused for out staging
  int bid = blockIdx.x;
  int head = bid & 7, np = bid >> 3;
  int n = np / 49, p = np % 49;
  int h0 = (p / 7) * 8, w0 = (p % 7) * 8;
  int lane = threadIdx.x;
  int lhi = lane >> 4, llo = lane & 15;

  int wi4[4];
#pragma unroll
  for (int t = 0; t < 4; t++) wi4[t] = idx[np * 4 + t];

#pragma unroll
  for (int it = 0; it < 4; it++) {
    int cell = lane >> 2;
    int chunk = lane & 3;
    int s = it * 16 + cell;
    const unsigned short* g = kvp + ((size_t)(n * 49 + wi4[it]) * 16 + cell) * 512
                              + 256 + head * 32 + chunk * 8;
    unsigned short vv[8];
    __builtin_memcpy(vv, g, 16);
#pragma unroll
    for (int j = 0; j < 8; j++) Vt[(chunk * 8 + j) * 72 + s] = vv[j];
  }

  bf16x8 qf[4], kf[4];
#pragma unroll
  for (int mi = 0; mi < 4; mi++) {
    int row = mi * 16 + llo;
    int h = h0 + (row >> 3), w = w0 + (row & 7);
    __builtin_memcpy(&qf[mi],
                     qvb + (((size_t)n * 56 + h) * 56 + w) * 512 + head * 32 + lhi * 8, 16);
  }
#pragma unroll
  for (int nj = 0; nj < 4; nj++) {
    __builtin_memcpy(&kf[nj],
                     kvp + ((size_t)(n * 49 + wi4[nj]) * 16 + llo) * 512 + head * 32 + lhi * 8,
                     16);
  }

  f32x4 acc[4][4];
#pragma unroll
  for (int mi = 0; mi < 4; mi++)
#pragma unroll
    for (int nj = 0; nj < 4; nj++) acc[mi][nj] = (f32x4){0.f, 0.f, 0.f, 0.f};
#pragma unroll
  for (int mi = 0; mi < 4; mi++)
#pragma unroll
    for (int nj = 0; nj < 4; nj++)
      acc[mi][nj] = __builtin_amdgcn_mfma_f32_16x16x32_bf16(qf[mi], kf[nj], acc[mi][nj], 0, 0, 0);

#pragma unroll
  for (int mi = 0; mi < 4; mi++)
#pragma unroll
    for (int nj = 0; nj < 4; nj++) acc[mi][nj] *= 0.0625f;
#pragma unroll
  for (int mi = 0; mi < 4; mi++) {
#pragma unroll
    for (int reg = 0; reg < 4; reg++) {
      float m = fmaxf(fmaxf(acc[mi][0][reg], acc[mi][1][reg]),
                      fmaxf(acc[mi][2][reg], acc[mi][3][reg]));
      m = fmaxf(m, __shfl_xor(m, 1));
      m = fmaxf(m, __shfl_xor(m, 2));
      m = fmaxf(m, __shfl_xor(m, 4));
      m = fmaxf(m, __shfl_xor(m, 8));
      float sum = 0.f;
#pragma unroll
      for (int nj = 0; nj < 4; nj++) {
        float e = __expf(acc[mi][nj][reg] - m);
        acc[mi][nj][reg] = e;
        sum += e;
      }
      sum += __shfl_xor(sum, 1);
      sum += __shfl_xor(sum, 2);
      sum += __shfl_xor(sum, 4);
      sum += __shfl_xor(sum, 8);
      float inv = 1.0f / sum;
#pragma unroll
      for (int nj = 0; nj < 4; nj++) acc[mi][nj][reg] *= inv;
    }
  }

#pragma unroll
  for (int mi = 0; mi < 4; mi++)
#pragma unroll
    for (int nj = 0; nj < 4; nj++)
#pragma unroll
      for (int reg = 0; reg < 4; reg++) {
        int row = mi * 16 + lhi * 4 + reg;
        Pl[row * 72 + nj * 16 + llo] = f2bf(acc[mi][nj][reg]);
      }

  f32x4 o[4][2];
#pragma unroll
  for (int mi = 0; mi < 4; mi++)
#pragma unroll
    for (int nc = 0; nc < 2; nc++) o[mi][nc] = (f32x4){0.f, 0.f, 0.f, 0.f};
#pragma unroll
  for (int ks = 0; ks < 2; ks++) {
    bf16x8 pa[4], vb[2];
#pragma unroll
    for (int mi = 0; mi < 4; mi++)
      __builtin_memcpy(&pa[mi], Pl + (mi * 16 + llo) * 72 + ks * 32 + lhi * 8, 16);
#pragma unroll
    for (int nc = 0; nc < 2; nc++)
      __builtin_memcpy(&vb[nc], Vt + (nc * 16 + llo) * 72 + ks * 32 + lhi * 8, 16);
#pragma unroll
    for (int mi = 0; mi < 4; mi++)
#pragma unroll
      for (int nc = 0; nc < 2; nc++)
        o[mi][nc] = __builtin_amdgcn_mfma_f32_16x16x32_bf16(pa[mi], vb[nc], o[mi][nc], 0, 0, 0);
  }

  // ---- stage o -> LDS (bf16 [64][40]) then 16B coalesced stores ----
  __syncthreads();
#pragma unroll
  for (int mi = 0; mi < 4; mi++)
#pragma unroll
    for (int nc = 0; nc < 2; nc++)
#pragma unroll
      for (int reg = 0; reg < 4; reg++) {
        int row = mi * 16 + lhi * 4 + reg;
        Pl[row * 40 + nc * 16 + llo] = f2bf(o[mi][nc][reg]);
      }
  __syncthreads();
#pragma unroll
  for (int it = 0; it < 4; it++) {
    int slot = it * 64 + lane;
    int row = slot >> 2, cp = slot & 3;
    unsigned short ov[8];
    __builtin_memcpy(ov, Pl + row * 40 + cp * 8, 16);
    int h = h0 + (row >> 3), w = w0 + (row & 7);
    __builtin_memcpy(out + (((size_t)n * 56 + h) * 56 + w) * 256 + head * 32 + cp * 8, ov, 16);
  }
}

// ---------------- 5x5 dwconv (lepe) ----------------
__global__ __launch_bounds__(256) void lepe_kernel(const unsigned short* __restrict__ qvb,
                                                   const float* __restrict__ w,
                                                   const float* __restrict__ b,
                                                   unsigned short* __restrict__ out) {
  int bid = blockIdx.x;
  int wgid = (bid & 7) * 784 + (bid >> 3);      // grid 6272 = 8*784
  int t = wgid * 8 + (threadIdx.x >> 5);
  int cg = threadIdx.x & 31;
  int c = cg * 8;
  int n = t / 3136, rem = t % 3136, h = rem / 56, ww = rem % 56;
  const unsigned short* vbase = qvb + (size_t)n * 3136 * 512 + 256 + c;

  float acc[8];
#pragma unroll
  for (int j = 0; j < 8; j++) acc[j] = b[c + j];
#pragma unroll
  for (int k = 0; k < 25; k++) {
    int dh = k / 5 - 2, dw = k % 5 - 2;
    int hh = h + dh, wc = ww + dw;
    float msk = ((unsigned)hh < 56u && (unsigned)wc < 56u) ? 1.f : 0.f;
    int hcl = hh < 0 ? 0 : (hh > 55 ? 55 : hh);
    int wcl = wc < 0 ? 0 : (wc > 55 ? 55 : wc);
    unsigned short vv[8];
    __builtin_memcpy(vv, vbase + (size_t)(hcl * 56 + wcl) * 512, 16);
    const float* wp = w + k * 256 + c;
#pragma unroll
    for (int j = 0; j < 8; j++) acc[j] += bf2f(vv[j]) * (wp[j] * msk);
  }

  size_t o = (size_t)t * 256 + c;
  unsigned short ov[8];
  __builtin_memcpy(ov, out + o, 16);
#pragma unroll
  for (int j = 0; j < 8; j++) ov[j] = f2bf(bf2f(ov[j]) + acc[j]);
  __builtin_memcpy(out + o, ov, 16);
}

// ---------------- launch ----------------
extern "C" void kernel_launch(void* const* d_in, const int* in_sizes, int n_in,
                              void* d_out, int out_size, void* d_ws, size_t ws_size,
                              hipStream_t stream) {
  const float* x      = (const float*)d_in[0];
  const float* pos_w  = (const float*)d_in[1];
  const float* pos_b  = (const float*)d_in[2];
  const float* ln1_g  = (const float*)d_in[3];
  const float* ln1_b  = (const float*)d_in[4];
  const float* ln2_g  = (const float*)d_in[5];
  const float* ln2_b  = (const float*)d_in[6];
  const float* qkv_w  = (const float*)d_in[7];
  const float* qkv_b  = (const float*)d_in[8];
  const float* wo_w   = (const float*)d_in[9];
  const float* wo_b   = (const float*)d_in[10];
  const float* lepe_w = (const float*)d_in[11];
  const float* lepe_b = (const float*)d_in[12];
  const float* fc1_w  = (const float*)d_in[13];
  const float* fc1_b  = (const float*)d_in[14];
  const float* fc2_w  = (const float*)d_in[15];
  const float* fc2_b  = (const float*)d_in[16];

  // d_out (TC f32 = 51.4 MB) timeline: xt -> qvb(bf16) -> hbuf(bf16) -> final
  float*          xt   = (float*)d_out;
  unsigned short* qvb  = (unsigned short*)d_out;   // [TOK][512] bf16: q|v
  unsigned short* hbuf = (unsigned short*)d_out;   // [TOK][512] bf16 MLP hidden half

  // ws arena (~101 MB)
  float*          r2   = (float*)d_ws;                       // TC f32 residual
  float*          wmx  = r2 + TC;                            // 784x256 f32
  float*          qkw  = wmx + (size_t)784 * 256;            // 784x512 f32
  float*          bqv  = qkw + (size_t)784 * 512;            // 512 f32
  unsigned short* lnb  = (unsigned short*)(bqv + 512);       // [TOK][256] bf16 (-> aob -> ln2b)
  unsigned short* aob  = lnb;
  unsigned short* ln2b = lnb;
  unsigned short* plx  = lnb + TC;                           // [PTOK][256] bf16
  unsigned short* kvp  = plx + (size_t)PTOK * 256;           // [PTOK][512] bf16
  unsigned short* wqv  = kvp + (size_t)PTOK * 512;           // [512][256] bf16
  unsigned short* wkv  = wqv + (size_t)512 * 256;            // [512][256] bf16
  unsigned short* wwo  = wkv + (size_t)512 * 256;            // [256][256] bf16
  unsigned short* wfc1 = wwo + (size_t)256 * 256;            // [1024][256] bf16
  unsigned short* wfc2 = wfc1 + (size_t)1024 * 256;          // [256][1024] bf16
  int*            idx  = (int*)(wfc2 + (size_t)256 * 1024);  // 784x4
  float*          murs = (float*)(idx + 784 * 4);            // [TOK][2] f32 (mu, rsigma)

  prep_kernel<<<3330, 256, 0, stream>>>(qkv_w, qkv_b, wo_w, fc1_w, fc2_w,
                                        wqv, wkv, wwo, wfc1, wfc2, bqv);
  nchw2nhwc<<<dim3(2, 8, NIMG * 56), 256, 0, stream>>>(x, xt);
  posln_kernel<<<TOK / 4, 256, 0, stream>>>(xt, pos_w, pos_b, ln1_g, ln1_b,
                                            r2, lnb, murs);
  pool_kernel<<<196, 256, 0, stream>>>(r2, murs, ln1_g, ln1_b, plx, wmx);
  mgemm2<true, false><<<784, 512, 0, stream>>>(lnb, 256, wqv, 256, bqv, nullptr,
                                               qvb, 512, 256, 0, 2,
                                               nullptr, nullptr, nullptr);
  mgemm2<true, false><<<196, 512, 0, stream>>>(plx, 256, wkv, 256, qkv_b + 256, nullptr,
                                               kvp, 512, 256, 0, 2,
                                               nullptr, nullptr, nullptr);
  winproj_kernel<<<784, 256, 0, stream>>>(wmx, qkv_w, qkv_b, qkw);
  topk_kernel<<<784, 64, 0, stream>>>(qkw, idx);
  attn_mfma<<<6272, 64, 0, stream>>>(qvb, kvp, idx, aob);
  lepe_kernel<<<TOK / 8, 256, 0, stream>>>(qvb, lepe_w, lepe_b, aob);
  mgemm2<false, true><<<392, 512, 0, stream>>>(aob, 256, wwo, 256, wo_b, r2,
                                               r2, 256, 256, 2, 1,
                                               ln2_g, ln2_b, ln2b);
  mgemm2<true, false><<<784, 512, 0, stream>>>(ln2b, 256, wfc1, 256, fc1_b, nullptr,
                                               hbuf, 512, 256, 1, 2,
                                               nullptr, nullptr, nullptr);
  mgemm2<false, false><<<392, 512, 0, stream>>>(hbuf, 512, wfc2, 1024, fc2_b, r2,
                                                r2, 256, 512, 2, 1,
                                                nullptr, nullptr, nullptr);
  mgemm2<true, false><<<784, 512, 0, stream>>>(ln2b, 256, wfc1 + (size_t)512 * 256, 256,
                                               fc1_b + 512, nullptr,
                                               hbuf, 512, 256, 1, 2,
                                               nullptr, nullptr, nullptr);
  mgemm2<false, false><<<392, 512, 0, stream>>>(hbuf, 512, wfc2 + 512, 1024, fc2_b, r2,
                                                r2, 256, 512, 2 | 8, 1,
                                                nullptr, nullptr, nullptr);
  nhwc2nchw<<<dim3(2, 8, NIMG * 56), 256, 0, stream>>>(r2, (float*)d_out);
}